// Round 4
// baseline (2998.791 us; speedup 1.0000x reference)
//
#include <hip/hip_runtime.h>

typedef unsigned short u16;
typedef unsigned int u32;
typedef __attribute__((ext_vector_type(8))) short short8;
typedef __attribute__((ext_vector_type(4))) float f32x4;

#define NB 2
#define NT 2048
#define NC 2048
#define NHV 32
#define KEYD 2048
#define VALD 4096
#define QKVD 8192
#define NBT 4096

static __device__ __forceinline__ float bf2f(u16 u) {
  union { u32 u; float f; } x; x.u = ((u32)u) << 16; return x.f;
}
static __device__ __forceinline__ u16 f2bf(float f) {
  union { float f; u32 u; } x; x.f = f;
  u32 r = x.u + 0x7fffu + ((x.u >> 16) & 1u);
  return (u16)(r >> 16);
}
static __device__ __forceinline__ float sigm(float x) { return 1.0f / (1.0f + __expf(-x)); }

// ---------------- sentinel: ws too small marker ----------------
__global__ void k_sentinel(float* out) { out[0] = 1.0e6f; }

// ---------------- build padded W_ba f32 [128][2048] ----------------
__global__ __launch_bounds__(256) void k_wba(const float* __restrict__ Wb, const float* __restrict__ Wa,
                                             float* __restrict__ out) {
  int i = blockIdx.x * 256 + threadIdx.x;
  int r = i >> 11, c = i & 2047;
  float v = 0.f;
  if (r < 32) v = Wb[r * 2048 + c];
  else if (r < 64) v = Wa[(r - 32) * 2048 + c];
  out[i] = v;
}

// ---------------- hi/lo staging: f32 [128 x 32] tile -> bf16 hi + bf16 lo, stride 48 ----------------
static __device__ __forceinline__ void stage_hl(const float* __restrict__ src, int ld,
                                                u16* hi, u16* lo, int tid) {
  const int r0 = tid >> 3, kq = (tid & 7) * 4;
#pragma unroll
  for (int p = 0; p < 4; ++p) {
    int r = p * 32 + r0;
    float4 v = *(const float4*)&src[(size_t)r * ld + kq];
    ushort4 h, l;
    h.x = f2bf(v.x); l.x = f2bf(v.x - bf2f(h.x));
    h.y = f2bf(v.y); l.y = f2bf(v.y - bf2f(h.y));
    h.z = f2bf(v.z); l.z = f2bf(v.z - bf2f(h.z));
    h.w = f2bf(v.w); l.w = f2bf(v.w - bf2f(h.w));
    *(ushort4*)&hi[r * 48 + kq] = h;
    *(ushort4*)&lo[r * 48 + kq] = l;
  }
}

// ---------------- hi/lo GEMM: C[M][N] = A[M][K] * B[N][K]^T, ~f32 precision via 3 bf16 MFMA passes ----
// MODE 0: f32 out. MODE 2: fused delta-net gate epilogue (z GEMM): omat = outr * rms * norm_w * silu(z)
template <int MODE>
__global__ __launch_bounds__(256) void k_gemm_hl(const float* __restrict__ A, const float* __restrict__ B,
                                                 void* __restrict__ Cv, int M, int N, int K,
                                                 const float* __restrict__ outr, const float* __restrict__ rms,
                                                 const float* __restrict__ nw) {
  __shared__ __align__(16) u16 Ah[128 * 48];
  __shared__ __align__(16) u16 Al[128 * 48];
  __shared__ __align__(16) u16 Bh[128 * 48];
  __shared__ __align__(16) u16 Bl[128 * 48];
  const int tid = threadIdx.x;
  const int lane = tid & 63, wave = tid >> 6;
  const int wr = wave >> 1, wc = wave & 1;
  const int l15 = lane & 15, l16 = lane >> 4;
  const int row0 = blockIdx.y * 128, col0 = blockIdx.x * 128;
  f32x4 acc[4][4] = {};
  for (int k0 = 0; k0 < K; k0 += 32) {
    stage_hl(A + (size_t)row0 * K + k0, K, Ah, Al, tid);
    stage_hl(B + (size_t)col0 * K + k0, K, Bh, Bl, tid);
    __syncthreads();
    short8 ah[4], al[4], bh[4], bl[4];
#pragma unroll
    for (int mi = 0; mi < 4; ++mi) {
      ah[mi] = *(short8*)&Ah[(wr * 64 + mi * 16 + l15) * 48 + l16 * 8];
      al[mi] = *(short8*)&Al[(wr * 64 + mi * 16 + l15) * 48 + l16 * 8];
    }
#pragma unroll
    for (int ni = 0; ni < 4; ++ni) {
      bh[ni] = *(short8*)&Bh[(wc * 64 + ni * 16 + l15) * 48 + l16 * 8];
      bl[ni] = *(short8*)&Bl[(wc * 64 + ni * 16 + l15) * 48 + l16 * 8];
    }
#pragma unroll
    for (int mi = 0; mi < 4; ++mi)
#pragma unroll
      for (int ni = 0; ni < 4; ++ni) {
        acc[mi][ni] = __builtin_amdgcn_mfma_f32_16x16x32_bf16(ah[mi], bh[ni], acc[mi][ni], 0, 0, 0);
        acc[mi][ni] = __builtin_amdgcn_mfma_f32_16x16x32_bf16(ah[mi], bl[ni], acc[mi][ni], 0, 0, 0);
        acc[mi][ni] = __builtin_amdgcn_mfma_f32_16x16x32_bf16(al[mi], bh[ni], acc[mi][ni], 0, 0, 0);
      }
    __syncthreads();
  }
#pragma unroll
  for (int mi = 0; mi < 4; ++mi) {
#pragma unroll
    for (int ni = 0; ni < 4; ++ni) {
      int rr = row0 + wr * 64 + mi * 16 + l16 * 4;
      int cc = col0 + wc * 64 + ni * 16 + l15;
#pragma unroll
      for (int i = 0; i < 4; ++i) {
        float v = acc[mi][ni][i];
        size_t idx = (size_t)(rr + i) * N + cc;
        if constexpr (MODE == 0) {
          ((float*)Cv)[idx] = v;
        } else {
          float zs = v * sigm(v);  // silu(z)
          float o = outr[idx] * rms[(size_t)(rr + i) * 32 + (cc >> 7)] * nw[cc & 127] * zs;
          ((float*)Cv)[idx] = o;
        }
      }
    }
  }
}

// ---------------- beta / g from ba [BT,128] f32 ----------------
__global__ __launch_bounds__(256) void k_bg(const float* __restrict__ ba, const float* __restrict__ dt_bias,
                                            const float* __restrict__ A_log, float* __restrict__ beta,
                                            float* __restrict__ g) {
  int i = blockIdx.x * 256 + threadIdx.x;  // 0..131071
  int bt = i >> 5, h = i & 31;
  float bv = ba[(size_t)bt * 128 + h];
  float av = ba[(size_t)bt * 128 + 32 + h];
  beta[i] = sigm(bv);
  float xx = av + dt_bias[h];
  float sp = (xx > 20.f) ? xx : log1pf(__expf(xx));
  g[i] = -__expf(A_log[h]) * sp;
}

// ---------------- fused conv+SiLU+L2norm + gated delta scan (all f32) ----------------
// grid: nb_local*128 blocks (dq 0..3, h 0..31, bl); block 256
// qkv: f32 [nb_local*2048][8192] (batch-local rows); outr: f32 [4096][4096] (global rows)
__global__ __launch_bounds__(256) void k_scanf(const float* __restrict__ qkv, const float* __restrict__ cw,
                                               const float* __restrict__ beta, const float* __restrict__ g,
                                               float* __restrict__ outr, int b_base) {
  __shared__ float rq[11][128], rk[11][128], rv[11][32];
  __shared__ float cq[8][128], ck[8][128], cv[8][32];
  __shared__ float nq[8], nk[8], bb[8], gg[8];
  __shared__ float part[8][8][32];
  const int tid = threadIdx.x;
  const int bid = blockIdx.x;
  const int dq = bid & 3, h = (bid >> 2) & 31, bl = bid >> 7;
  const int b = b_base + bl;
  const int hk = h >> 1;
  const int qch = hk * 128, kch = 2048 + hk * 128, vch = 4096 + h * 128 + dq * 32;
  const int seg = tid >> 5, dvl = tid & 31;
  const int d7 = tid & 127, hf = tid >> 7;
  const float4 cwq = *(const float4*)&cw[(qch + d7) * 4];
  const float4 cwk = *(const float4*)&cw[(kch + d7) * 4];
  const float4 cwv = *(const float4*)&cw[(vch + dvl) * 4];

  float s[16];
#pragma unroll
  for (int i = 0; i < 16; ++i) s[i] = 0.f;

  for (int tt = 0; tt < 256; ++tt) {
    const int t0 = tt * 8;
    // stage raw qkv rows t0-3 .. t0+7 (zero-pad t<0)
#pragma unroll
    for (int r = 0; r < 11; ++r) {
      int tr = t0 - 3 + r;
      size_t rowb = (size_t)(bl * 2048 + tr) * 8192;
      if (hf == 0) rq[r][d7] = (tr >= 0) ? qkv[rowb + qch + d7] : 0.f;
      else         rk[r][d7] = (tr >= 0) ? qkv[rowb + kch + d7] : 0.f;
    }
    {
      int r = tid >> 5;
      int tr = t0 - 3 + r;
      rv[r][dvl] = (tr >= 0) ? qkv[(size_t)(bl * 2048 + tr) * 8192 + vch + dvl] : 0.f;
      if (tid < 96) {
        int r2 = 8 + (tid >> 5);
        int tr2 = t0 - 3 + r2;
        rv[r2][dvl] = (tr2 >= 0) ? qkv[(size_t)(bl * 2048 + tr2) * 8192 + vch + dvl] : 0.f;
      }
    }
    if (tid < 16) {
      int t = tid & 7, w = tid >> 3;
      int idx = (b * 2048 + t0 + t) * 32 + h;
      if (w) gg[t] = g[idx]; else bb[t] = beta[idx];
    }
    __syncthreads();
    // conv (4 taps) + SiLU
#pragma unroll
    for (int i = 0; i < 4; ++i) {
      int t = 2 * i + hf;
      float aq = cwq.x * rq[t][d7] + cwq.y * rq[t + 1][d7] + cwq.z * rq[t + 2][d7] + cwq.w * rq[t + 3][d7];
      cq[t][d7] = aq * sigm(aq);
      float ak = cwk.x * rk[t][d7] + cwk.y * rk[t + 1][d7] + cwk.z * rk[t + 2][d7] + cwk.w * rk[t + 3][d7];
      ck[t][d7] = ak * sigm(ak);
    }
    {
      int t = tid >> 5;
      float av = cwv.x * rv[t][dvl] + cwv.y * rv[t + 1][dvl] + cwv.z * rv[t + 2][dvl] + cwv.w * rv[t + 3][dvl];
      cv[t][dvl] = av * sigm(av);
    }
    __syncthreads();
    // L2 norms of q,k per t: 16 groups x 16 lanes
    {
      int rt = tid >> 4, l16 = tid & 15;
      int t = rt & 7, isk = rt >> 3;
      const float* base = isk ? &ck[t][0] : &cq[t][0];
      float ss = 0.f;
#pragma unroll
      for (int m = 0; m < 8; ++m) { float v = base[l16 + m * 16]; ss += v * v; }
      ss += __shfl_xor(ss, 1); ss += __shfl_xor(ss, 2);
      ss += __shfl_xor(ss, 4); ss += __shfl_xor(ss, 8);
      if (l16 == 0) {
        float n = 1.f / fmaxf(sqrtf(ss), 1e-12f);
        if (isk) nk[t] = n; else nq[t] = n;
      }
    }
    __syncthreads();
    // gated delta scan (norm scales folded in)
#pragma unroll 1
    for (int t = 0; t < 8; ++t) {
      float eg = __expf(gg[t]);
      float bv = bb[t] * nk[t] * cv[t][dvl];
      float p = 0.f;
#pragma unroll
      for (int i = 0; i < 16; ++i) {
        float kk = ck[t][seg * 16 + i];
        s[i] = eg * s[i] + kk * bv;
        p += cq[t][seg * 16 + i] * s[i];
      }
      part[t][seg][dvl] = p * nq[t];
    }
    __syncthreads();
    // reduce 8 segments, write out
    {
      int t = tid >> 5, d = tid & 31;
      float sum = 0.f;
#pragma unroll
      for (int sg = 0; sg < 8; ++sg) sum += part[t][sg][d];
      outr[(size_t)(b * 2048 + t0 + t) * 4096 + h * 128 + dq * 32 + d] = sum;
    }
    __syncthreads();
  }
}

// ---------------- per-(bt,head) RMS scale from f32 outr ----------------
__global__ __launch_bounds__(256) void k_rms(const float* __restrict__ outr, float* __restrict__ rms) {
  int pair = blockIdx.x * 4 + (threadIdx.x >> 6);
  int lane = threadIdx.x & 63;
  float2 v = *(const float2*)&outr[(size_t)pair * 128 + lane * 2];
  float ss = v.x * v.x + v.y * v.y;
#pragma unroll
  for (int m = 1; m < 64; m <<= 1) ss += __shfl_xor(ss, m);
  if (lane == 0) rms[pair] = rsqrtf(ss * (1.0f / 128.0f) + 1e-6f);
}

extern "C" void kernel_launch(void* const* d_in, const int* in_sizes, int n_in,
                              void* d_out, int out_size, void* d_ws, size_t ws_size,
                              hipStream_t stream) {
  const float* x = (const float*)d_in[0];
  // d_in[1] = positions (int64) — unused by the math
  const float* W_qkv = (const float*)d_in[2];
  const float* W_z = (const float*)d_in[3];
  const float* W_b = (const float*)d_in[4];
  const float* W_a = (const float*)d_in[5];
  const float* conv_w = (const float*)d_in[6];
  const float* dt_bias = (const float*)d_in[7];
  const float* A_log = (const float*)d_in[8];
  const float* norm_w = (const float*)d_in[9];
  const float* W_out = (const float*)d_in[10];
  float* out = (float*)d_out;

  const size_t S_Q_FULL = (size_t)NBT * QKVD * 4;       // 128 MiB
  const size_t S_Q_HALF = (size_t)(NBT / 2) * QKVD * 4; // 64 MiB
  const size_t S_O = (size_t)NBT * VALD * 4;            // 64 MiB
  const size_t S_SM = (size_t)NBT * 32 * 4;             // 0.5 MiB

  const size_t need_full = S_Q_FULL + S_O + 3 * S_SM;
  const size_t need_half = S_Q_HALF + S_O + 3 * S_SM;
  const bool full = ws_size >= need_full;
  if (ws_size < need_half) {  // loud, distinguishable failure: absmax ~1e6
    k_sentinel<<<1, 1, 0, stream>>>(out);
    return;
  }
  char* ws = (char*)d_ws;
  char* regQ = ws;                                      // qkv f32 (full or per-batch), later omat
  char* regO = ws + (full ? S_Q_FULL : S_Q_HALF);       // outr f32 [4096][4096]
  float* betab = (float*)(regO + S_O);
  float* gbuf = betab + NBT * 32;
  float* rmsb = gbuf + NBT * 32;
  // wba/babuf overlay regO (dead before any outr write)
  float* wba = (float*)regO;
  float* babuf = (float*)(regO + (1 << 20));
  float* qkvf = (float*)regQ;
  float* outr = (float*)regO;
  float* omat = (float*)regQ;  // overlays qkv (dead after scans)

  // --- b/a path (before scans; babuf/wba die before outr is written) ---
  k_wba<<<128 * NC / 256, 256, 0, stream>>>(W_b, W_a, wba);
  k_gemm_hl<0><<<dim3(1, NBT / 128), 256, 0, stream>>>(x, wba, babuf, NBT, 128, NC,
                                                       nullptr, nullptr, nullptr);
  k_bg<<<NBT * 32 / 256, 256, 0, stream>>>(babuf, dt_bias, A_log, betab, gbuf);

  if (full) {
    k_gemm_hl<0><<<dim3(QKVD / 128, NBT / 128), 256, 0, stream>>>(x, W_qkv, qkvf, NBT, QKVD, NC,
                                                                  nullptr, nullptr, nullptr);
    k_scanf<<<256, 256, 0, stream>>>(qkvf, conv_w, betab, gbuf, outr, 0);
  } else {
    for (int b = 0; b < NB; ++b) {
      k_gemm_hl<0><<<dim3(QKVD / 128, NT / 128), 256, 0, stream>>>(x + (size_t)b * NT * NC, W_qkv, qkvf,
                                                                   NT, QKVD, NC, nullptr, nullptr, nullptr);
      k_scanf<<<128, 256, 0, stream>>>(qkvf, conv_w, betab, gbuf, outr, b);
    }
  }

  k_rms<<<NBT * NHV / 4, 256, 0, stream>>>(outr, rmsb);

  // z projection with fused gated-RMSNorm epilogue -> f32 omat (overlays qkv region)
  k_gemm_hl<2><<<dim3(VALD / 128, NBT / 128), 256, 0, stream>>>(x, W_z, omat, NBT, VALD, NC,
                                                                outr, rmsb, norm_w);

  // output projection -> f32 out
  k_gemm_hl<0><<<dim3(NC / 128, NBT / 128), 256, 0, stream>>>(omat, W_out, out, NBT, NC, VALD,
                                                              nullptr, nullptr, nullptr);
}

// Round 6
// 1916.623 us; speedup vs baseline: 1.5646x; 1.5646x over previous
//
#include <hip/hip_runtime.h>

typedef unsigned short u16;
typedef unsigned int u32;
typedef __attribute__((ext_vector_type(8))) short short8;
typedef __attribute__((ext_vector_type(4))) float f32x4;

#define NB 2
#define NT 2048
#define NC 2048
#define NHV 32
#define KEYD 2048
#define VALD 4096
#define QKVD 8192
#define NBT 4096
#define CL 64
#define NCH (NT / CL)

static __device__ __forceinline__ float bf2f(u16 u) {
  union { u32 u; float f; } x; x.u = ((u32)u) << 16; return x.f;
}
static __device__ __forceinline__ u16 f2bf(float f) {
  union { float f; u32 u; } x; x.f = f;
  u32 r = x.u + 0x7fffu + ((x.u >> 16) & 1u);
  return (u16)(r >> 16);
}
static __device__ __forceinline__ float sigm(float x) { return 1.0f / (1.0f + __expf(-x)); }

// ---------------- sentinel: ws too small marker ----------------
__global__ void k_sentinel(float* out) { out[0] = 1.0e6f; }

// ---------------- build padded W_ba f32 [128][2048] ----------------
__global__ __launch_bounds__(256) void k_wba(const float* __restrict__ Wb, const float* __restrict__ Wa,
                                             float* __restrict__ out) {
  int i = blockIdx.x * 256 + threadIdx.x;
  int r = i >> 11, c = i & 2047;
  float v = 0.f;
  if (r < 32) v = Wb[r * 2048 + c];
  else if (r < 64) v = Wa[(r - 32) * 2048 + c];
  out[i] = v;
}

// ---------------- hi/lo staging: f32 [128 x 32] tile -> bf16 hi + bf16 lo, stride 48 ----------------
static __device__ __forceinline__ void stage_hl(const float* __restrict__ src, int ld,
                                                u16* hi, u16* lo, int tid) {
  const int r0 = tid >> 3, kq = (tid & 7) * 4;
#pragma unroll
  for (int p = 0; p < 4; ++p) {
    int r = p * 32 + r0;
    float4 v = *(const float4*)&src[(size_t)r * ld + kq];
    ushort4 h, l;
    h.x = f2bf(v.x); l.x = f2bf(v.x - bf2f(h.x));
    h.y = f2bf(v.y); l.y = f2bf(v.y - bf2f(h.y));
    h.z = f2bf(v.z); l.z = f2bf(v.z - bf2f(h.z));
    h.w = f2bf(v.w); l.w = f2bf(v.w - bf2f(h.w));
    *(ushort4*)&hi[r * 48 + kq] = h;
    *(ushort4*)&lo[r * 48 + kq] = l;
  }
}

// ---------------- hi/lo GEMM: C[M][N] = A[M][K] * B[N][K]^T, ~f32 precision via 3 bf16 MFMA passes ----
// MODE 0: f32 out C0. MODE 2: z epilogue: C0 = e0(outr)*e1(rms)*e2(nw)*silu(acc).
// MODE 3: split: cols<4096 -> C0, cols>=4096 -> C1 (both f32 width 4096).
template <int MODE>
__global__ __launch_bounds__(256) void k_gemm_hl(const float* __restrict__ A, const float* __restrict__ B,
                                                 void* __restrict__ C0, void* __restrict__ C1,
                                                 int M, int N, int K,
                                                 const float* __restrict__ e0, const float* __restrict__ e1,
                                                 const float* __restrict__ e2) {
  __shared__ __align__(16) u16 Ah[128 * 48];
  __shared__ __align__(16) u16 Al[128 * 48];
  __shared__ __align__(16) u16 Bh[128 * 48];
  __shared__ __align__(16) u16 Bl[128 * 48];
  const int tid = threadIdx.x;
  const int lane = tid & 63, wave = tid >> 6;
  const int wr = wave >> 1, wc = wave & 1;
  const int l15 = lane & 15, l16 = lane >> 4;
  const int row0 = blockIdx.y * 128, col0 = blockIdx.x * 128;
  f32x4 acc[4][4] = {};
  for (int k0 = 0; k0 < K; k0 += 32) {
    stage_hl(A + (size_t)row0 * K + k0, K, Ah, Al, tid);
    stage_hl(B + (size_t)col0 * K + k0, K, Bh, Bl, tid);
    __syncthreads();
    short8 ah[4], al[4], bh[4], bl[4];
#pragma unroll
    for (int mi = 0; mi < 4; ++mi) {
      ah[mi] = *(short8*)&Ah[(wr * 64 + mi * 16 + l15) * 48 + l16 * 8];
      al[mi] = *(short8*)&Al[(wr * 64 + mi * 16 + l15) * 48 + l16 * 8];
    }
#pragma unroll
    for (int ni = 0; ni < 4; ++ni) {
      bh[ni] = *(short8*)&Bh[(wc * 64 + ni * 16 + l15) * 48 + l16 * 8];
      bl[ni] = *(short8*)&Bl[(wc * 64 + ni * 16 + l15) * 48 + l16 * 8];
    }
#pragma unroll
    for (int mi = 0; mi < 4; ++mi)
#pragma unroll
      for (int ni = 0; ni < 4; ++ni) {
        acc[mi][ni] = __builtin_amdgcn_mfma_f32_16x16x32_bf16(ah[mi], bh[ni], acc[mi][ni], 0, 0, 0);
        acc[mi][ni] = __builtin_amdgcn_mfma_f32_16x16x32_bf16(ah[mi], bl[ni], acc[mi][ni], 0, 0, 0);
        acc[mi][ni] = __builtin_amdgcn_mfma_f32_16x16x32_bf16(al[mi], bh[ni], acc[mi][ni], 0, 0, 0);
      }
    __syncthreads();
  }
#pragma unroll
  for (int mi = 0; mi < 4; ++mi) {
#pragma unroll
    for (int ni = 0; ni < 4; ++ni) {
      int rr = row0 + wr * 64 + mi * 16 + l16 * 4;
      int cc = col0 + wc * 64 + ni * 16 + l15;
#pragma unroll
      for (int i = 0; i < 4; ++i) {
        float v = acc[mi][ni][i];
        size_t idx = (size_t)(rr + i) * N + cc;
        if constexpr (MODE == 0) {
          ((float*)C0)[idx] = v;
        } else if constexpr (MODE == 2) {
          float zs = v * sigm(v);  // silu(z)
          float o = e0[idx] * e1[(size_t)(rr + i) * 32 + (cc >> 7)] * e2[cc & 127] * zs;
          ((float*)C0)[idx] = o;
        } else {  // MODE 3: split qk / v
          if (cc < 4096) ((float*)C0)[(size_t)(rr + i) * 4096 + cc] = v;
          else ((float*)C1)[(size_t)(rr + i) * 4096 + (cc - 4096)] = v;
        }
      }
    }
  }
}

// ---------------- beta / g from ba [BT,128] f32, TRANSPOSED out [32][4096] ----------------
__global__ __launch_bounds__(256) void k_bg(const float* __restrict__ ba, const float* __restrict__ dt_bias,
                                            const float* __restrict__ A_log, float* __restrict__ beta_t,
                                            float* __restrict__ g_t) {
  int i = blockIdx.x * 256 + threadIdx.x;  // 0..131071
  int bt = i >> 5, h = i & 31;
  float bv = ba[(size_t)bt * 128 + h];
  float av = ba[(size_t)bt * 128 + 32 + h];
  beta_t[h * 4096 + bt] = sigm(bv);
  float xx = av + dt_bias[h];
  float sp = (xx > 20.f) ? xx : log1pf(__expf(xx));
  g_t[h * 4096 + bt] = -__expf(A_log[h]) * sp;
}

// ---------------- conv+SiLU+L2norm for q,k: f32 in [2048][4096] -> f32 out [2048][4096] ----------------
__global__ __launch_bounds__(256) void k_convqk(const float* __restrict__ qkraw, const float* __restrict__ cw,
                                                float* __restrict__ qkn) {
  __shared__ float sval[4096];
  __shared__ float snrm[32];
  const int tid = threadIdx.x;
  const int t = blockIdx.x;
  for (int i = 0; i < 16; ++i) {
    int c = i * 256 + tid;  // 0..4095 (q:0-2047, k:2048-4095)
    float acc = 0.f;
#pragma unroll
    for (int j = 0; j < 4; ++j) {
      int ts = t - 3 + j;
      if (ts >= 0) acc += cw[c * 4 + j] * qkraw[(size_t)ts * 4096 + c];
    }
    sval[c] = acc * sigm(acc);
  }
  __syncthreads();
  {
    int gidx = tid >> 3, s = tid & 7;  // 32 groups (16 hk x {q,k}) x 8 threads
    float ss = 0.f;
#pragma unroll
    for (int i2 = 0; i2 < 16; ++i2) { float v = sval[gidx * 128 + s * 16 + i2]; ss += v * v; }
    ss += __shfl_xor(ss, 1); ss += __shfl_xor(ss, 2); ss += __shfl_xor(ss, 4);
    if (s == 0) snrm[gidx] = 1.0f / fmaxf(sqrtf(ss), 1e-12f);
  }
  __syncthreads();
  for (int i = 0; i < 16; ++i) {
    int c = i * 256 + tid;
    qkn[(size_t)t * 4096 + c] = sval[c] * snrm[c >> 7];
  }
}

// ---------------- chunked gated-linear-attention scan, MFMA, hi/lo-compensated ----------------
// grid 128 = dq(4) x h(32) per batch; block 256 (4 waves). Chunk L=64, 32 chunks sequential.
// out_t = e^{Gc[t]} q_t S_prev + sum_{s<=t} e^{Gc[t]-Gc[s]} beta_s (q_t.k_s) v_s
// S_new = e^{Gc[63]} S_prev + sum_s e^{Gc[63]-Gc[s]} beta_s k_s v_s^T
__global__ __launch_bounds__(256) void k_scanc(const float* __restrict__ qkn, const float* __restrict__ vraw,
                                               const float* __restrict__ cw,
                                               const float* __restrict__ beta_t, const float* __restrict__ g_t,
                                               float* __restrict__ outr, int b) {
  __shared__ __align__(16) u16 Qh[64][136], Ql[64][136], Kh[64][136], Kl[64][136];
  __shared__ __align__(16) u16 Vh[32][72], Vl[32][72];
  __shared__ __align__(16) u16 SIh[64][72], SIl[64][72];
  __shared__ __align__(16) float Stl[2][32][132];
  __shared__ float rv[67][33];
  __shared__ float garr[64], barr[64], warr[64], earr[64];
  __shared__ float sdt;

  const int tid = threadIdx.x;
  const int lane = tid & 63, wv = tid >> 6;
  const int l15 = lane & 15, l16 = lane >> 4;
  const int dq = blockIdx.x & 3, h = blockIdx.x >> 2;
  const int hk = h >> 1;
  const int dvl = tid & 31;
  const int vch = h * 128 + dq * 32;  // within 4096-wide v buffer
  const float4 cwv = *(const float4*)&cw[(4096 + vch + dvl) * 4];
  const int m0 = wv * 16;

  for (int i = tid; i < 2 * 32 * 132; i += 256) ((float*)Stl)[i] = 0.f;
  f32x4 st[2][2] = {};  // state frags [dv-block m][dk-sub n2]; wave dk band = wv*32

  for (int ch = 0; ch < NCH; ++ch) {
    const int t0 = ch * CL;
    const int p = ch & 1;
    // ---- stage Q,K f32 -> hi/lo bf16 tiles (64 x 128)
    {
      int sr = tid >> 2, d0 = (tid & 3) * 32;
      const float* qg = qkn + (size_t)(t0 + sr) * 4096 + hk * 128 + d0;
      const float* kg = qg + 2048;
#pragma unroll
      for (int pp = 0; pp < 8; ++pp) {
        float4 qv = *(const float4*)&qg[pp * 4];
        float4 kv = *(const float4*)&kg[pp * 4];
        ushort4 qh4, ql4, kh4, kl4;
        qh4.x = f2bf(qv.x); ql4.x = f2bf(qv.x - bf2f(qh4.x));
        qh4.y = f2bf(qv.y); ql4.y = f2bf(qv.y - bf2f(qh4.y));
        qh4.z = f2bf(qv.z); ql4.z = f2bf(qv.z - bf2f(qh4.z));
        qh4.w = f2bf(qv.w); ql4.w = f2bf(qv.w - bf2f(qh4.w));
        kh4.x = f2bf(kv.x); kl4.x = f2bf(kv.x - bf2f(kh4.x));
        kh4.y = f2bf(kv.y); kl4.y = f2bf(kv.y - bf2f(kh4.y));
        kh4.z = f2bf(kv.z); kl4.z = f2bf(kv.z - bf2f(kh4.z));
        kh4.w = f2bf(kv.w); kl4.w = f2bf(kv.w - bf2f(kh4.w));
        *(ushort4*)&Qh[sr][d0 + pp * 4] = qh4;
        *(ushort4*)&Ql[sr][d0 + pp * 4] = ql4;
        *(ushort4*)&Kh[sr][d0 + pp * 4] = kh4;
        *(ushort4*)&Kl[sr][d0 + pp * 4] = kl4;
      }
    }
    // ---- raw v rows t0-3..t0+63
    for (int r = tid >> 5; r < 67; r += 8) {
      int tr = t0 - 3 + r;
      rv[r][dvl] = (tr >= 0) ? vraw[(size_t)tr * 4096 + vch + dvl] : 0.f;
    }
    // ---- cumsum of g, beta (wave 0)
    if (wv == 0) {
      float gv = g_t[h * 4096 + b * 2048 + t0 + lane];
      float bv = beta_t[h * 4096 + b * 2048 + t0 + lane];
      float cum = gv;
#pragma unroll
      for (int off = 1; off < 64; off <<= 1) {
        float o = __shfl_up(cum, off);
        if (lane >= off) cum += o;
      }
      float tot = __shfl(cum, 63);
      garr[lane] = cum;
      earr[lane] = __expf(cum);
      warr[lane] = __expf(tot - cum) * bv;
      barr[lane] = bv;
      if (lane == 0) sdt = __expf(tot);
    }
    __syncthreads();  // B1
    // ---- v conv + silu -> hi/lo transposed [dv][s]
    {
      int tl = tid >> 5;
#pragma unroll
      for (int rr = 0; rr < 8; ++rr) {
        int t = rr * 8 + tl;
        float a = cwv.x * rv[t][dvl] + cwv.y * rv[t + 1][dvl] + cwv.z * rv[t + 2][dvl] + cwv.w * rv[t + 3][dvl];
        a = a * sigm(a);
        u16 hi = f2bf(a);
        Vh[dvl][t] = hi;
        Vl[dvl][t] = f2bf(a - bf2f(hi));
      }
    }
    // ---- A = Q K^T (hi/lo, 3 terms), mask -> SIh/SIl
    short8 ah[4], al[4];
#pragma unroll
    for (int kk = 0; kk < 4; ++kk) {
      ah[kk] = *(short8*)&Qh[m0 + l15][l16 * 8 + kk * 32];
      al[kk] = *(short8*)&Ql[m0 + l15][l16 * 8 + kk * 32];
    }
#pragma unroll
    for (int n = 0; n < 4; ++n) {
      f32x4 a4 = {};
#pragma unroll
      for (int kk = 0; kk < 4; ++kk) {
        short8 bh_ = *(short8*)&Kh[n * 16 + l15][l16 * 8 + kk * 32];
        short8 bl_ = *(short8*)&Kl[n * 16 + l15][l16 * 8 + kk * 32];
        a4 = __builtin_amdgcn_mfma_f32_16x16x32_bf16(ah[kk], bh_, a4, 0, 0, 0);
        a4 = __builtin_amdgcn_mfma_f32_16x16x32_bf16(ah[kk], bl_, a4, 0, 0, 0);
        a4 = __builtin_amdgcn_mfma_f32_16x16x32_bf16(al[kk], bh_, a4, 0, 0, 0);
      }
      int col = n * 16 + l15;
      float gc = garr[col], bc = barr[col];
#pragma unroll
      for (int i = 0; i < 4; ++i) {
        int row = m0 + l16 * 4 + i;
        float cval = (col <= row) ? __expf(garr[row] - gc) * bc * a4[i] : 0.f;
        u16 hh = f2bf(cval);
        SIh[row][col] = hh;
        SIl[row][col] = f2bf(cval - bf2f(hh));
      }
    }
    __syncthreads();  // B2
    // ---- out_inter = Q @ St_prev (Q hi/lo x S hi/lo, 3 terms), scaled by e^{Gc[t]}
    f32x4 ao[2] = {};
#pragma unroll
    for (int n = 0; n < 2; ++n) {
#pragma unroll
      for (int kk = 0; kk < 4; ++kk) {
        const float* sp_ = &Stl[p][n * 16 + l15][l16 * 8 + kk * 32];
        short8 sh8, sl8;
#pragma unroll
        for (int e = 0; e < 8; ++e) {
          float sv = sp_[e];
          u16 hh = f2bf(sv);
          sh8[e] = (short)hh;
          sl8[e] = (short)f2bf(sv - bf2f(hh));
        }
        ao[n] = __builtin_amdgcn_mfma_f32_16x16x32_bf16(ah[kk], sh8, ao[n], 0, 0, 0);
        ao[n] = __builtin_amdgcn_mfma_f32_16x16x32_bf16(ah[kk], sl8, ao[n], 0, 0, 0);
        ao[n] = __builtin_amdgcn_mfma_f32_16x16x32_bf16(al[kk], sh8, ao[n], 0, 0, 0);
      }
    }
#pragma unroll
    for (int n = 0; n < 2; ++n)
#pragma unroll
      for (int i = 0; i < 4; ++i) ao[n][i] *= earr[m0 + l16 * 4 + i];
    // ---- out += SI @ V (3 terms)
#pragma unroll
    for (int kk = 0; kk < 2; ++kk) {
      short8 asih = *(short8*)&SIh[m0 + l15][l16 * 8 + kk * 32];
      short8 asil = *(short8*)&SIl[m0 + l15][l16 * 8 + kk * 32];
#pragma unroll
      for (int n = 0; n < 2; ++n) {
        short8 bvh = *(short8*)&Vh[n * 16 + l15][l16 * 8 + kk * 32];
        short8 bvl = *(short8*)&Vl[n * 16 + l15][l16 * 8 + kk * 32];
        ao[n] = __builtin_amdgcn_mfma_f32_16x16x32_bf16(asih, bvh, ao[n], 0, 0, 0);
        ao[n] = __builtin_amdgcn_mfma_f32_16x16x32_bf16(asih, bvl, ao[n], 0, 0, 0);
        ao[n] = __builtin_amdgcn_mfma_f32_16x16x32_bf16(asil, bvh, ao[n], 0, 0, 0);
      }
    }
    // ---- write out rows
#pragma unroll
    for (int n = 0; n < 2; ++n)
#pragma unroll
      for (int i = 0; i < 4; ++i)
        outr[(size_t)(b * 2048 + t0 + m0 + l16 * 4 + i) * 4096 + vch + n * 16 + l15] = ao[n][i];
    // ---- state update: St = sdt*St + V^T (K.w), k from f32 (hi+lo), 3 terms
#pragma unroll
    for (int m = 0; m < 2; ++m)
#pragma unroll
      for (int n2 = 0; n2 < 2; ++n2)
#pragma unroll
        for (int i = 0; i < 4; ++i) st[m][n2][i] *= sdt;
#pragma unroll
    for (int kk = 0; kk < 2; ++kk) {
      short8 bwh[2], bwl[2];
#pragma unroll
      for (int n2 = 0; n2 < 2; ++n2) {
        int dk = wv * 32 + n2 * 16 + l15;
#pragma unroll
        for (int e = 0; e < 8; ++e) {
          int s = l16 * 8 + e + kk * 32;
          float kvv = (bf2f(Kh[s][dk]) + bf2f(Kl[s][dk])) * warr[s];
          u16 hh = f2bf(kvv);
          bwh[n2][e] = (short)hh;
          bwl[n2][e] = (short)f2bf(kvv - bf2f(hh));
        }
      }
#pragma unroll
      for (int m = 0; m < 2; ++m) {
        short8 avh = *(short8*)&Vh[m * 16 + l15][l16 * 8 + kk * 32];
        short8 avl = *(short8*)&Vl[m * 16 + l15][l16 * 8 + kk * 32];
#pragma unroll
        for (int n2 = 0; n2 < 2; ++n2) {
          st[m][n2] = __builtin_amdgcn_mfma_f32_16x16x32_bf16(avh, bwh[n2], st[m][n2], 0, 0, 0);
          st[m][n2] = __builtin_amdgcn_mfma_f32_16x16x32_bf16(avh, bwl[n2], st[m][n2], 0, 0, 0);
          st[m][n2] = __builtin_amdgcn_mfma_f32_16x16x32_bf16(avl, bwh[n2], st[m][n2], 0, 0, 0);
        }
      }
    }
    // ---- write state for next chunk
#pragma unroll
    for (int m = 0; m < 2; ++m)
#pragma unroll
      for (int n2 = 0; n2 < 2; ++n2)
#pragma unroll
        for (int i = 0; i < 4; ++i)
          Stl[p ^ 1][m * 16 + l16 * 4 + i][wv * 32 + n2 * 16 + l15] = st[m][n2][i];
    __syncthreads();  // B4
  }
}

// ---------------- per-(bt,head) RMS scale from f32 outr ----------------
__global__ __launch_bounds__(256) void k_rms(const float* __restrict__ outr, float* __restrict__ rms) {
  int pair = blockIdx.x * 4 + (threadIdx.x >> 6);
  int lane = threadIdx.x & 63;
  float2 v = *(const float2*)&outr[(size_t)pair * 128 + lane * 2];
  float ss = v.x * v.x + v.y * v.y;
#pragma unroll
  for (int m = 1; m < 64; m <<= 1) ss += __shfl_xor(ss, m);
  if (lane == 0) rms[pair] = rsqrtf(ss * (1.0f / 128.0f) + 1e-6f);
}

extern "C" void kernel_launch(void* const* d_in, const int* in_sizes, int n_in,
                              void* d_out, int out_size, void* d_ws, size_t ws_size,
                              hipStream_t stream) {
  const float* x = (const float*)d_in[0];
  // d_in[1] = positions (int64) — unused by the math
  const float* W_qkv = (const float*)d_in[2];
  const float* W_z = (const float*)d_in[3];
  const float* W_b = (const float*)d_in[4];
  const float* W_a = (const float*)d_in[5];
  const float* conv_w = (const float*)d_in[6];
  const float* dt_bias = (const float*)d_in[7];
  const float* A_log = (const float*)d_in[8];
  const float* norm_w = (const float*)d_in[9];
  const float* W_out = (const float*)d_in[10];
  float* out = (float*)d_out;

  const size_t S_H = (size_t)NT * 4096 * 4;   // 32 MiB: one [2048][4096] f32 buffer
  const size_t S_O = (size_t)NBT * VALD * 4;  // 64 MiB: outr f32
  const size_t S_SM = (size_t)NBT * 32 * 4;   // 0.5 MiB each

  const size_t need = 3 * S_H + S_O + 3 * S_SM;  // ~161.5 MiB (proven: ws >= 193.5 MiB)
  if (ws_size < need) {  // loud, distinguishable failure: absmax ~1e6
    k_sentinel<<<1, 1, 0, stream>>>(out);
    return;
  }
  char* ws = (char*)d_ws;
  float* qkA = (float*)ws;                    // raw qk per batch; part of omat later
  float* qkB = (float*)(ws + S_H);            // conv'd+normed qk per batch; part of omat later
  float* vbuf = (float*)(ws + 2 * S_H);       // raw v per batch
  char* regO = ws + 3 * S_H;
  float* outr = (float*)regO;
  float* beta_t = (float*)(regO + S_O);
  float* g_t = beta_t + NBT * 32;
  float* rmsb = g_t + NBT * 32;
  float* omat = qkA;                          // overlays qkA+qkB (64 MiB, dead after scans)
  float* wba = (float*)regO;                  // overlays outr (dead before outr writes)
  float* babuf = (float*)(regO + (1 << 20));

  // --- b/a path ---
  k_wba<<<128 * NC / 256, 256, 0, stream>>>(W_b, W_a, wba);
  k_gemm_hl<0><<<dim3(1, NBT / 128), 256, 0, stream>>>(x, wba, babuf, nullptr, NBT, 128, NC,
                                                       nullptr, nullptr, nullptr);
  k_bg<<<NBT * 32 / 256, 256, 0, stream>>>(babuf, dt_bias, A_log, beta_t, g_t);

  // --- per-batch: qkv projection (split) -> conv q/k (f32) -> chunked scan ---
  for (int b = 0; b < NB; ++b) {
    k_gemm_hl<3><<<dim3(QKVD / 128, NT / 128), 256, 0, stream>>>(x + (size_t)b * NT * NC, W_qkv,
                                                                 qkA, vbuf, NT, QKVD, NC,
                                                                 nullptr, nullptr, nullptr);
    k_convqk<<<NT, 256, 0, stream>>>(qkA, conv_w, qkB);
    k_scanc<<<128, 256, 0, stream>>>(qkB, vbuf, conv_w, beta_t, g_t, outr, b);
  }

  k_rms<<<NBT * NHV / 4, 256, 0, stream>>>(outr, rmsb);

  // z projection with fused gated-RMSNorm epilogue -> f32 omat (overlays qkA/qkB)
  k_gemm_hl<2><<<dim3(VALD / 128, NBT / 128), 256, 0, stream>>>(x, W_z, omat, nullptr, NBT, VALD, NC,
                                                                outr, rmsb, norm_w);

  // output projection -> f32 out
  k_gemm_hl<0><<<dim3(NC / 128, NBT / 128), 256, 0, stream>>>(omat, W_out, out, nullptr, NBT, NC, VALD,
                                                              nullptr, nullptr, nullptr);
}

// Round 7
// 1542.191 us; speedup vs baseline: 1.9445x; 1.2428x over previous
//
#include <hip/hip_runtime.h>

typedef unsigned short u16;
typedef unsigned int u32;
typedef __attribute__((ext_vector_type(8))) short short8;
typedef __attribute__((ext_vector_type(4))) float f32x4;

#define NB 2
#define NT 2048
#define NC 2048
#define NHV 32
#define KEYD 2048
#define VALD 4096
#define QKVD 8192
#define NBT 4096
#define CL 64
#define NCH (NT / CL)

static __device__ __forceinline__ float bf2f(u16 u) {
  union { u32 u; float f; } x; x.u = ((u32)u) << 16; return x.f;
}
static __device__ __forceinline__ u16 f2bf(float f) {
  union { float f; u32 u; } x; x.f = f;
  u32 r = x.u + 0x7fffu + ((x.u >> 16) & 1u);
  return (u16)(r >> 16);
}
static __device__ __forceinline__ float sigm(float x) { return 1.0f / (1.0f + __expf(-x)); }

// ---------------- sentinel: ws too small marker ----------------
__global__ void k_sentinel(float* out) { out[0] = 1.0e6f; }

// ---------------- build padded W_ba f32 [128][2048] ----------------
__global__ __launch_bounds__(256) void k_wba(const float* __restrict__ Wb, const float* __restrict__ Wa,
                                             float* __restrict__ out) {
  int i = blockIdx.x * 256 + threadIdx.x;
  int r = i >> 11, c = i & 2047;
  float v = 0.f;
  if (r < 32) v = Wb[r * 2048 + c];
  else if (r < 64) v = Wa[(r - 32) * 2048 + c];
  out[i] = v;
}

// ---------------- hi/lo staging: f32 [128 x 32] tile -> bf16 hi + bf16 lo, stride 48 ----------------
static __device__ __forceinline__ void stage_hl(const float* __restrict__ src, int ld,
                                                u16* hi, u16* lo, int tid) {
  const int r0 = tid >> 3, kq = (tid & 7) * 4;
#pragma unroll
  for (int p = 0; p < 4; ++p) {
    int r = p * 32 + r0;
    float4 v = *(const float4*)&src[(size_t)r * ld + kq];
    ushort4 h, l;
    h.x = f2bf(v.x); l.x = f2bf(v.x - bf2f(h.x));
    h.y = f2bf(v.y); l.y = f2bf(v.y - bf2f(h.y));
    h.z = f2bf(v.z); l.z = f2bf(v.z - bf2f(h.z));
    h.w = f2bf(v.w); l.w = f2bf(v.w - bf2f(h.w));
    *(ushort4*)&hi[r * 48 + kq] = h;
    *(ushort4*)&lo[r * 48 + kq] = l;
  }
}

// ---------------- hi/lo GEMM: C[M][N] = A[M][K] * B[N][K]^T, ~f32 precision via 3 bf16 MFMA passes ----
// MODE 0: f32 out C0. MODE 2: z epilogue: C0 = e0(outr)*e1(rms)*e2(nw)*silu(acc).
// MODE 3: split: cols<4096 -> C0, cols>=4096 -> C1 (both f32 width 4096).
template <int MODE>
__global__ __launch_bounds__(256) void k_gemm_hl(const float* __restrict__ A, const float* __restrict__ B,
                                                 void* __restrict__ C0, void* __restrict__ C1,
                                                 int M, int N, int K,
                                                 const float* __restrict__ e0, const float* __restrict__ e1,
                                                 const float* __restrict__ e2) {
  __shared__ __align__(16) u16 Ah[128 * 48];
  __shared__ __align__(16) u16 Al[128 * 48];
  __shared__ __align__(16) u16 Bh[128 * 48];
  __shared__ __align__(16) u16 Bl[128 * 48];
  const int tid = threadIdx.x;
  const int lane = tid & 63, wave = tid >> 6;
  const int wr = wave >> 1, wc = wave & 1;
  const int l15 = lane & 15, l16 = lane >> 4;
  const int row0 = blockIdx.y * 128, col0 = blockIdx.x * 128;
  f32x4 acc[4][4] = {};
  for (int k0 = 0; k0 < K; k0 += 32) {
    stage_hl(A + (size_t)row0 * K + k0, K, Ah, Al, tid);
    stage_hl(B + (size_t)col0 * K + k0, K, Bh, Bl, tid);
    __syncthreads();
    short8 ah[4], al[4], bh[4], bl[4];
#pragma unroll
    for (int mi = 0; mi < 4; ++mi) {
      ah[mi] = *(short8*)&Ah[(wr * 64 + mi * 16 + l15) * 48 + l16 * 8];
      al[mi] = *(short8*)&Al[(wr * 64 + mi * 16 + l15) * 48 + l16 * 8];
    }
#pragma unroll
    for (int ni = 0; ni < 4; ++ni) {
      bh[ni] = *(short8*)&Bh[(wc * 64 + ni * 16 + l15) * 48 + l16 * 8];
      bl[ni] = *(short8*)&Bl[(wc * 64 + ni * 16 + l15) * 48 + l16 * 8];
    }
#pragma unroll
    for (int mi = 0; mi < 4; ++mi)
#pragma unroll
      for (int ni = 0; ni < 4; ++ni) {
        acc[mi][ni] = __builtin_amdgcn_mfma_f32_16x16x32_bf16(ah[mi], bh[ni], acc[mi][ni], 0, 0, 0);
        acc[mi][ni] = __builtin_amdgcn_mfma_f32_16x16x32_bf16(ah[mi], bl[ni], acc[mi][ni], 0, 0, 0);
        acc[mi][ni] = __builtin_amdgcn_mfma_f32_16x16x32_bf16(al[mi], bh[ni], acc[mi][ni], 0, 0, 0);
      }
    __syncthreads();
  }
#pragma unroll
  for (int mi = 0; mi < 4; ++mi) {
#pragma unroll
    for (int ni = 0; ni < 4; ++ni) {
      int rr = row0 + wr * 64 + mi * 16 + l16 * 4;
      int cc = col0 + wc * 64 + ni * 16 + l15;
#pragma unroll
      for (int i = 0; i < 4; ++i) {
        float v = acc[mi][ni][i];
        size_t idx = (size_t)(rr + i) * N + cc;
        if constexpr (MODE == 0) {
          ((float*)C0)[idx] = v;
        } else if constexpr (MODE == 2) {
          float zs = v * sigm(v);  // silu(z)
          float o = e0[idx] * e1[(size_t)(rr + i) * 32 + (cc >> 7)] * e2[cc & 127] * zs;
          ((float*)C0)[idx] = o;
        } else {  // MODE 3: split qk / v
          if (cc < 4096) ((float*)C0)[(size_t)(rr + i) * 4096 + cc] = v;
          else ((float*)C1)[(size_t)(rr + i) * 4096 + (cc - 4096)] = v;
        }
      }
    }
  }
}

// ---------------- beta / g from ba [BT,128] f32, TRANSPOSED out [32][4096] ----------------
__global__ __launch_bounds__(256) void k_bg(const float* __restrict__ ba, const float* __restrict__ dt_bias,
                                            const float* __restrict__ A_log, float* __restrict__ beta_t,
                                            float* __restrict__ g_t) {
  int i = blockIdx.x * 256 + threadIdx.x;  // 0..131071
  int bt = i >> 5, h = i & 31;
  float bv = ba[(size_t)bt * 128 + h];
  float av = ba[(size_t)bt * 128 + 32 + h];
  beta_t[h * 4096 + bt] = sigm(bv);
  float xx = av + dt_bias[h];
  float sp = (xx > 20.f) ? xx : log1pf(__expf(xx));
  g_t[h * 4096 + bt] = -__expf(A_log[h]) * sp;
}

// ---------------- conv+SiLU+L2norm for q,k: f32 in [4096][4096] -> f32 out [4096][4096] ----------------
// one block per global bt; causal within batch
__global__ __launch_bounds__(256) void k_convqk(const float* __restrict__ qkraw, const float* __restrict__ cw,
                                                float* __restrict__ qkn) {
  __shared__ float sval[4096];
  __shared__ float snrm[32];
  const int tid = threadIdx.x;
  const int bt = blockIdx.x;
  const int b = bt >> 11, t = bt & 2047;
  for (int i = 0; i < 16; ++i) {
    int c = i * 256 + tid;  // 0..4095 (q:0-2047, k:2048-4095)
    float acc = 0.f;
#pragma unroll
    for (int j = 0; j < 4; ++j) {
      int ts = t - 3 + j;
      if (ts >= 0) acc += cw[c * 4 + j] * qkraw[(size_t)(b * 2048 + ts) * 4096 + c];
    }
    sval[c] = acc * sigm(acc);
  }
  __syncthreads();
  {
    int gidx = tid >> 3, s = tid & 7;  // 32 groups (16 hk x {q,k}) x 8 threads
    float ss = 0.f;
#pragma unroll
    for (int i2 = 0; i2 < 16; ++i2) { float v = sval[gidx * 128 + s * 16 + i2]; ss += v * v; }
    ss += __shfl_xor(ss, 1); ss += __shfl_xor(ss, 2); ss += __shfl_xor(ss, 4);
    if (s == 0) snrm[gidx] = 1.0f / fmaxf(sqrtf(ss), 1e-12f);
  }
  __syncthreads();
  for (int i = 0; i < 16; ++i) {
    int c = i * 256 + tid;
    qkn[(size_t)bt * 4096 + c] = sval[c] * snrm[c >> 7];
  }
}

// ---------------- chunked gated-linear-attention scan, MFMA, hi/lo-compensated ----------------
// grid 256 = dq(4) x h(32) x b(2); block 256 (4 waves). Chunk L=64, 32 chunks sequential.
// out_t = e^{Gc[t]} q_t S_prev + sum_{s<=t} e^{Gc[t]-Gc[s]} beta_s (q_t.k_s) v_s
// S_new = e^{Gc[63]} S_prev + sum_s e^{Gc[63]-Gc[s]} beta_s k_s v_s^T
// Global loads for chunk ch+1 are register-prefetched during chunk ch's compute (T14).
__global__ __launch_bounds__(256) void k_scanc(const float* __restrict__ qkn, const float* __restrict__ vraw,
                                               const float* __restrict__ cw,
                                               const float* __restrict__ beta_t, const float* __restrict__ g_t,
                                               float* __restrict__ outr) {
  __shared__ __align__(16) u16 Qh[64][136], Ql[64][136], Kh[64][136], Kl[64][136];
  __shared__ __align__(16) u16 Vh[32][72], Vl[32][72];
  __shared__ __align__(16) u16 SIh[64][72], SIl[64][72];
  __shared__ __align__(16) float Stl[2][32][132];
  __shared__ float rv[67][33];
  __shared__ float garr[64], barr[64], warr[64], earr[64];
  __shared__ float sdt;

  const int tid = threadIdx.x;
  const int lane = tid & 63, wv = tid >> 6;
  const int l15 = lane & 15, l16 = lane >> 4;
  const int dq = blockIdx.x & 3, h = (blockIdx.x >> 2) & 31, b = blockIdx.x >> 7;
  const int bT = b * 2048;
  const int hk = h >> 1;
  const int dvl = tid & 31;
  const int vch = h * 128 + dq * 32;  // within 4096-wide v buffer
  const float4 cwv = *(const float4*)&cw[(4096 + vch + dvl) * 4];
  const int m0 = wv * 16;
  const int sr = tid >> 2, d0 = (tid & 3) * 32;  // qk staging map
  const int r0v = tid >> 5;                       // v staging map

  for (int i = tid; i < 2 * 32 * 132; i += 256) ((float*)Stl)[i] = 0.f;
  f32x4 st[2][2] = {};  // state frags [dv-block m][dk-sub n2]; wave dk band = wv*32

  // ---- register prefetch buffers ----
  float4 pq[8], pk[8];
  float pv[9];
  auto LOADQK = [&](int t0) {
    const float* qg = qkn + (size_t)(bT + t0 + sr) * 4096 + hk * 128 + d0;
#pragma unroll
    for (int pp = 0; pp < 8; ++pp) {
      pq[pp] = *(const float4*)&qg[pp * 4];
      pk[pp] = *(const float4*)&qg[2048 + pp * 4];
    }
  };
  auto LOADV = [&](int t0) {
#pragma unroll
    for (int i = 0; i < 9; ++i) {
      int r = r0v + i * 8;
      int tr = t0 - 3 + r;
      pv[i] = (r < 67 && tr >= 0) ? vraw[(size_t)(bT + tr) * 4096 + vch + dvl] : 0.f;
    }
  };

  LOADQK(0);
  LOADV(0);

  for (int ch = 0; ch < NCH; ++ch) {
    const int t0 = ch * CL;
    const int p = ch & 1;
    // ---- write prefetched Q,K (f32 -> hi/lo bf16) and raw v rows to LDS
#pragma unroll
    for (int pp = 0; pp < 8; ++pp) {
      float4 qv = pq[pp], kv = pk[pp];
      ushort4 qh4, ql4, kh4, kl4;
      qh4.x = f2bf(qv.x); ql4.x = f2bf(qv.x - bf2f(qh4.x));
      qh4.y = f2bf(qv.y); ql4.y = f2bf(qv.y - bf2f(qh4.y));
      qh4.z = f2bf(qv.z); ql4.z = f2bf(qv.z - bf2f(qh4.z));
      qh4.w = f2bf(qv.w); ql4.w = f2bf(qv.w - bf2f(qh4.w));
      kh4.x = f2bf(kv.x); kl4.x = f2bf(kv.x - bf2f(kh4.x));
      kh4.y = f2bf(kv.y); kl4.y = f2bf(kv.y - bf2f(kh4.y));
      kh4.z = f2bf(kv.z); kl4.z = f2bf(kv.z - bf2f(kh4.z));
      kh4.w = f2bf(kv.w); kl4.w = f2bf(kv.w - bf2f(kh4.w));
      *(ushort4*)&Qh[sr][d0 + pp * 4] = qh4;
      *(ushort4*)&Ql[sr][d0 + pp * 4] = ql4;
      *(ushort4*)&Kh[sr][d0 + pp * 4] = kh4;
      *(ushort4*)&Kl[sr][d0 + pp * 4] = kl4;
    }
#pragma unroll
    for (int i = 0; i < 9; ++i) {
      int r = r0v + i * 8;
      if (r < 67) rv[r][dvl] = pv[i];
    }
    // ---- cumsum of g, beta (wave 0)
    if (wv == 0) {
      float gv = g_t[h * 4096 + bT + t0 + lane];
      float bv = beta_t[h * 4096 + bT + t0 + lane];
      float cum = gv;
#pragma unroll
      for (int off = 1; off < 64; off <<= 1) {
        float o = __shfl_up(cum, off);
        if (lane >= off) cum += o;
      }
      float tot = __shfl(cum, 63);
      garr[lane] = cum;
      earr[lane] = __expf(cum);
      warr[lane] = __expf(tot - cum) * bv;
      barr[lane] = bv;
      if (lane == 0) sdt = __expf(tot);
    }
    __syncthreads();  // B1
    // ---- prefetch next chunk (latency hides under compute below)
    if (ch + 1 < NCH) {
      LOADQK(t0 + CL);
      LOADV(t0 + CL);
    }
    // ---- v conv + silu -> hi/lo transposed [dv][s]
    {
      int tl = tid >> 5;
#pragma unroll
      for (int rr = 0; rr < 8; ++rr) {
        int t = rr * 8 + tl;
        float a = cwv.x * rv[t][dvl] + cwv.y * rv[t + 1][dvl] + cwv.z * rv[t + 2][dvl] + cwv.w * rv[t + 3][dvl];
        a = a * sigm(a);
        u16 hi = f2bf(a);
        Vh[dvl][t] = hi;
        Vl[dvl][t] = f2bf(a - bf2f(hi));
      }
    }
    // ---- A = Q K^T (hi/lo, 3 terms), mask -> SIh/SIl
    short8 ah[4], al[4];
#pragma unroll
    for (int kk = 0; kk < 4; ++kk) {
      ah[kk] = *(short8*)&Qh[m0 + l15][l16 * 8 + kk * 32];
      al[kk] = *(short8*)&Ql[m0 + l15][l16 * 8 + kk * 32];
    }
#pragma unroll
    for (int n = 0; n < 4; ++n) {
      f32x4 a4 = {};
#pragma unroll
      for (int kk = 0; kk < 4; ++kk) {
        short8 bh_ = *(short8*)&Kh[n * 16 + l15][l16 * 8 + kk * 32];
        short8 bl_ = *(short8*)&Kl[n * 16 + l15][l16 * 8 + kk * 32];
        a4 = __builtin_amdgcn_mfma_f32_16x16x32_bf16(ah[kk], bh_, a4, 0, 0, 0);
        a4 = __builtin_amdgcn_mfma_f32_16x16x32_bf16(ah[kk], bl_, a4, 0, 0, 0);
        a4 = __builtin_amdgcn_mfma_f32_16x16x32_bf16(al[kk], bh_, a4, 0, 0, 0);
      }
      int col = n * 16 + l15;
      float gc = garr[col], bc = barr[col];
#pragma unroll
      for (int i = 0; i < 4; ++i) {
        int row = m0 + l16 * 4 + i;
        float cval = (col <= row) ? __expf(garr[row] - gc) * bc * a4[i] : 0.f;
        u16 hh = f2bf(cval);
        SIh[row][col] = hh;
        SIl[row][col] = f2bf(cval - bf2f(hh));
      }
    }
    __syncthreads();  // B2
    // ---- out_inter = Q @ St_prev (Q hi/lo x S hi/lo, 3 terms), scaled by e^{Gc[t]}
    f32x4 ao[2] = {};
#pragma unroll
    for (int n = 0; n < 2; ++n) {
#pragma unroll
      for (int kk = 0; kk < 4; ++kk) {
        const float* sp_ = &Stl[p][n * 16 + l15][l16 * 8 + kk * 32];
        short8 sh8, sl8;
#pragma unroll
        for (int e = 0; e < 8; ++e) {
          float sv = sp_[e];
          u16 hh = f2bf(sv);
          sh8[e] = (short)hh;
          sl8[e] = (short)f2bf(sv - bf2f(hh));
        }
        ao[n] = __builtin_amdgcn_mfma_f32_16x16x32_bf16(ah[kk], sh8, ao[n], 0, 0, 0);
        ao[n] = __builtin_amdgcn_mfma_f32_16x16x32_bf16(ah[kk], sl8, ao[n], 0, 0, 0);
        ao[n] = __builtin_amdgcn_mfma_f32_16x16x32_bf16(al[kk], sh8, ao[n], 0, 0, 0);
      }
    }
#pragma unroll
    for (int n = 0; n < 2; ++n)
#pragma unroll
      for (int i = 0; i < 4; ++i) ao[n][i] *= earr[m0 + l16 * 4 + i];
    // ---- out += SI @ V (3 terms)
#pragma unroll
    for (int kk = 0; kk < 2; ++kk) {
      short8 asih = *(short8*)&SIh[m0 + l15][l16 * 8 + kk * 32];
      short8 asil = *(short8*)&SIl[m0 + l15][l16 * 8 + kk * 32];
#pragma unroll
      for (int n = 0; n < 2; ++n) {
        short8 bvh = *(short8*)&Vh[n * 16 + l15][l16 * 8 + kk * 32];
        short8 bvl = *(short8*)&Vl[n * 16 + l15][l16 * 8 + kk * 32];
        ao[n] = __builtin_amdgcn_mfma_f32_16x16x32_bf16(asih, bvh, ao[n], 0, 0, 0);
        ao[n] = __builtin_amdgcn_mfma_f32_16x16x32_bf16(asih, bvl, ao[n], 0, 0, 0);
        ao[n] = __builtin_amdgcn_mfma_f32_16x16x32_bf16(asil, bvh, ao[n], 0, 0, 0);
      }
    }
    // ---- write out rows
#pragma unroll
    for (int n = 0; n < 2; ++n)
#pragma unroll
      for (int i = 0; i < 4; ++i)
        outr[(size_t)(bT + t0 + m0 + l16 * 4 + i) * 4096 + vch + n * 16 + l15] = ao[n][i];
    // ---- state update: St = sdt*St + V^T (K.w), k from f32 (hi+lo), 3 terms
#pragma unroll
    for (int m = 0; m < 2; ++m)
#pragma unroll
      for (int n2 = 0; n2 < 2; ++n2)
#pragma unroll
        for (int i = 0; i < 4; ++i) st[m][n2][i] *= sdt;
#pragma unroll
    for (int kk = 0; kk < 2; ++kk) {
      short8 bwh[2], bwl[2];
#pragma unroll
      for (int n2 = 0; n2 < 2; ++n2) {
        int dk = wv * 32 + n2 * 16 + l15;
#pragma unroll
        for (int e = 0; e < 8; ++e) {
          int s = l16 * 8 + e + kk * 32;
          float kvv = (bf2f(Kh[s][dk]) + bf2f(Kl[s][dk])) * warr[s];
          u16 hh = f2bf(kvv);
          bwh[n2][e] = (short)hh;
          bwl[n2][e] = (short)f2bf(kvv - bf2f(hh));
        }
      }
#pragma unroll
      for (int m = 0; m < 2; ++m) {
        short8 avh = *(short8*)&Vh[m * 16 + l15][l16 * 8 + kk * 32];
        short8 avl = *(short8*)&Vl[m * 16 + l15][l16 * 8 + kk * 32];
#pragma unroll
        for (int n2 = 0; n2 < 2; ++n2) {
          st[m][n2] = __builtin_amdgcn_mfma_f32_16x16x32_bf16(avh, bwh[n2], st[m][n2], 0, 0, 0);
          st[m][n2] = __builtin_amdgcn_mfma_f32_16x16x32_bf16(avh, bwl[n2], st[m][n2], 0, 0, 0);
          st[m][n2] = __builtin_amdgcn_mfma_f32_16x16x32_bf16(avl, bwh[n2], st[m][n2], 0, 0, 0);
        }
      }
    }
    // ---- write state for next chunk
#pragma unroll
    for (int m = 0; m < 2; ++m)
#pragma unroll
      for (int n2 = 0; n2 < 2; ++n2)
#pragma unroll
        for (int i = 0; i < 4; ++i)
          Stl[p ^ 1][m * 16 + l16 * 4 + i][wv * 32 + n2 * 16 + l15] = st[m][n2][i];
    __syncthreads();  // B4
  }
}

// ---------------- per-(bt,head) RMS scale from f32 outr ----------------
__global__ __launch_bounds__(256) void k_rms(const float* __restrict__ outr, float* __restrict__ rms) {
  int pair = blockIdx.x * 4 + (threadIdx.x >> 6);
  int lane = threadIdx.x & 63;
  float2 v = *(const float2*)&outr[(size_t)pair * 128 + lane * 2];
  float ss = v.x * v.x + v.y * v.y;
#pragma unroll
  for (int m = 1; m < 64; m <<= 1) ss += __shfl_xor(ss, m);
  if (lane == 0) rms[pair] = rsqrtf(ss * (1.0f / 128.0f) + 1e-6f);
}

extern "C" void kernel_launch(void* const* d_in, const int* in_sizes, int n_in,
                              void* d_out, int out_size, void* d_ws, size_t ws_size,
                              hipStream_t stream) {
  const float* x = (const float*)d_in[0];
  // d_in[1] = positions (int64) — unused by the math
  const float* W_qkv = (const float*)d_in[2];
  const float* W_z = (const float*)d_in[3];
  const float* W_b = (const float*)d_in[4];
  const float* W_a = (const float*)d_in[5];
  const float* conv_w = (const float*)d_in[6];
  const float* dt_bias = (const float*)d_in[7];
  const float* A_log = (const float*)d_in[8];
  const float* norm_w = (const float*)d_in[9];
  const float* W_out = (const float*)d_in[10];
  float* out = (float*)d_out;

  const size_t S_R = (size_t)NBT * 4096 * 4;  // 64 MiB: one [4096][4096] f32 region
  const size_t S_SM = (size_t)NBT * 32 * 4;   // 0.5 MiB each

  const size_t need = 3 * S_R + 3 * S_SM;  // 202,899,456 B == proven ws lower bound (round 4)
  if (ws_size < need) {  // loud, distinguishable failure: absmax ~1e6
    k_sentinel<<<1, 1, 0, stream>>>(out);
    return;
  }
  char* ws = (char*)d_ws;
  float* qkA = (float*)ws;                    // raw qk [4096][4096]; -> outr after conv
  float* qkB = (float*)(ws + S_R);            // normed qk; -> omat after scan
  float* vbuf = (float*)(ws + 2 * S_R);       // raw v; wba/babuf overlay before qkv GEMM
  float* beta_t = (float*)(ws + 3 * S_R);
  float* g_t = beta_t + NBT * 32;
  float* rmsb = g_t + NBT * 32;
  float* outr = qkA;                          // overlays raw qk (dead after conv)
  float* omat = qkB;                          // overlays normed qk (dead after scan)
  float* wba = vbuf;                          // overlays v (dead before qkv GEMM)
  float* babuf = vbuf + (1 << 18);            // +1 MiB

  // --- b/a path ---
  k_wba<<<128 * NC / 256, 256, 0, stream>>>(W_b, W_a, wba);
  k_gemm_hl<0><<<dim3(1, NBT / 128), 256, 0, stream>>>(x, wba, babuf, nullptr, NBT, 128, NC,
                                                       nullptr, nullptr, nullptr);
  k_bg<<<NBT * 32 / 256, 256, 0, stream>>>(babuf, dt_bias, A_log, beta_t, g_t);

  // --- qkv projection (both batches, split) -> conv q/k (f32) -> chunked scan (both batches) ---
  k_gemm_hl<3><<<dim3(QKVD / 128, NBT / 128), 256, 0, stream>>>(x, W_qkv, qkA, vbuf, NBT, QKVD, NC,
                                                                nullptr, nullptr, nullptr);
  k_convqk<<<NBT, 256, 0, stream>>>(qkA, conv_w, qkB);
  k_scanc<<<256, 256, 0, stream>>>(qkB, vbuf, conv_w, beta_t, g_t, outr);

  k_rms<<<NBT * NHV / 4, 256, 0, stream>>>(outr, rmsb);

  // z projection with fused gated-RMSNorm epilogue -> f32 omat (overlays qkB)
  k_gemm_hl<2><<<dim3(VALD / 128, NBT / 128), 256, 0, stream>>>(x, W_z, omat, nullptr, NBT, VALD, NC,
                                                                outr, rmsb, norm_w);

  // output projection -> f32 out
  k_gemm_hl<0><<<dim3(NC / 128, NBT / 128), 256, 0, stream>>>(omat, W_out, out, nullptr, NBT, NC, VALD,
                                                              nullptr, nullptr, nullptr);
}

// Round 8
// 1325.445 us; speedup vs baseline: 2.2625x; 1.1635x over previous
//
#include <hip/hip_runtime.h>

typedef unsigned short u16;
typedef unsigned int u32;
typedef __attribute__((ext_vector_type(8))) short short8;
typedef __attribute__((ext_vector_type(4))) float f32x4;

#define NB 2
#define NT 2048
#define NC 2048
#define NHV 32
#define KEYD 2048
#define VALD 4096
#define QKVD 8192
#define NBT 4096
#define CL 64
#define NCH (NT / CL)

static __device__ __forceinline__ float bf2f(u16 u) {
  union { u32 u; float f; } x; x.u = ((u32)u) << 16; return x.f;
}
static __device__ __forceinline__ u16 f2bf(float f) {
  union { float f; u32 u; } x; x.f = f;
  u32 r = x.u + 0x7fffu + ((x.u >> 16) & 1u);
  return (u16)(r >> 16);
}
static __device__ __forceinline__ float sigm(float x) { return 1.0f / (1.0f + __expf(-x)); }

// ---------------- sentinel: ws too small marker ----------------
__global__ void k_sentinel(float* out) { out[0] = 1.0e6f; }

// ---------------- f32 -> bf16 hi (+ optional lo residual) planes ----------------
template <bool LO>
__global__ __launch_bounds__(256) void k_cvt(const float* __restrict__ in, u16* __restrict__ hi,
                                             u16* __restrict__ lo, int n4) {
  int i = blockIdx.x * 256 + threadIdx.x;
  if (i >= n4) return;
  float4 v = ((const float4*)in)[i];
  ushort4 h;
  h.x = f2bf(v.x); h.y = f2bf(v.y); h.z = f2bf(v.z); h.w = f2bf(v.w);
  ((ushort4*)hi)[i] = h;
  if constexpr (LO) {
    ushort4 l;
    l.x = f2bf(v.x - bf2f(h.x)); l.y = f2bf(v.y - bf2f(h.y));
    l.z = f2bf(v.z - bf2f(h.z)); l.w = f2bf(v.w - bf2f(h.w));
    ((ushort4*)lo)[i] = l;
  }
}

// ---------------- build padded W_ba hi/lo planes [128][2048] ----------------
__global__ __launch_bounds__(256) void k_wba(const float* __restrict__ Wb, const float* __restrict__ Wa,
                                             u16* __restrict__ hi, u16* __restrict__ lo) {
  int i = blockIdx.x * 256 + threadIdx.x;
  int r = i >> 11, c = i & 2047;
  float v = 0.f;
  if (r < 32) v = Wb[r * 2048 + c];
  else if (r < 64) v = Wa[(r - 32) * 2048 + c];
  u16 h = f2bf(v);
  hi[i] = h;
  lo[i] = f2bf(v - bf2f(h));
}

// ---------------- GEMM on pre-split bf16 planes: C = A[M][K] * B[N][K]^T ----------------
// PASSES 3: acc += AhBh + AlBh + AhBl (~f32). PASSES 2: acc += AhBh + AlBh (B single).
// MODE 0: f32 out C0. MODE 2: z epilogue: o = e0(outr)*e1(rms)*e2(nw)*silu(acc) -> hi/lo planes C0,C1.
template <int MODE, int PASSES>
__global__ __launch_bounds__(256) void k_gemm_bf(const u16* __restrict__ Ahg, const u16* __restrict__ Alg,
                                                 const u16* __restrict__ Bhg, const u16* __restrict__ Blg,
                                                 void* __restrict__ C0, void* __restrict__ C1,
                                                 int M, int N, int K,
                                                 const float* __restrict__ e0, const float* __restrict__ e1,
                                                 const float* __restrict__ e2) {
  __shared__ __align__(16) u16 As_h[128 * 48];
  __shared__ __align__(16) u16 As_l[128 * 48];
  __shared__ __align__(16) u16 Bs_h[128 * 48];
  __shared__ __align__(16) u16 Bs_l[(PASSES == 3) ? 128 * 48 : 8];
  const int tid = threadIdx.x;
  const int lane = tid & 63, wave = tid >> 6;
  const int wr = wave >> 1, wc = wave & 1;
  const int l15 = lane & 15, l16 = lane >> 4;
  const int row0 = blockIdx.y * 128, col0 = blockIdx.x * 128;
  const int sr = tid >> 1, sk = (tid & 1) * 16;
  f32x4 acc[4][4] = {};
  for (int k0 = 0; k0 < K; k0 += 32) {
    const size_t aoff = (size_t)(row0 + sr) * K + k0 + sk;
    const size_t boff = (size_t)(col0 + sr) * K + k0 + sk;
    *(short8*)&As_h[sr * 48 + sk] = *(const short8*)&Ahg[aoff];
    *(short8*)&As_h[sr * 48 + sk + 8] = *(const short8*)&Ahg[aoff + 8];
    *(short8*)&As_l[sr * 48 + sk] = *(const short8*)&Alg[aoff];
    *(short8*)&As_l[sr * 48 + sk + 8] = *(const short8*)&Alg[aoff + 8];
    *(short8*)&Bs_h[sr * 48 + sk] = *(const short8*)&Bhg[boff];
    *(short8*)&Bs_h[sr * 48 + sk + 8] = *(const short8*)&Bhg[boff + 8];
    if constexpr (PASSES == 3) {
      *(short8*)&Bs_l[sr * 48 + sk] = *(const short8*)&Blg[boff];
      *(short8*)&Bs_l[sr * 48 + sk + 8] = *(const short8*)&Blg[boff + 8];
    }
    __syncthreads();
    short8 ah[4], al[4], bh[4], bl[4];
#pragma unroll
    for (int mi = 0; mi < 4; ++mi) {
      ah[mi] = *(short8*)&As_h[(wr * 64 + mi * 16 + l15) * 48 + l16 * 8];
      al[mi] = *(short8*)&As_l[(wr * 64 + mi * 16 + l15) * 48 + l16 * 8];
    }
#pragma unroll
    for (int ni = 0; ni < 4; ++ni) {
      bh[ni] = *(short8*)&Bs_h[(wc * 64 + ni * 16 + l15) * 48 + l16 * 8];
      if constexpr (PASSES == 3)
        bl[ni] = *(short8*)&Bs_l[(wc * 64 + ni * 16 + l15) * 48 + l16 * 8];
    }
#pragma unroll
    for (int mi = 0; mi < 4; ++mi)
#pragma unroll
      for (int ni = 0; ni < 4; ++ni) {
        acc[mi][ni] = __builtin_amdgcn_mfma_f32_16x16x32_bf16(ah[mi], bh[ni], acc[mi][ni], 0, 0, 0);
        acc[mi][ni] = __builtin_amdgcn_mfma_f32_16x16x32_bf16(al[mi], bh[ni], acc[mi][ni], 0, 0, 0);
        if constexpr (PASSES == 3)
          acc[mi][ni] = __builtin_amdgcn_mfma_f32_16x16x32_bf16(ah[mi], bl[ni], acc[mi][ni], 0, 0, 0);
      }
    __syncthreads();
  }
#pragma unroll
  for (int mi = 0; mi < 4; ++mi) {
#pragma unroll
    for (int ni = 0; ni < 4; ++ni) {
      int rr = row0 + wr * 64 + mi * 16 + l16 * 4;
      int cc = col0 + wc * 64 + ni * 16 + l15;
#pragma unroll
      for (int i = 0; i < 4; ++i) {
        float v = acc[mi][ni][i];
        size_t idx = (size_t)(rr + i) * N + cc;
        if constexpr (MODE == 0) {
          ((float*)C0)[idx] = v;
        } else {
          float zs = v * sigm(v);  // silu(z)
          float o = e0[idx] * e1[(size_t)(rr + i) * 32 + (cc >> 7)] * e2[cc & 127] * zs;
          u16 hh = f2bf(o);
          ((u16*)C0)[idx] = hh;
          ((u16*)C1)[idx] = f2bf(o - bf2f(hh));
        }
      }
    }
  }
}

// ---------------- beta / g from ba [BT,128] f32, TRANSPOSED out [32][4096] ----------------
__global__ __launch_bounds__(256) void k_bg(const float* __restrict__ ba, const float* __restrict__ dt_bias,
                                            const float* __restrict__ A_log, float* __restrict__ beta_t,
                                            float* __restrict__ g_t) {
  int i = blockIdx.x * 256 + threadIdx.x;  // 0..131071
  int bt = i >> 5, h = i & 31;
  float bv = ba[(size_t)bt * 128 + h];
  float av = ba[(size_t)bt * 128 + 32 + h];
  beta_t[h * 4096 + bt] = sigm(bv);
  float xx = av + dt_bias[h];
  float sp = (xx > 20.f) ? xx : log1pf(__expf(xx));
  g_t[h * 4096 + bt] = -__expf(A_log[h]) * sp;
}

// ---------------- conv+SiLU+L2norm for q,k: f32 in [2048][4096] (batch-local) -> f32 out (global) ----
__global__ __launch_bounds__(256) void k_convqk(const float* __restrict__ qkraw, const float* __restrict__ cw,
                                                float* __restrict__ qkn, int b) {
  __shared__ float sval[4096];
  __shared__ float snrm[32];
  const int tid = threadIdx.x;
  const int t = blockIdx.x;
  for (int i = 0; i < 16; ++i) {
    int c = i * 256 + tid;  // 0..4095 (q:0-2047, k:2048-4095)
    float acc = 0.f;
#pragma unroll
    for (int j = 0; j < 4; ++j) {
      int ts = t - 3 + j;
      if (ts >= 0) acc += cw[c * 4 + j] * qkraw[(size_t)ts * 4096 + c];
    }
    sval[c] = acc * sigm(acc);
  }
  __syncthreads();
  {
    int gidx = tid >> 3, s = tid & 7;  // 32 groups (16 hk x {q,k}) x 8 threads
    float ss = 0.f;
#pragma unroll
    for (int i2 = 0; i2 < 16; ++i2) { float v = sval[gidx * 128 + s * 16 + i2]; ss += v * v; }
    ss += __shfl_xor(ss, 1); ss += __shfl_xor(ss, 2); ss += __shfl_xor(ss, 4);
    if (s == 0) snrm[gidx] = 1.0f / fmaxf(sqrtf(ss), 1e-12f);
  }
  __syncthreads();
  for (int i = 0; i < 16; ++i) {
    int c = i * 256 + tid;
    qkn[(size_t)(b * 2048 + t) * 4096 + c] = sval[c] * snrm[c >> 7];
  }
}

// ---------------- chunked gated-linear-attention scan, MFMA, hi/lo-compensated ----------------
// grid 256 = dq(4) x h(32) x b(2); block 256 (4 waves). Chunk L=64, 32 chunks sequential.
__global__ __launch_bounds__(256) void k_scanc(const float* __restrict__ qkn, const float* __restrict__ vraw,
                                               const float* __restrict__ cw,
                                               const float* __restrict__ beta_t, const float* __restrict__ g_t,
                                               float* __restrict__ outr) {
  __shared__ __align__(16) u16 Qh[64][136], Ql[64][136], Kh[64][136], Kl[64][136];
  __shared__ __align__(16) u16 Vh[32][72], Vl[32][72];
  __shared__ __align__(16) u16 SIh[64][72], SIl[64][72];
  __shared__ __align__(16) float Stl[2][32][132];
  __shared__ float rv[67][33];
  __shared__ float garr[64], barr[64], warr[64], earr[64];
  __shared__ float sdt;

  const int tid = threadIdx.x;
  const int lane = tid & 63, wv = tid >> 6;
  const int l15 = lane & 15, l16 = lane >> 4;
  const int dq = blockIdx.x & 3, h = (blockIdx.x >> 2) & 31, b = blockIdx.x >> 7;
  const int bT = b * 2048;
  const int hk = h >> 1;
  const int dvl = tid & 31;
  const int vch = h * 128 + dq * 32;  // within 4096-wide v buffer
  const float4 cwv = *(const float4*)&cw[(4096 + vch + dvl) * 4];
  const int m0 = wv * 16;
  const int sr = tid >> 2, d0 = (tid & 3) * 32;  // qk staging map
  const int r0v = tid >> 5;                       // v staging map

  for (int i = tid; i < 2 * 32 * 132; i += 256) ((float*)Stl)[i] = 0.f;
  f32x4 st[2][2] = {};  // state frags [dv-block m][dk-sub n2]; wave dk band = wv*32

  // ---- register prefetch buffers ----
  float4 pq[8], pk[8];
  float pv[9];
  auto LOADQK = [&](int t0) {
    const float* qg = qkn + (size_t)(bT + t0 + sr) * 4096 + hk * 128 + d0;
#pragma unroll
    for (int pp = 0; pp < 8; ++pp) {
      pq[pp] = *(const float4*)&qg[pp * 4];
      pk[pp] = *(const float4*)&qg[2048 + pp * 4];
    }
  };
  auto LOADV = [&](int t0) {
#pragma unroll
    for (int i = 0; i < 9; ++i) {
      int r = r0v + i * 8;
      int tr = t0 - 3 + r;
      pv[i] = (r < 67 && tr >= 0) ? vraw[(size_t)(bT + tr) * 4096 + vch + dvl] : 0.f;
    }
  };

  LOADQK(0);
  LOADV(0);

  for (int ch = 0; ch < NCH; ++ch) {
    const int t0 = ch * CL;
    const int p = ch & 1;
    // ---- write prefetched Q,K (f32 -> hi/lo bf16) and raw v rows to LDS
#pragma unroll
    for (int pp = 0; pp < 8; ++pp) {
      float4 qv = pq[pp], kv = pk[pp];
      ushort4 qh4, ql4, kh4, kl4;
      qh4.x = f2bf(qv.x); ql4.x = f2bf(qv.x - bf2f(qh4.x));
      qh4.y = f2bf(qv.y); ql4.y = f2bf(qv.y - bf2f(qh4.y));
      qh4.z = f2bf(qv.z); ql4.z = f2bf(qv.z - bf2f(qh4.z));
      qh4.w = f2bf(qv.w); ql4.w = f2bf(qv.w - bf2f(qh4.w));
      kh4.x = f2bf(kv.x); kl4.x = f2bf(kv.x - bf2f(kh4.x));
      kh4.y = f2bf(kv.y); kl4.y = f2bf(kv.y - bf2f(kh4.y));
      kh4.z = f2bf(kv.z); kl4.z = f2bf(kv.z - bf2f(kh4.z));
      kh4.w = f2bf(kv.w); kl4.w = f2bf(kv.w - bf2f(kh4.w));
      *(ushort4*)&Qh[sr][d0 + pp * 4] = qh4;
      *(ushort4*)&Ql[sr][d0 + pp * 4] = ql4;
      *(ushort4*)&Kh[sr][d0 + pp * 4] = kh4;
      *(ushort4*)&Kl[sr][d0 + pp * 4] = kl4;
    }
#pragma unroll
    for (int i = 0; i < 9; ++i) {
      int r = r0v + i * 8;
      if (r < 67) rv[r][dvl] = pv[i];
    }
    // ---- cumsum of g, beta (wave 0)
    if (wv == 0) {
      float gv = g_t[h * 4096 + bT + t0 + lane];
      float bv = beta_t[h * 4096 + bT + t0 + lane];
      float cum = gv;
#pragma unroll
      for (int off = 1; off < 64; off <<= 1) {
        float o = __shfl_up(cum, off);
        if (lane >= off) cum += o;
      }
      float tot = __shfl(cum, 63);
      garr[lane] = cum;
      earr[lane] = __expf(cum);
      warr[lane] = __expf(tot - cum) * bv;
      barr[lane] = bv;
      if (lane == 0) sdt = __expf(tot);
    }
    __syncthreads();  // B1
    // ---- prefetch next chunk (latency hides under compute below)
    if (ch + 1 < NCH) {
      LOADQK(t0 + CL);
      LOADV(t0 + CL);
    }
    // ---- v conv + silu -> hi/lo transposed [dv][s]
    {
      int tl = tid >> 5;
#pragma unroll
      for (int rr = 0; rr < 8; ++rr) {
        int t = rr * 8 + tl;
        float a = cwv.x * rv[t][dvl] + cwv.y * rv[t + 1][dvl] + cwv.z * rv[t + 2][dvl] + cwv.w * rv[t + 3][dvl];
        a = a * sigm(a);
        u16 hi = f2bf(a);
        Vh[dvl][t] = hi;
        Vl[dvl][t] = f2bf(a - bf2f(hi));
      }
    }
    // ---- A = Q K^T (hi/lo, 3 terms), mask -> SIh/SIl
    short8 ah[4], al[4];
#pragma unroll
    for (int kk = 0; kk < 4; ++kk) {
      ah[kk] = *(short8*)&Qh[m0 + l15][l16 * 8 + kk * 32];
      al[kk] = *(short8*)&Ql[m0 + l15][l16 * 8 + kk * 32];
    }
#pragma unroll
    for (int n = 0; n < 4; ++n) {
      f32x4 a4 = {};
#pragma unroll
      for (int kk = 0; kk < 4; ++kk) {
        short8 bh_ = *(short8*)&Kh[n * 16 + l15][l16 * 8 + kk * 32];
        short8 bl_ = *(short8*)&Kl[n * 16 + l15][l16 * 8 + kk * 32];
        a4 = __builtin_amdgcn_mfma_f32_16x16x32_bf16(ah[kk], bh_, a4, 0, 0, 0);
        a4 = __builtin_amdgcn_mfma_f32_16x16x32_bf16(ah[kk], bl_, a4, 0, 0, 0);
        a4 = __builtin_amdgcn_mfma_f32_16x16x32_bf16(al[kk], bh_, a4, 0, 0, 0);
      }
      int col = n * 16 + l15;
      float gc = garr[col], bc = barr[col];
#pragma unroll
      for (int i = 0; i < 4; ++i) {
        int row = m0 + l16 * 4 + i;
        float cval = (col <= row) ? __expf(garr[row] - gc) * bc * a4[i] : 0.f;
        u16 hh = f2bf(cval);
        SIh[row][col] = hh;
        SIl[row][col] = f2bf(cval - bf2f(hh));
      }
    }
    __syncthreads();  // B2
    // ---- out_inter = Q @ St_prev (Q hi/lo x S hi/lo, 3 terms), scaled by e^{Gc[t]}
    f32x4 ao[2] = {};
#pragma unroll
    for (int n = 0; n < 2; ++n) {
#pragma unroll
      for (int kk = 0; kk < 4; ++kk) {
        const float* sp_ = &Stl[p][n * 16 + l15][l16 * 8 + kk * 32];
        short8 sh8, sl8;
#pragma unroll
        for (int e = 0; e < 8; ++e) {
          float sv = sp_[e];
          u16 hh = f2bf(sv);
          sh8[e] = (short)hh;
          sl8[e] = (short)f2bf(sv - bf2f(hh));
        }
        ao[n] = __builtin_amdgcn_mfma_f32_16x16x32_bf16(ah[kk], sh8, ao[n], 0, 0, 0);
        ao[n] = __builtin_amdgcn_mfma_f32_16x16x32_bf16(ah[kk], sl8, ao[n], 0, 0, 0);
        ao[n] = __builtin_amdgcn_mfma_f32_16x16x32_bf16(al[kk], sh8, ao[n], 0, 0, 0);
      }
    }
#pragma unroll
    for (int n = 0; n < 2; ++n)
#pragma unroll
      for (int i = 0; i < 4; ++i) ao[n][i] *= earr[m0 + l16 * 4 + i];
    // ---- out += SI @ V (3 terms)
#pragma unroll
    for (int kk = 0; kk < 2; ++kk) {
      short8 asih = *(short8*)&SIh[m0 + l15][l16 * 8 + kk * 32];
      short8 asil = *(short8*)&SIl[m0 + l15][l16 * 8 + kk * 32];
#pragma unroll
      for (int n = 0; n < 2; ++n) {
        short8 bvh = *(short8*)&Vh[n * 16 + l15][l16 * 8 + kk * 32];
        short8 bvl = *(short8*)&Vl[n * 16 + l15][l16 * 8 + kk * 32];
        ao[n] = __builtin_amdgcn_mfma_f32_16x16x32_bf16(asih, bvh, ao[n], 0, 0, 0);
        ao[n] = __builtin_amdgcn_mfma_f32_16x16x32_bf16(asih, bvl, ao[n], 0, 0, 0);
        ao[n] = __builtin_amdgcn_mfma_f32_16x16x32_bf16(asil, bvh, ao[n], 0, 0, 0);
      }
    }
    // ---- write out rows
#pragma unroll
    for (int n = 0; n < 2; ++n)
#pragma unroll
      for (int i = 0; i < 4; ++i)
        outr[(size_t)(bT + t0 + m0 + l16 * 4 + i) * 4096 + vch + n * 16 + l15] = ao[n][i];
    // ---- state update: St = sdt*St + V^T (K.w), k from f32 (hi+lo), 3 terms
#pragma unroll
    for (int m = 0; m < 2; ++m)
#pragma unroll
      for (int n2 = 0; n2 < 2; ++n2)
#pragma unroll
        for (int i = 0; i < 4; ++i) st[m][n2][i] *= sdt;
#pragma unroll
    for (int kk = 0; kk < 2; ++kk) {
      short8 bwh[2], bwl[2];
#pragma unroll
      for (int n2 = 0; n2 < 2; ++n2) {
        int dk = wv * 32 + n2 * 16 + l15;
#pragma unroll
        for (int e = 0; e < 8; ++e) {
          int s = l16 * 8 + e + kk * 32;
          float kvv = (bf2f(Kh[s][dk]) + bf2f(Kl[s][dk])) * warr[s];
          u16 hh = f2bf(kvv);
          bwh[n2][e] = (short)hh;
          bwl[n2][e] = (short)f2bf(kvv - bf2f(hh));
        }
      }
#pragma unroll
      for (int m = 0; m < 2; ++m) {
        short8 avh = *(short8*)&Vh[m * 16 + l15][l16 * 8 + kk * 32];
        short8 avl = *(short8*)&Vl[m * 16 + l15][l16 * 8 + kk * 32];
#pragma unroll
        for (int n2 = 0; n2 < 2; ++n2) {
          st[m][n2] = __builtin_amdgcn_mfma_f32_16x16x32_bf16(avh, bwh[n2], st[m][n2], 0, 0, 0);
          st[m][n2] = __builtin_amdgcn_mfma_f32_16x16x32_bf16(avh, bwl[n2], st[m][n2], 0, 0, 0);
          st[m][n2] = __builtin_amdgcn_mfma_f32_16x16x32_bf16(avl, bwh[n2], st[m][n2], 0, 0, 0);
        }
      }
    }
    // ---- write state for next chunk
#pragma unroll
    for (int m = 0; m < 2; ++m)
#pragma unroll
      for (int n2 = 0; n2 < 2; ++n2)
#pragma unroll
        for (int i = 0; i < 4; ++i)
          Stl[p ^ 1][m * 16 + l16 * 4 + i][wv * 32 + n2 * 16 + l15] = st[m][n2][i];
    __syncthreads();  // B4
  }
}

// ---------------- per-(bt,head) RMS scale from f32 outr ----------------
__global__ __launch_bounds__(256) void k_rms(const float* __restrict__ outr, float* __restrict__ rms) {
  int pair = blockIdx.x * 4 + (threadIdx.x >> 6);
  int lane = threadIdx.x & 63;
  float2 v = *(const float2*)&outr[(size_t)pair * 128 + lane * 2];
  float ss = v.x * v.x + v.y * v.y;
#pragma unroll
  for (int m = 1; m < 64; m <<= 1) ss += __shfl_xor(ss, m);
  if (lane == 0) rms[pair] = rsqrtf(ss * (1.0f / 128.0f) + 1e-6f);
}

extern "C" void kernel_launch(void* const* d_in, const int* in_sizes, int n_in,
                              void* d_out, int out_size, void* d_ws, size_t ws_size,
                              hipStream_t stream) {
  const float* x = (const float*)d_in[0];
  // d_in[1] = positions (int64) — unused by the math
  const float* W_qkv = (const float*)d_in[2];
  const float* W_z = (const float*)d_in[3];
  const float* W_b = (const float*)d_in[4];
  const float* W_a = (const float*)d_in[5];
  const float* conv_w = (const float*)d_in[6];
  const float* dt_bias = (const float*)d_in[7];
  const float* A_log = (const float*)d_in[8];
  const float* norm_w = (const float*)d_in[9];
  const float* W_out = (const float*)d_in[10];
  float* out = (float*)d_out;

  const size_t MB = 1ull << 20;
  const size_t need = 192 * MB + 3 * (size_t)NBT * 32 * 4;  // 202,899,456 B == proven bound
  if (ws_size < need) {  // loud, distinguishable failure: absmax ~1e6
    k_sentinel<<<1, 1, 0, stream>>>(out);
    return;
  }
  char* ws = (char*)d_ws;
  // Region [0,64MB): x planes (16+16) + W-slot planes (16+16); later outr f32; later wout hi
  u16* xh = (u16*)ws;
  u16* xl = (u16*)(ws + 16 * MB);
  u16* wsh = (u16*)(ws + 32 * MB);   // wqk planes, then wv planes
  u16* wsl = (u16*)(ws + 48 * MB);
  float* outr = (float*)ws;
  u16* wouth = (u16*)ws;
  // Region [64,128MB): early: wba planes + babuf; then qkB f32; later om planes
  u16* wbah = (u16*)(ws + 64 * MB);
  u16* wbal = (u16*)(ws + 64 * MB + 512 * 1024);
  float* babuf = (float*)(ws + 65 * MB);
  float* qkB = (float*)(ws + 64 * MB);
  u16* omh = (u16*)(ws + 64 * MB);
  u16* oml = (u16*)(ws + 96 * MB);
  // Region [128,192MB): qkA f32 (first 32MB) then vbuf f32 (full); later x2 planes + wz hi
  float* qkA = (float*)(ws + 128 * MB);
  float* vbuf = (float*)(ws + 128 * MB);
  u16* xh2 = (u16*)(ws + 128 * MB);
  u16* xl2 = (u16*)(ws + 144 * MB);
  u16* wzh = (u16*)(ws + 160 * MB);
  // smalls at 192MB
  float* beta_t = (float*)(ws + 192 * MB);
  float* g_t = beta_t + (size_t)NBT * 32;
  float* rmsb = g_t + (size_t)NBT * 32;

  const int N4X = NBT * NC / 4;      // 2,097,152 float4s for 8.4M-elem buffers
  // --- conversions (x, W_qk rows) + ba path (uses [64,67MB) before qkB exists) ---
  k_cvt<true><<<N4X / 256, 256, 0, stream>>>(x, xh, xl, N4X);
  k_cvt<true><<<N4X / 256, 256, 0, stream>>>(W_qkv, wsh, wsl, N4X);  // qk rows 0..4095
  k_wba<<<128 * NC / 256, 256, 0, stream>>>(W_b, W_a, wbah, wbal);
  k_gemm_bf<0, 3><<<dim3(1, NBT / 128), 256, 0, stream>>>(xh, xl, wbah, wbal, babuf, nullptr,
                                                          NBT, 128, NC, nullptr, nullptr, nullptr);
  k_bg<<<NBT * 32 / 256, 256, 0, stream>>>(babuf, dt_bias, A_log, beta_t, g_t);

  // --- qk projection per batch -> conv+norm -> qkB (global) ---
  for (int b = 0; b < NB; ++b) {
    k_gemm_bf<0, 3><<<dim3(4096 / 128, NT / 128), 256, 0, stream>>>(
        xh + (size_t)b * NT * NC, xl + (size_t)b * NT * NC, wsh, wsl, qkA, nullptr,
        NT, 4096, NC, nullptr, nullptr, nullptr);
    k_convqk<<<NT, 256, 0, stream>>>(qkA, conv_w, qkB, b);
  }

  // --- v projection (both batches) ---
  k_cvt<true><<<N4X / 256, 256, 0, stream>>>(W_qkv + (size_t)4096 * NC, wsh, wsl, N4X);  // v rows
  k_gemm_bf<0, 3><<<dim3(4096 / 128, NBT / 128), 256, 0, stream>>>(xh, xl, wsh, wsl, vbuf, nullptr,
                                                                   NBT, 4096, NC, nullptr, nullptr, nullptr);

  // --- chunked scan (both batches) -> outr (overlays x/w planes, all dead) ---
  k_scanc<<<256, 256, 0, stream>>>(qkB, vbuf, conv_w, beta_t, g_t, outr);
  k_rms<<<NBT * NHV / 4, 256, 0, stream>>>(outr, rmsb);

  // --- z projection (2-pass, B single) with fused gate epilogue -> om hi/lo planes ---
  k_cvt<true><<<N4X / 256, 256, 0, stream>>>(x, xh2, xl2, N4X);      // re-convert x (vbuf dead)
  k_cvt<false><<<N4X / 256, 256, 0, stream>>>(W_z, wzh, nullptr, N4X);
  k_gemm_bf<2, 2><<<dim3(VALD / 128, NBT / 128), 256, 0, stream>>>(xh2, xl2, wzh, nullptr, omh, oml,
                                                                   NBT, VALD, NC, outr, rmsb, norm_w);

  // --- output projection (2-pass, B single) -> f32 out ---
  k_cvt<false><<<N4X / 256, 256, 0, stream>>>(W_out, wouth, nullptr, N4X);  // outr dead after z GEMM
  k_gemm_bf<0, 2><<<dim3(NC / 128, NBT / 128), 256, 0, stream>>>(omh, oml, wouth, nullptr, out, nullptr,
                                                                 NBT, NC, VALD, nullptr, nullptr, nullptr);
}

// Round 9
// 1219.099 us; speedup vs baseline: 2.4598x; 1.0872x over previous
//
#include <hip/hip_runtime.h>

typedef unsigned short u16;
typedef unsigned int u32;
typedef __attribute__((ext_vector_type(8))) short short8;
typedef __attribute__((ext_vector_type(4))) float f32x4;

#define NB 2
#define NT 2048
#define NC 2048
#define NHV 32
#define KEYD 2048
#define VALD 4096
#define QKVD 8192
#define NBT 4096
#define CL 64
#define NCH (NT / CL)

static __device__ __forceinline__ float bf2f(u16 u) {
  union { u32 u; float f; } x; x.u = ((u32)u) << 16; return x.f;
}
static __device__ __forceinline__ u16 f2bf(float f) {
  union { float f; u32 u; } x; x.f = f;
  u32 r = x.u + 0x7fffu + ((x.u >> 16) & 1u);
  return (u16)(r >> 16);
}
static __device__ __forceinline__ float sigm(float x) { return 1.0f / (1.0f + __expf(-x)); }

// ---------------- sentinel: ws too small marker ----------------
__global__ void k_sentinel(float* out) { out[0] = 1.0e6f; }

// ---------------- f32 -> bf16 hi (+ optional lo residual) planes ----------------
template <bool LO>
__global__ __launch_bounds__(256) void k_cvt(const float* __restrict__ in, u16* __restrict__ hi,
                                             u16* __restrict__ lo, int n4) {
  int i = blockIdx.x * 256 + threadIdx.x;
  if (i >= n4) return;
  float4 v = ((const float4*)in)[i];
  ushort4 h;
  h.x = f2bf(v.x); h.y = f2bf(v.y); h.z = f2bf(v.z); h.w = f2bf(v.w);
  ((ushort4*)hi)[i] = h;
  if constexpr (LO) {
    ushort4 l;
    l.x = f2bf(v.x - bf2f(h.x)); l.y = f2bf(v.y - bf2f(h.y));
    l.z = f2bf(v.z - bf2f(h.z)); l.w = f2bf(v.w - bf2f(h.w));
    ((ushort4*)lo)[i] = l;
  }
}

// ---------------- build padded W_ba hi/lo planes [128][2048] ----------------
__global__ __launch_bounds__(256) void k_wba(const float* __restrict__ Wb, const float* __restrict__ Wa,
                                             u16* __restrict__ hi, u16* __restrict__ lo) {
  int i = blockIdx.x * 256 + threadIdx.x;
  int r = i >> 11, c = i & 2047;
  float v = 0.f;
  if (r < 32) v = Wb[r * 2048 + c];
  else if (r < 64) v = Wa[(r - 32) * 2048 + c];
  u16 h = f2bf(v);
  hi[i] = h;
  lo[i] = f2bf(v - bf2f(h));
}

// ---------------- GEMM on pre-split bf16 planes: C = A[M][K] * B[N][K]^T ----------------
// PASSES 3: acc += AhBh + AlBh + AhBl (~f32). PASSES 2: acc += AhBh + AlBh (B single).
// MODE 0: f32 out C0. MODE 2: z epilogue: o = e0(outr)*e1(rms)*e2(nw)*silu(acc) -> hi/lo planes C0,C1.
template <int MODE, int PASSES>
__global__ __launch_bounds__(256) void k_gemm_bf(const u16* __restrict__ Ahg, const u16* __restrict__ Alg,
                                                 const u16* __restrict__ Bhg, const u16* __restrict__ Blg,
                                                 void* __restrict__ C0, void* __restrict__ C1,
                                                 int M, int N, int K,
                                                 const float* __restrict__ e0, const float* __restrict__ e1,
                                                 const float* __restrict__ e2) {
  __shared__ __align__(16) u16 As_h[128 * 48];
  __shared__ __align__(16) u16 As_l[128 * 48];
  __shared__ __align__(16) u16 Bs_h[128 * 48];
  __shared__ __align__(16) u16 Bs_l[(PASSES == 3) ? 128 * 48 : 8];
  const int tid = threadIdx.x;
  const int lane = tid & 63, wave = tid >> 6;
  const int wr = wave >> 1, wc = wave & 1;
  const int l15 = lane & 15, l16 = lane >> 4;
  const int row0 = blockIdx.y * 128, col0 = blockIdx.x * 128;
  const int sr = tid >> 1, sk = (tid & 1) * 16;
  f32x4 acc[4][4] = {};
  for (int k0 = 0; k0 < K; k0 += 32) {
    const size_t aoff = (size_t)(row0 + sr) * K + k0 + sk;
    const size_t boff = (size_t)(col0 + sr) * K + k0 + sk;
    *(short8*)&As_h[sr * 48 + sk] = *(const short8*)&Ahg[aoff];
    *(short8*)&As_h[sr * 48 + sk + 8] = *(const short8*)&Ahg[aoff + 8];
    *(short8*)&As_l[sr * 48 + sk] = *(const short8*)&Alg[aoff];
    *(short8*)&As_l[sr * 48 + sk + 8] = *(const short8*)&Alg[aoff + 8];
    *(short8*)&Bs_h[sr * 48 + sk] = *(const short8*)&Bhg[boff];
    *(short8*)&Bs_h[sr * 48 + sk + 8] = *(const short8*)&Bhg[boff + 8];
    if constexpr (PASSES == 3) {
      *(short8*)&Bs_l[sr * 48 + sk] = *(const short8*)&Blg[boff];
      *(short8*)&Bs_l[sr * 48 + sk + 8] = *(const short8*)&Blg[boff + 8];
    }
    __syncthreads();
    short8 ah[4], al[4], bh[4], bl[4];
#pragma unroll
    for (int mi = 0; mi < 4; ++mi) {
      ah[mi] = *(short8*)&As_h[(wr * 64 + mi * 16 + l15) * 48 + l16 * 8];
      al[mi] = *(short8*)&As_l[(wr * 64 + mi * 16 + l15) * 48 + l16 * 8];
    }
#pragma unroll
    for (int ni = 0; ni < 4; ++ni) {
      bh[ni] = *(short8*)&Bs_h[(wc * 64 + ni * 16 + l15) * 48 + l16 * 8];
      if constexpr (PASSES == 3)
        bl[ni] = *(short8*)&Bs_l[(wc * 64 + ni * 16 + l15) * 48 + l16 * 8];
    }
#pragma unroll
    for (int mi = 0; mi < 4; ++mi)
#pragma unroll
      for (int ni = 0; ni < 4; ++ni) {
        acc[mi][ni] = __builtin_amdgcn_mfma_f32_16x16x32_bf16(ah[mi], bh[ni], acc[mi][ni], 0, 0, 0);
        acc[mi][ni] = __builtin_amdgcn_mfma_f32_16x16x32_bf16(al[mi], bh[ni], acc[mi][ni], 0, 0, 0);
        if constexpr (PASSES == 3)
          acc[mi][ni] = __builtin_amdgcn_mfma_f32_16x16x32_bf16(ah[mi], bl[ni], acc[mi][ni], 0, 0, 0);
      }
    __syncthreads();
  }
#pragma unroll
  for (int mi = 0; mi < 4; ++mi) {
#pragma unroll
    for (int ni = 0; ni < 4; ++ni) {
      int rr = row0 + wr * 64 + mi * 16 + l16 * 4;
      int cc = col0 + wc * 64 + ni * 16 + l15;
#pragma unroll
      for (int i = 0; i < 4; ++i) {
        float v = acc[mi][ni][i];
        size_t idx = (size_t)(rr + i) * N + cc;
        if constexpr (MODE == 0) {
          ((float*)C0)[idx] = v;
        } else {
          float zs = v * sigm(v);  // silu(z)
          float o = e0[idx] * e1[(size_t)(rr + i) * 32 + (cc >> 7)] * e2[cc & 127] * zs;
          u16 hh = f2bf(o);
          ((u16*)C0)[idx] = hh;
          ((u16*)C1)[idx] = f2bf(o - bf2f(hh));
        }
      }
    }
  }
}

// ---------------- beta / g from ba [BT,128] f32, TRANSPOSED out [32][4096] ----------------
__global__ __launch_bounds__(256) void k_bg(const float* __restrict__ ba, const float* __restrict__ dt_bias,
                                            const float* __restrict__ A_log, float* __restrict__ beta_t,
                                            float* __restrict__ g_t) {
  int i = blockIdx.x * 256 + threadIdx.x;  // 0..131071
  int bt = i >> 5, h = i & 31;
  float bv = ba[(size_t)bt * 128 + h];
  float av = ba[(size_t)bt * 128 + 32 + h];
  beta_t[h * 4096 + bt] = sigm(bv);
  float xx = av + dt_bias[h];
  float sp = (xx > 20.f) ? xx : log1pf(__expf(xx));
  g_t[h * 4096 + bt] = -__expf(A_log[h]) * sp;
}

// ---------------- conv+SiLU+L2norm for q,k: f32 in [4096][4096] -> f32 out [4096][4096] ----------------
__global__ __launch_bounds__(256) void k_convqk(const float* __restrict__ qkraw, const float* __restrict__ cw,
                                                float* __restrict__ qkn) {
  __shared__ float sval[4096];
  __shared__ float snrm[32];
  const int tid = threadIdx.x;
  const int bt = blockIdx.x;
  const int b = bt >> 11, t = bt & 2047;
  for (int i = 0; i < 16; ++i) {
    int c = i * 256 + tid;  // 0..4095 (q:0-2047, k:2048-4095)
    float acc = 0.f;
#pragma unroll
    for (int j = 0; j < 4; ++j) {
      int ts = t - 3 + j;
      if (ts >= 0) acc += cw[c * 4 + j] * qkraw[(size_t)(b * 2048 + ts) * 4096 + c];
    }
    sval[c] = acc * sigm(acc);
  }
  __syncthreads();
  {
    int gidx = tid >> 3, s = tid & 7;  // 32 groups (16 hk x {q,k}) x 8 threads
    float ss = 0.f;
#pragma unroll
    for (int i2 = 0; i2 < 16; ++i2) { float v = sval[gidx * 128 + s * 16 + i2]; ss += v * v; }
    ss += __shfl_xor(ss, 1); ss += __shfl_xor(ss, 2); ss += __shfl_xor(ss, 4);
    if (s == 0) snrm[gidx] = 1.0f / fmaxf(sqrtf(ss), 1e-12f);
  }
  __syncthreads();
  for (int i = 0; i < 16; ++i) {
    int c = i * 256 + tid;
    qkn[(size_t)bt * 4096 + c] = sval[c] * snrm[c >> 7];
  }
}

// ---------------- chunked gated-linear-attention scan, MFMA, hi/lo-compensated ----------------
// grid 256 = dq(4) x h(32) x b(2); block 512 (8 waves). Chunk L=64, 32 chunks sequential.
// 8-way work split: QK^T wave(m=wv&3, nh=wv>>2) 2 col-blocks; inter/SIV/out (m,nh) one 16x16 block;
// state update: wave wv owns dk band wv*16.
__global__ __launch_bounds__(512) void k_scanc(const float* __restrict__ qkn, const float* __restrict__ vraw,
                                               const float* __restrict__ cw,
                                               const float* __restrict__ beta_t, const float* __restrict__ g_t,
                                               float* __restrict__ outr) {
  __shared__ __align__(16) u16 Qh[64][136], Ql[64][136], Kh[64][136], Kl[64][136];
  __shared__ __align__(16) u16 Vh[32][72], Vl[32][72];
  __shared__ __align__(16) u16 SIh[64][72], SIl[64][72];
  __shared__ __align__(16) float Stl[2][32][132];
  __shared__ float rv[67][33];
  __shared__ float garr[64], barr[64], warr[64], earr[64];
  __shared__ float sdt;

  const int tid = threadIdx.x;
  const int lane = tid & 63, wv = tid >> 6;
  const int l15 = lane & 15, l16 = lane >> 4;
  const int dq = blockIdx.x & 3, h = (blockIdx.x >> 2) & 31, b = blockIdx.x >> 7;
  const int bT = b * 2048;
  const int hk = h >> 1;
  const int dvl = tid & 31;
  const int vch = h * 128 + dq * 32;  // within 4096-wide v buffer
  const float4 cwv = *(const float4*)&cw[(4096 + vch + dvl) * 4];
  const int mblk = wv & 3, nh = wv >> 2;
  const int m0 = mblk * 16;
  const int sr = tid >> 3, d0 = (tid & 7) * 16;  // qk staging map (512 threads)
  const int r0v = tid >> 5;                      // v staging map (0..15)

  for (int i = tid; i < 2 * 32 * 132; i += 512) ((float*)Stl)[i] = 0.f;
  f32x4 st[2] = {};  // state frags [dv-block m]; wave dk band = wv*16

  // ---- register prefetch buffers ----
  float4 pq[4], pk[4];
  float pv[5];
  auto LOADQK = [&](int t0) {
    const float* qg = qkn + (size_t)(bT + t0 + sr) * 4096 + hk * 128 + d0;
#pragma unroll
    for (int pp = 0; pp < 4; ++pp) {
      pq[pp] = *(const float4*)&qg[pp * 4];
      pk[pp] = *(const float4*)&qg[2048 + pp * 4];
    }
  };
  auto LOADV = [&](int t0) {
#pragma unroll
    for (int i = 0; i < 5; ++i) {
      int r = r0v + i * 16;
      int tr = t0 - 3 + r;
      pv[i] = (r < 67 && tr >= 0) ? vraw[(size_t)(bT + tr) * 4096 + vch + dvl] : 0.f;
    }
  };

  LOADQK(0);
  LOADV(0);

  for (int ch = 0; ch < NCH; ++ch) {
    const int t0 = ch * CL;
    const int p = ch & 1;
    // ---- write prefetched Q,K (f32 -> hi/lo bf16) and raw v rows to LDS
#pragma unroll
    for (int pp = 0; pp < 4; ++pp) {
      float4 qv = pq[pp], kv = pk[pp];
      ushort4 qh4, ql4, kh4, kl4;
      qh4.x = f2bf(qv.x); ql4.x = f2bf(qv.x - bf2f(qh4.x));
      qh4.y = f2bf(qv.y); ql4.y = f2bf(qv.y - bf2f(qh4.y));
      qh4.z = f2bf(qv.z); ql4.z = f2bf(qv.z - bf2f(qh4.z));
      qh4.w = f2bf(qv.w); ql4.w = f2bf(qv.w - bf2f(qh4.w));
      kh4.x = f2bf(kv.x); kl4.x = f2bf(kv.x - bf2f(kh4.x));
      kh4.y = f2bf(kv.y); kl4.y = f2bf(kv.y - bf2f(kh4.y));
      kh4.z = f2bf(kv.z); kl4.z = f2bf(kv.z - bf2f(kh4.z));
      kh4.w = f2bf(kv.w); kl4.w = f2bf(kv.w - bf2f(kh4.w));
      *(ushort4*)&Qh[sr][d0 + pp * 4] = qh4;
      *(ushort4*)&Ql[sr][d0 + pp * 4] = ql4;
      *(ushort4*)&Kh[sr][d0 + pp * 4] = kh4;
      *(ushort4*)&Kl[sr][d0 + pp * 4] = kl4;
    }
#pragma unroll
    for (int i = 0; i < 5; ++i) {
      int r = r0v + i * 16;
      if (r < 67) rv[r][dvl] = pv[i];
    }
    // ---- cumsum of g, beta (wave 0)
    if (wv == 0) {
      float gv = g_t[h * 4096 + bT + t0 + lane];
      float bv = beta_t[h * 4096 + bT + t0 + lane];
      float cum = gv;
#pragma unroll
      for (int off = 1; off < 64; off <<= 1) {
        float o = __shfl_up(cum, off);
        if (lane >= off) cum += o;
      }
      float tot = __shfl(cum, 63);
      garr[lane] = cum;
      earr[lane] = __expf(cum);
      warr[lane] = __expf(tot - cum) * bv;
      barr[lane] = bv;
      if (lane == 0) sdt = __expf(tot);
    }
    __syncthreads();  // B1
    // ---- prefetch next chunk (latency hides under compute below)
    if (ch + 1 < NCH) {
      LOADQK(t0 + CL);
      LOADV(t0 + CL);
    }
    // ---- v conv + silu -> hi/lo transposed [dv][s]
    {
      int tl = tid >> 5;
#pragma unroll
      for (int rr = 0; rr < 4; ++rr) {
        int t = rr * 16 + tl;
        float a = cwv.x * rv[t][dvl] + cwv.y * rv[t + 1][dvl] + cwv.z * rv[t + 2][dvl] + cwv.w * rv[t + 3][dvl];
        a = a * sigm(a);
        u16 hi = f2bf(a);
        Vh[dvl][t] = hi;
        Vl[dvl][t] = f2bf(a - bf2f(hi));
      }
    }
    // ---- A = Q K^T (hi/lo, 3 terms), this wave: rows m0..m0+15, col blocks nh*2, nh*2+1
    short8 ah[4], al[4];
#pragma unroll
    for (int kk = 0; kk < 4; ++kk) {
      ah[kk] = *(short8*)&Qh[m0 + l15][l16 * 8 + kk * 32];
      al[kk] = *(short8*)&Ql[m0 + l15][l16 * 8 + kk * 32];
    }
#pragma unroll
    for (int j = 0; j < 2; ++j) {
      int n = nh * 2 + j;
      f32x4 a4 = {};
#pragma unroll
      for (int kk = 0; kk < 4; ++kk) {
        short8 bh_ = *(short8*)&Kh[n * 16 + l15][l16 * 8 + kk * 32];
        short8 bl_ = *(short8*)&Kl[n * 16 + l15][l16 * 8 + kk * 32];
        a4 = __builtin_amdgcn_mfma_f32_16x16x32_bf16(ah[kk], bh_, a4, 0, 0, 0);
        a4 = __builtin_amdgcn_mfma_f32_16x16x32_bf16(ah[kk], bl_, a4, 0, 0, 0);
        a4 = __builtin_amdgcn_mfma_f32_16x16x32_bf16(al[kk], bh_, a4, 0, 0, 0);
      }
      int col = n * 16 + l15;
      float gc = garr[col], bc = barr[col];
#pragma unroll
      for (int i = 0; i < 4; ++i) {
        int row = m0 + l16 * 4 + i;
        float cval = (col <= row) ? __expf(garr[row] - gc) * bc * a4[i] : 0.f;
        u16 hh = f2bf(cval);
        SIh[row][col] = hh;
        SIl[row][col] = f2bf(cval - bf2f(hh));
      }
    }
    __syncthreads();  // B2
    // ---- out_inter = Q @ St_prev (Q hi/lo x S hi/lo, 3 terms); this wave: (m0, dv block nh)
    f32x4 ao = {};
#pragma unroll
    for (int kk = 0; kk < 4; ++kk) {
      const float* sp_ = &Stl[p][nh * 16 + l15][l16 * 8 + kk * 32];
      short8 sh8, sl8;
#pragma unroll
      for (int e = 0; e < 8; ++e) {
        float sv = sp_[e];
        u16 hh = f2bf(sv);
        sh8[e] = (short)hh;
        sl8[e] = (short)f2bf(sv - bf2f(hh));
      }
      ao = __builtin_amdgcn_mfma_f32_16x16x32_bf16(ah[kk], sh8, ao, 0, 0, 0);
      ao = __builtin_amdgcn_mfma_f32_16x16x32_bf16(ah[kk], sl8, ao, 0, 0, 0);
      ao = __builtin_amdgcn_mfma_f32_16x16x32_bf16(al[kk], sh8, ao, 0, 0, 0);
    }
#pragma unroll
    for (int i = 0; i < 4; ++i) ao[i] *= earr[m0 + l16 * 4 + i];
    // ---- out += SI @ V (3 terms)
#pragma unroll
    for (int kk = 0; kk < 2; ++kk) {
      short8 asih = *(short8*)&SIh[m0 + l15][l16 * 8 + kk * 32];
      short8 asil = *(short8*)&SIl[m0 + l15][l16 * 8 + kk * 32];
      short8 bvh = *(short8*)&Vh[nh * 16 + l15][l16 * 8 + kk * 32];
      short8 bvl = *(short8*)&Vl[nh * 16 + l15][l16 * 8 + kk * 32];
      ao = __builtin_amdgcn_mfma_f32_16x16x32_bf16(asih, bvh, ao, 0, 0, 0);
      ao = __builtin_amdgcn_mfma_f32_16x16x32_bf16(asih, bvl, ao, 0, 0, 0);
      ao = __builtin_amdgcn_mfma_f32_16x16x32_bf16(asil, bvh, ao, 0, 0, 0);
    }
    // ---- write out rows (wave quarter: rows m0.., dv cols nh*16..)
#pragma unroll
    for (int i = 0; i < 4; ++i)
      outr[(size_t)(bT + t0 + m0 + l16 * 4 + i) * 4096 + vch + nh * 16 + l15] = ao[i];
    // ---- state update: St = sdt*St + V^T (K.w); this wave: dk band wv*16
#pragma unroll
    for (int m = 0; m < 2; ++m)
#pragma unroll
      for (int i = 0; i < 4; ++i) st[m][i] *= sdt;
#pragma unroll
    for (int kk = 0; kk < 2; ++kk) {
      short8 bwh, bwl;
      {
        int dk = wv * 16 + l15;
#pragma unroll
        for (int e = 0; e < 8; ++e) {
          int s = l16 * 8 + e + kk * 32;
          float kvv = (bf2f(Kh[s][dk]) + bf2f(Kl[s][dk])) * warr[s];
          u16 hh = f2bf(kvv);
          bwh[e] = (short)hh;
          bwl[e] = (short)f2bf(kvv - bf2f(hh));
        }
      }
#pragma unroll
      for (int m = 0; m < 2; ++m) {
        short8 avh = *(short8*)&Vh[m * 16 + l15][l16 * 8 + kk * 32];
        short8 avl = *(short8*)&Vl[m * 16 + l15][l16 * 8 + kk * 32];
        st[m] = __builtin_amdgcn_mfma_f32_16x16x32_bf16(avh, bwh, st[m], 0, 0, 0);
        st[m] = __builtin_amdgcn_mfma_f32_16x16x32_bf16(avh, bwl, st[m], 0, 0, 0);
        st[m] = __builtin_amdgcn_mfma_f32_16x16x32_bf16(avl, bwh, st[m], 0, 0, 0);
      }
    }
    // ---- write state for next chunk (wave band: dk cols wv*16..wv*16+15)
#pragma unroll
    for (int m = 0; m < 2; ++m)
#pragma unroll
      for (int i = 0; i < 4; ++i)
        Stl[p ^ 1][m * 16 + l16 * 4 + i][wv * 16 + l15] = st[m][i];
    __syncthreads();  // B4
  }
}

// ---------------- per-(bt,head) RMS scale from f32 outr ----------------
__global__ __launch_bounds__(256) void k_rms(const float* __restrict__ outr, float* __restrict__ rms) {
  int pair = blockIdx.x * 4 + (threadIdx.x >> 6);
  int lane = threadIdx.x & 63;
  float2 v = *(const float2*)&outr[(size_t)pair * 128 + lane * 2];
  float ss = v.x * v.x + v.y * v.y;
#pragma unroll
  for (int m = 1; m < 64; m <<= 1) ss += __shfl_xor(ss, m);
  if (lane == 0) rms[pair] = rsqrtf(ss * (1.0f / 128.0f) + 1e-6f);
}

extern "C" void kernel_launch(void* const* d_in, const int* in_sizes, int n_in,
                              void* d_out, int out_size, void* d_ws, size_t ws_size,
                              hipStream_t stream) {
  const float* x = (const float*)d_in[0];
  // d_in[1] = positions (int64) — unused by the math
  const float* W_qkv = (const float*)d_in[2];
  const float* W_z = (const float*)d_in[3];
  const float* W_b = (const float*)d_in[4];
  const float* W_a = (const float*)d_in[5];
  const float* conv_w = (const float*)d_in[6];
  const float* dt_bias = (const float*)d_in[7];
  const float* A_log = (const float*)d_in[8];
  const float* norm_w = (const float*)d_in[9];
  const float* W_out = (const float*)d_in[10];
  float* out = (float*)d_out;

  const size_t MB = 1ull << 20;
  const size_t need = 192 * MB + 3 * (size_t)NBT * 32 * 4;  // 202,899,456 B == proven bound
  if (ws_size < need) {  // loud, distinguishable failure: absmax ~1e6
    k_sentinel<<<1, 1, 0, stream>>>(out);
    return;
  }
  char* ws = (char*)d_ws;
  // Region A [0,64MB): x planes (16+16) + W-slot planes (16+16); later outr f32; later wout hi
  u16* xh = (u16*)ws;
  u16* xl = (u16*)(ws + 16 * MB);
  u16* wsh = (u16*)(ws + 32 * MB);   // wqk planes, then wv planes
  u16* wsl = (u16*)(ws + 48 * MB);
  float* outr = (float*)ws;
  u16* wouth = (u16*)ws;
  // Region B [64,128MB): early: wba planes + babuf; then qkB f32 (full 64MB); later om planes
  u16* wbah = (u16*)(ws + 64 * MB);
  u16* wbal = (u16*)(ws + 64 * MB + 512 * 1024);
  float* babuf = (float*)(ws + 65 * MB);
  float* qkB = (float*)(ws + 64 * MB);
  u16* omh = (u16*)(ws + 64 * MB);
  u16* oml = (u16*)(ws + 96 * MB);
  // Region C [128,192MB): qkA f32 (full 64MB); then vbuf f32 (overwrites); later x2 planes + wz hi
  float* qkA = (float*)(ws + 128 * MB);
  float* vbuf = (float*)(ws + 128 * MB);
  u16* xh2 = (u16*)(ws + 128 * MB);
  u16* xl2 = (u16*)(ws + 144 * MB);
  u16* wzh = (u16*)(ws + 160 * MB);
  // smalls at 192MB
  float* beta_t = (float*)(ws + 192 * MB);
  float* g_t = beta_t + (size_t)NBT * 32;
  float* rmsb = g_t + (size_t)NBT * 32;

  const int N4X = NBT * NC / 4;
  // --- conversions (x, W_qk rows) + ba path (uses [64,66MB) before qkB exists) ---
  k_cvt<true><<<N4X / 256, 256, 0, stream>>>(x, xh, xl, N4X);
  k_cvt<true><<<N4X / 256, 256, 0, stream>>>(W_qkv, wsh, wsl, N4X);  // qk rows 0..4095
  k_wba<<<128 * NC / 256, 256, 0, stream>>>(W_b, W_a, wbah, wbal);
  k_gemm_bf<0, 3><<<dim3(1, NBT / 128), 256, 0, stream>>>(xh, xl, wbah, wbal, babuf, nullptr,
                                                          NBT, 128, NC, nullptr, nullptr, nullptr);
  k_bg<<<NBT * 32 / 256, 256, 0, stream>>>(babuf, dt_bias, A_log, beta_t, g_t);

  // --- qk projection (both batches) -> conv+norm -> qkB ---
  k_gemm_bf<0, 3><<<dim3(4096 / 128, NBT / 128), 256, 0, stream>>>(xh, xl, wsh, wsl, qkA, nullptr,
                                                                   NBT, 4096, NC, nullptr, nullptr, nullptr);
  k_convqk<<<NBT, 256, 0, stream>>>(qkA, conv_w, qkB);

  // --- v projection (both batches; vbuf overwrites qkA which is dead) ---
  k_cvt<true><<<N4X / 256, 256, 0, stream>>>(W_qkv + (size_t)4096 * NC, wsh, wsl, N4X);  // v rows
  k_gemm_bf<0, 3><<<dim3(4096 / 128, NBT / 128), 256, 0, stream>>>(xh, xl, wsh, wsl, vbuf, nullptr,
                                                                   NBT, 4096, NC, nullptr, nullptr, nullptr);

  // --- chunked scan (both batches) -> outr (overlays x/w planes, all dead) ---
  k_scanc<<<256, 512, 0, stream>>>(qkB, vbuf, conv_w, beta_t, g_t, outr);
  k_rms<<<NBT * NHV / 4, 256, 0, stream>>>(outr, rmsb);

  // --- z projection (2-pass, B single) with fused gate epilogue -> om hi/lo planes ---
  k_cvt<true><<<N4X / 256, 256, 0, stream>>>(x, xh2, xl2, N4X);      // re-convert x (vbuf dead)
  k_cvt<false><<<N4X / 256, 256, 0, stream>>>(W_z, wzh, nullptr, N4X);
  k_gemm_bf<2, 2><<<dim3(VALD / 128, NBT / 128), 256, 0, stream>>>(xh2, xl2, wzh, nullptr, omh, oml,
                                                                   NBT, VALD, NC, outr, rmsb, norm_w);

  // --- output projection (2-pass, B single) -> f32 out ---
  k_cvt<false><<<N4X / 256, 256, 0, stream>>>(W_out, wouth, nullptr, N4X);  // outr dead after z GEMM
  k_gemm_bf<0, 2><<<dim3(NC / 128, NBT / 128), 256, 0, stream>>>(omh, oml, wouth, nullptr, out, nullptr,
                                                                 NBT, NC, VALD, nullptr, nullptr, nullptr);
}

// Round 10
// 1205.197 us; speedup vs baseline: 2.4882x; 1.0115x over previous
//
#include <hip/hip_runtime.h>

typedef unsigned short u16;
typedef unsigned int u32;
typedef __attribute__((ext_vector_type(8))) short short8;
typedef __attribute__((ext_vector_type(4))) float f32x4;

#define NB 2
#define NT 2048
#define NC 2048
#define NHV 32
#define KEYD 2048
#define VALD 4096
#define QKVD 8192
#define NBT 4096
#define CL 64
#define NCH (NT / CL)

static __device__ __forceinline__ float bf2f(u16 u) {
  union { u32 u; float f; } x; x.u = ((u32)u) << 16; return x.f;
}
static __device__ __forceinline__ u16 f2bf(float f) {
  union { float f; u32 u; } x; x.f = f;
  u32 r = x.u + 0x7fffu + ((x.u >> 16) & 1u);
  return (u16)(r >> 16);
}
static __device__ __forceinline__ float sigm(float x) { return 1.0f / (1.0f + __expf(-x)); }

#define BAR __builtin_amdgcn_s_barrier()
#define LGKM0 do { asm volatile("s_waitcnt lgkmcnt(0)" ::: "memory"); __builtin_amdgcn_sched_barrier(0); } while (0)
#define VM0   do { asm volatile("s_waitcnt vmcnt(0)" ::: "memory"); __builtin_amdgcn_sched_barrier(0); } while (0)
#define GL16(gp, lp) __builtin_amdgcn_global_load_lds( \
    (const __attribute__((address_space(1))) unsigned int*)(gp), \
    (__attribute__((address_space(3))) unsigned int*)(lp), 16, 0, 0)

// ---------------- sentinel: ws too small marker ----------------
__global__ void k_sentinel(float* out) { out[0] = 1.0e6f; }

// ---------------- f32 -> bf16 hi (+ optional lo residual) planes ----------------
template <bool LO>
__global__ __launch_bounds__(256) void k_cvt(const float* __restrict__ in, u16* __restrict__ hi,
                                             u16* __restrict__ lo, int n4) {
  int i = blockIdx.x * 256 + threadIdx.x;
  if (i >= n4) return;
  float4 v = ((const float4*)in)[i];
  ushort4 h;
  h.x = f2bf(v.x); h.y = f2bf(v.y); h.z = f2bf(v.z); h.w = f2bf(v.w);
  ((ushort4*)hi)[i] = h;
  if constexpr (LO) {
    ushort4 l;
    l.x = f2bf(v.x - bf2f(h.x)); l.y = f2bf(v.y - bf2f(h.y));
    l.z = f2bf(v.z - bf2f(h.z)); l.w = f2bf(v.w - bf2f(h.w));
    ((ushort4*)lo)[i] = l;
  }
}

// ---------------- build padded W_ba hi/lo planes [128][2048] ----------------
__global__ __launch_bounds__(256) void k_wba(const float* __restrict__ Wb, const float* __restrict__ Wa,
                                             u16* __restrict__ hi, u16* __restrict__ lo) {
  int i = blockIdx.x * 256 + threadIdx.x;
  int r = i >> 11, c = i & 2047;
  float v = 0.f;
  if (r < 32) v = Wb[r * 2048 + c];
  else if (r < 64) v = Wa[(r - 32) * 2048 + c];
  u16 h = f2bf(v);
  hi[i] = h;
  lo[i] = f2bf(v - bf2f(h));
}

// ---------------- 128x128 2-barrier GEMM (kept for the small ba projection) ----------------
template <int MODE, int PASSES>
__global__ __launch_bounds__(256) void k_gemm_bf(const u16* __restrict__ Ahg, const u16* __restrict__ Alg,
                                                 const u16* __restrict__ Bhg, const u16* __restrict__ Blg,
                                                 void* __restrict__ C0, void* __restrict__ C1,
                                                 int M, int N, int K,
                                                 const float* __restrict__ e0, const float* __restrict__ e1,
                                                 const float* __restrict__ e2) {
  __shared__ __align__(16) u16 As_h[128 * 48];
  __shared__ __align__(16) u16 As_l[128 * 48];
  __shared__ __align__(16) u16 Bs_h[128 * 48];
  __shared__ __align__(16) u16 Bs_l[(PASSES == 3) ? 128 * 48 : 8];
  const int tid = threadIdx.x;
  const int lane = tid & 63, wave = tid >> 6;
  const int wr = wave >> 1, wc = wave & 1;
  const int l15 = lane & 15, l16 = lane >> 4;
  const int row0 = blockIdx.y * 128, col0 = blockIdx.x * 128;
  const int sr = tid >> 1, sk = (tid & 1) * 16;
  f32x4 acc[4][4] = {};
  for (int k0 = 0; k0 < K; k0 += 32) {
    const size_t aoff = (size_t)(row0 + sr) * K + k0 + sk;
    const size_t boff = (size_t)(col0 + sr) * K + k0 + sk;
    *(short8*)&As_h[sr * 48 + sk] = *(const short8*)&Ahg[aoff];
    *(short8*)&As_h[sr * 48 + sk + 8] = *(const short8*)&Ahg[aoff + 8];
    *(short8*)&As_l[sr * 48 + sk] = *(const short8*)&Alg[aoff];
    *(short8*)&As_l[sr * 48 + sk + 8] = *(const short8*)&Alg[aoff + 8];
    *(short8*)&Bs_h[sr * 48 + sk] = *(const short8*)&Bhg[boff];
    *(short8*)&Bs_h[sr * 48 + sk + 8] = *(const short8*)&Bhg[boff + 8];
    if constexpr (PASSES == 3) {
      *(short8*)&Bs_l[sr * 48 + sk] = *(const short8*)&Blg[boff];
      *(short8*)&Bs_l[sr * 48 + sk + 8] = *(const short8*)&Blg[boff + 8];
    }
    __syncthreads();
    short8 ah[4], al[4], bh[4], bl[4];
#pragma unroll
    for (int mi = 0; mi < 4; ++mi) {
      ah[mi] = *(short8*)&As_h[(wr * 64 + mi * 16 + l15) * 48 + l16 * 8];
      al[mi] = *(short8*)&As_l[(wr * 64 + mi * 16 + l15) * 48 + l16 * 8];
    }
#pragma unroll
    for (int ni = 0; ni < 4; ++ni) {
      bh[ni] = *(short8*)&Bs_h[(wc * 64 + ni * 16 + l15) * 48 + l16 * 8];
      if constexpr (PASSES == 3)
        bl[ni] = *(short8*)&Bs_l[(wc * 64 + ni * 16 + l15) * 48 + l16 * 8];
    }
#pragma unroll
    for (int mi = 0; mi < 4; ++mi)
#pragma unroll
      for (int ni = 0; ni < 4; ++ni) {
        acc[mi][ni] = __builtin_amdgcn_mfma_f32_16x16x32_bf16(ah[mi], bh[ni], acc[mi][ni], 0, 0, 0);
        acc[mi][ni] = __builtin_amdgcn_mfma_f32_16x16x32_bf16(al[mi], bh[ni], acc[mi][ni], 0, 0, 0);
        if constexpr (PASSES == 3)
          acc[mi][ni] = __builtin_amdgcn_mfma_f32_16x16x32_bf16(ah[mi], bl[ni], acc[mi][ni], 0, 0, 0);
      }
    __syncthreads();
  }
#pragma unroll
  for (int mi = 0; mi < 4; ++mi) {
#pragma unroll
    for (int ni = 0; ni < 4; ++ni) {
      int rr = row0 + wr * 64 + mi * 16 + l16 * 4;
      int cc = col0 + wc * 64 + ni * 16 + l15;
#pragma unroll
      for (int i = 0; i < 4; ++i) {
        float v = acc[mi][ni][i];
        size_t idx = (size_t)(rr + i) * N + cc;
        if constexpr (MODE == 0) {
          ((float*)C0)[idx] = v;
        } else {
          float zs = v * sigm(v);
          float o = e0[idx] * e1[(size_t)(rr + i) * 32 + (cc >> 7)] * e2[cc & 127] * zs;
          u16 hh = f2bf(o);
          ((u16*)C0)[idx] = hh;
          ((u16*)C1)[idx] = f2bf(o - bf2f(hh));
        }
      }
    }
  }
}

// ---------------- 256x256 8-wave 4-phase GEMM (T1+T2+T3+T4+T5), hi/lo planes ----------------
// C = A[M][K] * B[N][K]^T. PASSES 3: AhBh+AlBh+AhBl. PASSES 2: AhBh+AlBh.
// MODE 0: f32 C0. MODE 2: z epilogue -> omat hi/lo planes C0,C1.
// LDS linear [256][32] u16 per plane, dbuf; swizzle col16 ^= (row>>1)&3 on BOTH global src and ds_read.
template <int MODE, int PASSES>
__global__ __launch_bounds__(512, 2) void k_gemm8(const u16* __restrict__ Ahg, const u16* __restrict__ Alg,
                                                  const u16* __restrict__ Bhg, const u16* __restrict__ Blg,
                                                  void* __restrict__ C0, void* __restrict__ C1,
                                                  int M, int N, int K,
                                                  const float* __restrict__ e0, const float* __restrict__ e1,
                                                  const float* __restrict__ e2) {
  __shared__ __align__(16) u16 AhS[2 * 8192];
  __shared__ __align__(16) u16 AlS[2 * 8192];
  __shared__ __align__(16) u16 BhS[2 * 8192];
  __shared__ __align__(16) u16 BlS[(PASSES == 3) ? 2 * 8192 : 16];
  const int tid = threadIdx.x;
  const int wv = tid >> 6, l = tid & 63;
  const int l15 = l & 15, l16 = l >> 4;
  // T1: bijective XCD swizzle (gridDim.x % 8 == 0 for all our launches)
  const int cpx = gridDim.x >> 3;
  const int bid = blockIdx.x;
  const int swz = (bid & 7) * cpx + (bid >> 3);
  const int nbx = N >> 8;
  const int bx = swz % nbx, by = swz / nbx;
  const int row0 = by * 256, col0 = bx * 256;
  const int wr = wv >> 2, wc = wv & 3;  // wave grid 2(M) x 4(N); per-wave out 128x64
  // staging maps: wave wv round r covers LDS rows [wv*32+r*16, +16); lane l -> (row +l/4, col16 l&3)
  u32 sA[2], sB[2], sL[2];
#pragma unroll
  for (int r = 0; r < 2; ++r) {
    int rs = wv * 32 + r * 16 + (l >> 2);
    int c16 = (l & 3) ^ ((rs >> 1) & 3);  // pre-swizzled global source
    sA[r] = (u32)(row0 + rs) * (u32)K + c16 * 8;
    sB[r] = (u32)(col0 + rs) * (u32)K + c16 * 8;
    sL[r] = (u32)((wv * 32 + r * 16) * 32);
  }
  // fragment read offsets (swizzled)
  u32 offA[8], offB[4];
#pragma unroll
  for (int mb = 0; mb < 8; ++mb) {
    int row = wr * 128 + mb * 16 + l15;
    offA[mb] = (u32)(row * 32 + (l16 ^ ((row >> 1) & 3)) * 8);
  }
#pragma unroll
  for (int nbi = 0; nbi < 4; ++nbi) {
    int row = wc * 64 + nbi * 16 + l15;
    offB[nbi] = (u32)(row * 32 + (l16 ^ ((row >> 1) & 3)) * 8);
  }
  f32x4 acc[8][4] = {};
  const int NTILES = K >> 5;
  int cur = 0;
  // prologue: stage tile 0 into buf 0
#pragma unroll
  for (int r = 0; r < 2; ++r) {
    GL16(Ahg + sA[r], &AhS[sL[r]]);
    GL16(Alg + sA[r], &AlS[sL[r]]);
    GL16(Bhg + sB[r], &BhS[sL[r]]);
    if constexpr (PASSES == 3) GL16(Blg + sB[r], &BlS[sL[r]]);
  }
  VM0; BAR;
  for (int t = 0; t < NTILES; ++t) {
    const u32 cb = (u32)cur * 8192;
    const u32 nbuf = cb ^ 8192;
    const int kn = (t + 1) << 5;
    const bool pf = (t + 1 < NTILES);
    short8 b_h[4], b_l[4];
#pragma unroll
    for (int q = 0; q < 4; ++q) {
      // ---- issue staging for tile t+1 (spread across phases)
      if (pf) {
        if (q == 0) { GL16(Ahg + sA[0] + kn, &AhS[nbuf + sL[0]]); GL16(Ahg + sA[1] + kn, &AhS[nbuf + sL[1]]); }
        if (q == 1) { GL16(Alg + sA[0] + kn, &AlS[nbuf + sL[0]]); GL16(Alg + sA[1] + kn, &AlS[nbuf + sL[1]]); }
        if (q == 2) {
          GL16(Bhg + sB[0] + kn, &BhS[nbuf + sL[0]]);
          if constexpr (PASSES == 3) GL16(Bhg + sB[1] + kn, &BhS[nbuf + sL[1]]);
        }
        if (q == 3) {
          if constexpr (PASSES == 3) {
            GL16(Blg + sB[0] + kn, &BlS[nbuf + sL[0]]);
            GL16(Blg + sB[1] + kn, &BlS[nbuf + sL[1]]);
          } else {
            GL16(Bhg + sB[1] + kn, &BhS[nbuf + sL[1]]);
          }
        }
      }
      // ---- ds reads for this phase
      if (q == 0) {
#pragma unroll
        for (int nbi = 0; nbi < 4; ++nbi) {
          b_h[nbi] = *(short8*)&BhS[cb + offB[nbi]];
          if constexpr (PASSES == 3) b_l[nbi] = *(short8*)&BlS[cb + offB[nbi]];
        }
      }
      short8 a_h[2], a_l[2];
#pragma unroll
      for (int m2 = 0; m2 < 2; ++m2) {
        a_h[m2] = *(short8*)&AhS[cb + offA[2 * q + m2]];
        a_l[m2] = *(short8*)&AlS[cb + offA[2 * q + m2]];
      }
      BAR;
      LGKM0;
      __builtin_amdgcn_s_setprio(1);
#pragma unroll
      for (int m2 = 0; m2 < 2; ++m2)
#pragma unroll
        for (int nbi = 0; nbi < 4; ++nbi) {
          acc[2 * q + m2][nbi] = __builtin_amdgcn_mfma_f32_16x16x32_bf16(a_h[m2], b_h[nbi], acc[2 * q + m2][nbi], 0, 0, 0);
          acc[2 * q + m2][nbi] = __builtin_amdgcn_mfma_f32_16x16x32_bf16(a_l[m2], b_h[nbi], acc[2 * q + m2][nbi], 0, 0, 0);
          if constexpr (PASSES == 3)
            acc[2 * q + m2][nbi] = __builtin_amdgcn_mfma_f32_16x16x32_bf16(a_h[m2], b_l[nbi], acc[2 * q + m2][nbi], 0, 0, 0);
        }
      __builtin_amdgcn_s_setprio(0);
      if (q == 3) { VM0; }  // own t+1 staging landed; barrier below makes it block-wide
      BAR;
    }
    cur ^= 1;
  }
  // ---- epilogue
#pragma unroll
  for (int mb = 0; mb < 8; ++mb) {
#pragma unroll
    for (int nbi = 0; nbi < 4; ++nbi) {
      int rr = row0 + wr * 128 + mb * 16 + l16 * 4;
      int cc = col0 + wc * 64 + nbi * 16 + l15;
#pragma unroll
      for (int i = 0; i < 4; ++i) {
        float v = acc[mb][nbi][i];
        size_t idx = (size_t)(rr + i) * N + cc;
        if constexpr (MODE == 0) {
          ((float*)C0)[idx] = v;
        } else {
          float zs = v * sigm(v);
          float o = e0[idx] * e1[(size_t)(rr + i) * 32 + (cc >> 7)] * e2[cc & 127] * zs;
          u16 hh = f2bf(o);
          ((u16*)C0)[idx] = hh;
          ((u16*)C1)[idx] = f2bf(o - bf2f(hh));
        }
      }
    }
  }
}

// ---------------- beta / g from ba [BT,128] f32, TRANSPOSED out [32][4096] ----------------
__global__ __launch_bounds__(256) void k_bg(const float* __restrict__ ba, const float* __restrict__ dt_bias,
                                            const float* __restrict__ A_log, float* __restrict__ beta_t,
                                            float* __restrict__ g_t) {
  int i = blockIdx.x * 256 + threadIdx.x;  // 0..131071
  int bt = i >> 5, h = i & 31;
  float bv = ba[(size_t)bt * 128 + h];
  float av = ba[(size_t)bt * 128 + 32 + h];
  beta_t[h * 4096 + bt] = sigm(bv);
  float xx = av + dt_bias[h];
  float sp = (xx > 20.f) ? xx : log1pf(__expf(xx));
  g_t[h * 4096 + bt] = -__expf(A_log[h]) * sp;
}

// ---------------- conv+SiLU+L2norm for q,k: f32 in [4096][4096] -> f32 out [4096][4096] ----------------
__global__ __launch_bounds__(256) void k_convqk(const float* __restrict__ qkraw, const float* __restrict__ cw,
                                                float* __restrict__ qkn) {
  __shared__ float sval[4096];
  __shared__ float snrm[32];
  const int tid = threadIdx.x;
  const int bt = blockIdx.x;
  const int b = bt >> 11, t = bt & 2047;
  for (int i = 0; i < 16; ++i) {
    int c = i * 256 + tid;  // 0..4095 (q:0-2047, k:2048-4095)
    float acc = 0.f;
#pragma unroll
    for (int j = 0; j < 4; ++j) {
      int ts = t - 3 + j;
      if (ts >= 0) acc += cw[c * 4 + j] * qkraw[(size_t)(b * 2048 + ts) * 4096 + c];
    }
    sval[c] = acc * sigm(acc);
  }
  __syncthreads();
  {
    int gidx = tid >> 3, s = tid & 7;
    float ss = 0.f;
#pragma unroll
    for (int i2 = 0; i2 < 16; ++i2) { float v = sval[gidx * 128 + s * 16 + i2]; ss += v * v; }
    ss += __shfl_xor(ss, 1); ss += __shfl_xor(ss, 2); ss += __shfl_xor(ss, 4);
    if (s == 0) snrm[gidx] = 1.0f / fmaxf(sqrtf(ss), 1e-12f);
  }
  __syncthreads();
  for (int i = 0; i < 16; ++i) {
    int c = i * 256 + tid;
    qkn[(size_t)bt * 4096 + c] = sval[c] * snrm[c >> 7];
  }
}

// ---------------- chunked gated-linear-attention scan, MFMA, hi/lo-compensated ----------------
// grid 256 = dq(4) x h(32) x b(2); block 512 (8 waves). Chunk L=64, 32 chunks sequential.
__global__ __launch_bounds__(512) void k_scanc(const float* __restrict__ qkn, const float* __restrict__ vraw,
                                               const float* __restrict__ cw,
                                               const float* __restrict__ beta_t, const float* __restrict__ g_t,
                                               float* __restrict__ outr) {
  __shared__ __align__(16) u16 Qh[64][136], Ql[64][136], Kh[64][136], Kl[64][136];
  __shared__ __align__(16) u16 Vh[32][72], Vl[32][72];
  __shared__ __align__(16) u16 SIh[64][72], SIl[64][72];
  __shared__ __align__(16) float Stl[2][32][132];
  __shared__ float rv[67][33];
  __shared__ float garr[64], barr[64], warr[64], earr[64];
  __shared__ float sdt;

  const int tid = threadIdx.x;
  const int lane = tid & 63, wv = tid >> 6;
  const int l15 = lane & 15, l16 = lane >> 4;
  const int dq = blockIdx.x & 3, h = (blockIdx.x >> 2) & 31, b = blockIdx.x >> 7;
  const int bT = b * 2048;
  const int hk = h >> 1;
  const int dvl = tid & 31;
  const int vch = h * 128 + dq * 32;
  const float4 cwv = *(const float4*)&cw[(4096 + vch + dvl) * 4];
  const int mblk = wv & 3, nh = wv >> 2;
  const int m0 = mblk * 16;
  const int sr = tid >> 3, d0 = (tid & 7) * 16;
  const int r0v = tid >> 5;

  for (int i = tid; i < 2 * 32 * 132; i += 512) ((float*)Stl)[i] = 0.f;
  f32x4 st[2] = {};

  float4 pq[4], pk[4];
  float pv[5];
  auto LOADQK = [&](int t0) {
    const float* qg = qkn + (size_t)(bT + t0 + sr) * 4096 + hk * 128 + d0;
#pragma unroll
    for (int pp = 0; pp < 4; ++pp) {
      pq[pp] = *(const float4*)&qg[pp * 4];
      pk[pp] = *(const float4*)&qg[2048 + pp * 4];
    }
  };
  auto LOADV = [&](int t0) {
#pragma unroll
    for (int i = 0; i < 5; ++i) {
      int r = r0v + i * 16;
      int tr = t0 - 3 + r;
      pv[i] = (r < 67 && tr >= 0) ? vraw[(size_t)(bT + tr) * 4096 + vch + dvl] : 0.f;
    }
  };

  LOADQK(0);
  LOADV(0);

  for (int ch = 0; ch < NCH; ++ch) {
    const int t0 = ch * CL;
    const int p = ch & 1;
#pragma unroll
    for (int pp = 0; pp < 4; ++pp) {
      float4 qv = pq[pp], kv = pk[pp];
      ushort4 qh4, ql4, kh4, kl4;
      qh4.x = f2bf(qv.x); ql4.x = f2bf(qv.x - bf2f(qh4.x));
      qh4.y = f2bf(qv.y); ql4.y = f2bf(qv.y - bf2f(qh4.y));
      qh4.z = f2bf(qv.z); ql4.z = f2bf(qv.z - bf2f(qh4.z));
      qh4.w = f2bf(qv.w); ql4.w = f2bf(qv.w - bf2f(qh4.w));
      kh4.x = f2bf(kv.x); kl4.x = f2bf(kv.x - bf2f(kh4.x));
      kh4.y = f2bf(kv.y); kl4.y = f2bf(kv.y - bf2f(kh4.y));
      kh4.z = f2bf(kv.z); kl4.z = f2bf(kv.z - bf2f(kh4.z));
      kh4.w = f2bf(kv.w); kl4.w = f2bf(kv.w - bf2f(kh4.w));
      *(ushort4*)&Qh[sr][d0 + pp * 4] = qh4;
      *(ushort4*)&Ql[sr][d0 + pp * 4] = ql4;
      *(ushort4*)&Kh[sr][d0 + pp * 4] = kh4;
      *(ushort4*)&Kl[sr][d0 + pp * 4] = kl4;
    }
#pragma unroll
    for (int i = 0; i < 5; ++i) {
      int r = r0v + i * 16;
      if (r < 67) rv[r][dvl] = pv[i];
    }
    if (wv == 0) {
      float gv = g_t[h * 4096 + bT + t0 + lane];
      float bv = beta_t[h * 4096 + bT + t0 + lane];
      float cum = gv;
#pragma unroll
      for (int off = 1; off < 64; off <<= 1) {
        float o = __shfl_up(cum, off);
        if (lane >= off) cum += o;
      }
      float tot = __shfl(cum, 63);
      garr[lane] = cum;
      earr[lane] = __expf(cum);
      warr[lane] = __expf(tot - cum) * bv;
      barr[lane] = bv;
      if (lane == 0) sdt = __expf(tot);
    }
    __syncthreads();  // B1
    if (ch + 1 < NCH) {
      LOADQK(t0 + CL);
      LOADV(t0 + CL);
    }
    {
      int tl = tid >> 5;
#pragma unroll
      for (int rr = 0; rr < 4; ++rr) {
        int t = rr * 16 + tl;
        float a = cwv.x * rv[t][dvl] + cwv.y * rv[t + 1][dvl] + cwv.z * rv[t + 2][dvl] + cwv.w * rv[t + 3][dvl];
        a = a * sigm(a);
        u16 hi = f2bf(a);
        Vh[dvl][t] = hi;
        Vl[dvl][t] = f2bf(a - bf2f(hi));
      }
    }
    short8 ah[4], al[4];
#pragma unroll
    for (int kk = 0; kk < 4; ++kk) {
      ah[kk] = *(short8*)&Qh[m0 + l15][l16 * 8 + kk * 32];
      al[kk] = *(short8*)&Ql[m0 + l15][l16 * 8 + kk * 32];
    }
#pragma unroll
    for (int j = 0; j < 2; ++j) {
      int n = nh * 2 + j;
      f32x4 a4 = {};
#pragma unroll
      for (int kk = 0; kk < 4; ++kk) {
        short8 bh_ = *(short8*)&Kh[n * 16 + l15][l16 * 8 + kk * 32];
        short8 bl_ = *(short8*)&Kl[n * 16 + l15][l16 * 8 + kk * 32];
        a4 = __builtin_amdgcn_mfma_f32_16x16x32_bf16(ah[kk], bh_, a4, 0, 0, 0);
        a4 = __builtin_amdgcn_mfma_f32_16x16x32_bf16(ah[kk], bl_, a4, 0, 0, 0);
        a4 = __builtin_amdgcn_mfma_f32_16x16x32_bf16(al[kk], bh_, a4, 0, 0, 0);
      }
      int col = n * 16 + l15;
      float gc = garr[col], bc = barr[col];
#pragma unroll
      for (int i = 0; i < 4; ++i) {
        int row = m0 + l16 * 4 + i;
        float cval = (col <= row) ? __expf(garr[row] - gc) * bc * a4[i] : 0.f;
        u16 hh = f2bf(cval);
        SIh[row][col] = hh;
        SIl[row][col] = f2bf(cval - bf2f(hh));
      }
    }
    __syncthreads();  // B2
    f32x4 ao = {};
#pragma unroll
    for (int kk = 0; kk < 4; ++kk) {
      const float* sp_ = &Stl[p][nh * 16 + l15][l16 * 8 + kk * 32];
      short8 sh8, sl8;
#pragma unroll
      for (int e = 0; e < 8; ++e) {
        float sv = sp_[e];
        u16 hh = f2bf(sv);
        sh8[e] = (short)hh;
        sl8[e] = (short)f2bf(sv - bf2f(hh));
      }
      ao = __builtin_amdgcn_mfma_f32_16x16x32_bf16(ah[kk], sh8, ao, 0, 0, 0);
      ao = __builtin_amdgcn_mfma_f32_16x16x32_bf16(ah[kk], sl8, ao, 0, 0, 0);
      ao = __builtin_amdgcn_mfma_f32_16x16x32_bf16(al[kk], sh8, ao, 0, 0, 0);
    }
#pragma unroll
    for (int i = 0; i < 4; ++i) ao[i] *= earr[m0 + l16 * 4 + i];
#pragma unroll
    for (int kk = 0; kk < 2; ++kk) {
      short8 asih = *(short8*)&SIh[m0 + l15][l16 * 8 + kk * 32];
      short8 asil = *(short8*)&SIl[m0 + l15][l16 * 8 + kk * 32];
      short8 bvh = *(short8*)&Vh[nh * 16 + l15][l16 * 8 + kk * 32];
      short8 bvl = *(short8*)&Vl[nh * 16 + l15][l16 * 8 + kk * 32];
      ao = __builtin_amdgcn_mfma_f32_16x16x32_bf16(asih, bvh, ao, 0, 0, 0);
      ao = __builtin_amdgcn_mfma_f32_16x16x32_bf16(asih, bvl, ao, 0, 0, 0);
      ao = __builtin_amdgcn_mfma_f32_16x16x32_bf16(asil, bvh, ao, 0, 0, 0);
    }
#pragma unroll
    for (int i = 0; i < 4; ++i)
      outr[(size_t)(bT + t0 + m0 + l16 * 4 + i) * 4096 + vch + nh * 16 + l15] = ao[i];
#pragma unroll
    for (int m = 0; m < 2; ++m)
#pragma unroll
      for (int i = 0; i < 4; ++i) st[m][i] *= sdt;
#pragma unroll
    for (int kk = 0; kk < 2; ++kk) {
      short8 bwh, bwl;
      {
        int dk = wv * 16 + l15;
#pragma unroll
        for (int e = 0; e < 8; ++e) {
          int s = l16 * 8 + e + kk * 32;
          float kvv = (bf2f(Kh[s][dk]) + bf2f(Kl[s][dk])) * warr[s];
          u16 hh = f2bf(kvv);
          bwh[e] = (short)hh;
          bwl[e] = (short)f2bf(kvv - bf2f(hh));
        }
      }
#pragma unroll
      for (int m = 0; m < 2; ++m) {
        short8 avh = *(short8*)&Vh[m * 16 + l15][l16 * 8 + kk * 32];
        short8 avl = *(short8*)&Vl[m * 16 + l15][l16 * 8 + kk * 32];
        st[m] = __builtin_amdgcn_mfma_f32_16x16x32_bf16(avh, bwh, st[m], 0, 0, 0);
        st[m] = __builtin_amdgcn_mfma_f32_16x16x32_bf16(avh, bwl, st[m], 0, 0, 0);
        st[m] = __builtin_amdgcn_mfma_f32_16x16x32_bf16(avl, bwh, st[m], 0, 0, 0);
      }
    }
#pragma unroll
    for (int m = 0; m < 2; ++m)
#pragma unroll
      for (int i = 0; i < 4; ++i)
        Stl[p ^ 1][m * 16 + l16 * 4 + i][wv * 16 + l15] = st[m][i];
    __syncthreads();  // B4
  }
}

// ---------------- per-(bt,head) RMS scale from f32 outr ----------------
__global__ __launch_bounds__(256) void k_rms(const float* __restrict__ outr, float* __restrict__ rms) {
  int pair = blockIdx.x * 4 + (threadIdx.x >> 6);
  int lane = threadIdx.x & 63;
  float2 v = *(const float2*)&outr[(size_t)pair * 128 + lane * 2];
  float ss = v.x * v.x + v.y * v.y;
#pragma unroll
  for (int m = 1; m < 64; m <<= 1) ss += __shfl_xor(ss, m);
  if (lane == 0) rms[pair] = rsqrtf(ss * (1.0f / 128.0f) + 1e-6f);
}

extern "C" void kernel_launch(void* const* d_in, const int* in_sizes, int n_in,
                              void* d_out, int out_size, void* d_ws, size_t ws_size,
                              hipStream_t stream) {
  const float* x = (const float*)d_in[0];
  // d_in[1] = positions (int64) — unused by the math
  const float* W_qkv = (const float*)d_in[2];
  const float* W_z = (const float*)d_in[3];
  const float* W_b = (const float*)d_in[4];
  const float* W_a = (const float*)d_in[5];
  const float* conv_w = (const float*)d_in[6];
  const float* dt_bias = (const float*)d_in[7];
  const float* A_log = (const float*)d_in[8];
  const float* norm_w = (const float*)d_in[9];
  const float* W_out = (const float*)d_in[10];
  float* out = (float*)d_out;

  const size_t MB = 1ull << 20;
  const size_t need = 192 * MB + 3 * (size_t)NBT * 32 * 4;  // 202,899,456 B == proven bound
  if (ws_size < need) {
    k_sentinel<<<1, 1, 0, stream>>>(out);
    return;
  }
  char* ws = (char*)d_ws;
  // Region A [0,64MB): x planes + W-slot planes; later outr f32; later wout hi
  u16* xh = (u16*)ws;
  u16* xl = (u16*)(ws + 16 * MB);
  u16* wsh = (u16*)(ws + 32 * MB);
  u16* wsl = (u16*)(ws + 48 * MB);
  float* outr = (float*)ws;
  u16* wouth = (u16*)ws;
  // Region B [64,128MB): early: wba planes + babuf; then qkB f32; later om planes
  u16* wbah = (u16*)(ws + 64 * MB);
  u16* wbal = (u16*)(ws + 64 * MB + 512 * 1024);
  float* babuf = (float*)(ws + 65 * MB);
  float* qkB = (float*)(ws + 64 * MB);
  u16* omh = (u16*)(ws + 64 * MB);
  u16* oml = (u16*)(ws + 96 * MB);
  // Region C [128,192MB): qkA f32; then vbuf f32; later x2 planes + wz hi
  float* qkA = (float*)(ws + 128 * MB);
  float* vbuf = (float*)(ws + 128 * MB);
  u16* xh2 = (u16*)(ws + 128 * MB);
  u16* xl2 = (u16*)(ws + 144 * MB);
  u16* wzh = (u16*)(ws + 160 * MB);
  float* beta_t = (float*)(ws + 192 * MB);
  float* g_t = beta_t + (size_t)NBT * 32;
  float* rmsb = g_t + (size_t)NBT * 32;

  const int N4X = NBT * NC / 4;
  // --- conversions + ba path ---
  k_cvt<true><<<N4X / 256, 256, 0, stream>>>(x, xh, xl, N4X);
  k_cvt<true><<<N4X / 256, 256, 0, stream>>>(W_qkv, wsh, wsl, N4X);  // qk rows 0..4095
  k_wba<<<128 * NC / 256, 256, 0, stream>>>(W_b, W_a, wbah, wbal);
  k_gemm_bf<0, 3><<<dim3(1, NBT / 128), 256, 0, stream>>>(xh, xl, wbah, wbal, babuf, nullptr,
                                                          NBT, 128, NC, nullptr, nullptr, nullptr);
  k_bg<<<NBT * 32 / 256, 256, 0, stream>>>(babuf, dt_bias, A_log, beta_t, g_t);

  // --- qk projection (8-phase 256^2) -> conv+norm -> qkB ---
  k_gemm8<0, 3><<<256, 512, 0, stream>>>(xh, xl, wsh, wsl, qkA, nullptr,
                                         NBT, 4096, NC, nullptr, nullptr, nullptr);
  k_convqk<<<NBT, 256, 0, stream>>>(qkA, conv_w, qkB);

  // --- v projection (vbuf overwrites qkA which is dead) ---
  k_cvt<true><<<N4X / 256, 256, 0, stream>>>(W_qkv + (size_t)4096 * NC, wsh, wsl, N4X);  // v rows
  k_gemm8<0, 3><<<256, 512, 0, stream>>>(xh, xl, wsh, wsl, vbuf, nullptr,
                                         NBT, 4096, NC, nullptr, nullptr, nullptr);

  // --- chunked scan (both batches) -> outr (overlays x/w planes, all dead) ---
  k_scanc<<<256, 512, 0, stream>>>(qkB, vbuf, conv_w, beta_t, g_t, outr);
  k_rms<<<NBT * NHV / 4, 256, 0, stream>>>(outr, rmsb);

  // --- z projection (2-pass) with fused gate epilogue -> om hi/lo planes ---
  k_cvt<true><<<N4X / 256, 256, 0, stream>>>(x, xh2, xl2, N4X);
  k_cvt<false><<<N4X / 256, 256, 0, stream>>>(W_z, wzh, nullptr, N4X);
  k_gemm8<2, 2><<<256, 512, 0, stream>>>(xh2, xl2, wzh, nullptr, omh, oml,
                                         NBT, VALD, NC, outr, rmsb, norm_w);

  // --- output projection (2-pass) -> f32 out ---
  k_cvt<false><<<N4X / 256, 256, 0, stream>>>(W_out, wouth, nullptr, N4X);
  k_gemm8<0, 2><<<128, 512, 0, stream>>>(omh, oml, wouth, nullptr, out, nullptr,
                                         NBT, NC, VALD, nullptr, nullptr, nullptr);
}

// Round 12
// 1193.815 us; speedup vs baseline: 2.5119x; 1.0095x over previous
//
#include <hip/hip_runtime.h>

typedef unsigned short u16;
typedef unsigned int u32;
typedef __attribute__((ext_vector_type(8))) short short8;
typedef __attribute__((ext_vector_type(4))) float f32x4;

#define NB 2
#define NT 2048
#define NC 2048
#define NHV 32
#define KEYD 2048
#define VALD 4096
#define QKVD 8192
#define NBT 4096
#define CL 64
#define NCH (NT / CL)

static __device__ __forceinline__ float bf2f(u16 u) {
  union { u32 u; float f; } x; x.u = ((u32)u) << 16; return x.f;
}
static __device__ __forceinline__ u16 f2bf(float f) {
  union { float f; u32 u; } x; x.f = f;
  u32 r = x.u + 0x7fffu + ((x.u >> 16) & 1u);
  return (u16)(r >> 16);
}
static __device__ __forceinline__ float sigm(float x) { return 1.0f / (1.0f + __expf(-x)); }

// ---------------- sentinel: ws too small marker ----------------
__global__ void k_sentinel(float* out) { out[0] = 1.0e6f; }

// ---------------- f32 -> bf16 hi (+ optional lo residual) planes ----------------
template <bool LO>
__global__ __launch_bounds__(256) void k_cvt(const float* __restrict__ in, u16* __restrict__ hi,
                                             u16* __restrict__ lo, int n4) {
  int i = blockIdx.x * 256 + threadIdx.x;
  if (i >= n4) return;
  float4 v = ((const float4*)in)[i];
  ushort4 h;
  h.x = f2bf(v.x); h.y = f2bf(v.y); h.z = f2bf(v.z); h.w = f2bf(v.w);
  ((ushort4*)hi)[i] = h;
  if constexpr (LO) {
    ushort4 l;
    l.x = f2bf(v.x - bf2f(h.x)); l.y = f2bf(v.y - bf2f(h.y));
    l.z = f2bf(v.z - bf2f(h.z)); l.w = f2bf(v.w - bf2f(h.w));
    ((ushort4*)lo)[i] = l;
  }
}

// ---------------- build padded W_ba hi/lo planes [128][2048] ----------------
__global__ __launch_bounds__(256) void k_wba(const float* __restrict__ Wb, const float* __restrict__ Wa,
                                             u16* __restrict__ hi, u16* __restrict__ lo) {
  int i = blockIdx.x * 256 + threadIdx.x;
  int r = i >> 11, c = i & 2047;
  float v = 0.f;
  if (r < 32) v = Wb[r * 2048 + c];
  else if (r < 64) v = Wa[(r - 32) * 2048 + c];
  u16 h = f2bf(v);
  hi[i] = h;
  lo[i] = f2bf(v - bf2f(h));
}

// ---------------- GEMM on pre-split bf16 planes: C = A[M][K] * B[N][K]^T ----------------
// PASSES 3: acc += AhBh + AlBh + AhBl (~f32). PASSES 2: acc += AhBh + AlBh (B single bf16).
// MODE 0: f32 out C0. MODE 2: z epilogue: o = e0(outr)*e1(rms)*e2(nw)*silu(acc) -> hi/lo planes C0,C1.
template <int MODE, int PASSES>
__global__ __launch_bounds__(256) void k_gemm_bf(const u16* __restrict__ Ahg, const u16* __restrict__ Alg,
                                                 const u16* __restrict__ Bhg, const u16* __restrict__ Blg,
                                                 void* __restrict__ C0, void* __restrict__ C1,
                                                 int M, int N, int K,
                                                 const float* __restrict__ e0, const float* __restrict__ e1,
                                                 const float* __restrict__ e2) {
  __shared__ __align__(16) u16 As_h[128 * 48];
  __shared__ __align__(16) u16 As_l[128 * 48];
  __shared__ __align__(16) u16 Bs_h[128 * 48];
  __shared__ __align__(16) u16 Bs_l[(PASSES == 3) ? 128 * 48 : 8];
  const int tid = threadIdx.x;
  const int lane = tid & 63, wave = tid >> 6;
  const int wr = wave >> 1, wc = wave & 1;
  const int l15 = lane & 15, l16 = lane >> 4;
  const int row0 = blockIdx.y * 128, col0 = blockIdx.x * 128;
  const int sr = tid >> 1, sk = (tid & 1) * 16;
  f32x4 acc[4][4] = {};
  for (int k0 = 0; k0 < K; k0 += 32) {
    const size_t aoff = (size_t)(row0 + sr) * K + k0 + sk;
    const size_t boff = (size_t)(col0 + sr) * K + k0 + sk;
    *(short8*)&As_h[sr * 48 + sk] = *(const short8*)&Ahg[aoff];
    *(short8*)&As_h[sr * 48 + sk + 8] = *(const short8*)&Ahg[aoff + 8];
    *(short8*)&As_l[sr * 48 + sk] = *(const short8*)&Alg[aoff];
    *(short8*)&As_l[sr * 48 + sk + 8] = *(const short8*)&Alg[aoff + 8];
    *(short8*)&Bs_h[sr * 48 + sk] = *(const short8*)&Bhg[boff];
    *(short8*)&Bs_h[sr * 48 + sk + 8] = *(const short8*)&Bhg[boff + 8];
    if constexpr (PASSES == 3) {
      *(short8*)&Bs_l[sr * 48 + sk] = *(const short8*)&Blg[boff];
      *(short8*)&Bs_l[sr * 48 + sk + 8] = *(const short8*)&Blg[boff + 8];
    }
    __syncthreads();
    short8 ah[4], al[4], bh[4], bl[4];
#pragma unroll
    for (int mi = 0; mi < 4; ++mi) {
      ah[mi] = *(short8*)&As_h[(wr * 64 + mi * 16 + l15) * 48 + l16 * 8];
      al[mi] = *(short8*)&As_l[(wr * 64 + mi * 16 + l15) * 48 + l16 * 8];
    }
#pragma unroll
    for (int ni = 0; ni < 4; ++ni) {
      bh[ni] = *(short8*)&Bs_h[(wc * 64 + ni * 16 + l15) * 48 + l16 * 8];
      if constexpr (PASSES == 3)
        bl[ni] = *(short8*)&Bs_l[(wc * 64 + ni * 16 + l15) * 48 + l16 * 8];
    }
#pragma unroll
    for (int mi = 0; mi < 4; ++mi)
#pragma unroll
      for (int ni = 0; ni < 4; ++ni) {
        acc[mi][ni] = __builtin_amdgcn_mfma_f32_16x16x32_bf16(ah[mi], bh[ni], acc[mi][ni], 0, 0, 0);
        acc[mi][ni] = __builtin_amdgcn_mfma_f32_16x16x32_bf16(al[mi], bh[ni], acc[mi][ni], 0, 0, 0);
        if constexpr (PASSES == 3)
          acc[mi][ni] = __builtin_amdgcn_mfma_f32_16x16x32_bf16(ah[mi], bl[ni], acc[mi][ni], 0, 0, 0);
      }
    __syncthreads();
  }
#pragma unroll
  for (int mi = 0; mi < 4; ++mi) {
#pragma unroll
    for (int ni = 0; ni < 4; ++ni) {
      int rr = row0 + wr * 64 + mi * 16 + l16 * 4;
      int cc = col0 + wc * 64 + ni * 16 + l15;
#pragma unroll
      for (int i = 0; i < 4; ++i) {
        float v = acc[mi][ni][i];
        size_t idx = (size_t)(rr + i) * N + cc;
        if constexpr (MODE == 0) {
          ((float*)C0)[idx] = v;
        } else {
          float zs = v * sigm(v);
          float o = e0[idx] * e1[(size_t)(rr + i) * 32 + (cc >> 7)] * e2[cc & 127] * zs;
          u16 hh = f2bf(o);
          ((u16*)C0)[idx] = hh;
          ((u16*)C1)[idx] = f2bf(o - bf2f(hh));
        }
      }
    }
  }
}

// ---------------- beta / g from ba [BT,128] f32, TRANSPOSED out [32][4096] ----------------
__global__ __launch_bounds__(256) void k_bg(const float* __restrict__ ba, const float* __restrict__ dt_bias,
                                            const float* __restrict__ A_log, float* __restrict__ beta_t,
                                            float* __restrict__ g_t) {
  int i = blockIdx.x * 256 + threadIdx.x;  // 0..131071
  int bt = i >> 5, h = i & 31;
  float bv = ba[(size_t)bt * 128 + h];
  float av = ba[(size_t)bt * 128 + 32 + h];
  beta_t[h * 4096 + bt] = sigm(bv);
  float xx = av + dt_bias[h];
  float sp = (xx > 20.f) ? xx : log1pf(__expf(xx));
  g_t[h * 4096 + bt] = -__expf(A_log[h]) * sp;
}

// ---------------- conv+SiLU+L2norm for q,k -> pre-split hi/lo bf16 planes ----------------
// f32 in [4096][4096]; out qkh/qkl planes [4096][4096] u16
__global__ __launch_bounds__(256) void k_convqk(const float* __restrict__ qkraw, const float* __restrict__ cw,
                                                u16* __restrict__ qkh, u16* __restrict__ qkl) {
  __shared__ float sval[4096];
  __shared__ float snrm[32];
  const int tid = threadIdx.x;
  const int bt = blockIdx.x;
  const int b = bt >> 11, t = bt & 2047;
  for (int i = 0; i < 16; ++i) {
    int c = i * 256 + tid;  // 0..4095 (q:0-2047, k:2048-4095)
    float acc = 0.f;
#pragma unroll
    for (int j = 0; j < 4; ++j) {
      int ts = t - 3 + j;
      if (ts >= 0) acc += cw[c * 4 + j] * qkraw[(size_t)(b * 2048 + ts) * 4096 + c];
    }
    sval[c] = acc * sigm(acc);
  }
  __syncthreads();
  {
    int gidx = tid >> 3, s = tid & 7;
    float ss = 0.f;
#pragma unroll
    for (int i2 = 0; i2 < 16; ++i2) { float v = sval[gidx * 128 + s * 16 + i2]; ss += v * v; }
    ss += __shfl_xor(ss, 1); ss += __shfl_xor(ss, 2); ss += __shfl_xor(ss, 4);
    if (s == 0) snrm[gidx] = 1.0f / fmaxf(sqrtf(ss), 1e-12f);
  }
  __syncthreads();
  for (int i = 0; i < 16; ++i) {
    int c = i * 256 + tid;
    float v = sval[c] * snrm[c >> 7];
    u16 hh = f2bf(v);
    qkh[(size_t)bt * 4096 + c] = hh;
    qkl[(size_t)bt * 4096 + c] = f2bf(v - bf2f(hh));
  }
}

// ---------------- chunked gated-linear-attention scan, MFMA, hi/lo-compensated ----------------
// grid 256 = dq(4) x h(32) x b(2); block 512 (8 waves). Chunk L=64, 32 chunks sequential.
// Q/K arrive pre-split (qkh/qkl planes): staging is pure short8 copies.
// State LDS copy stored as hi/lo bf16 planes (producer-rounded; identical values to consumer-rounding).
__global__ __launch_bounds__(512) void k_scanc(const u16* __restrict__ qkh, const u16* __restrict__ qkl,
                                               const float* __restrict__ vraw, const float* __restrict__ cw,
                                               const float* __restrict__ beta_t, const float* __restrict__ g_t,
                                               float* __restrict__ outr) {
  __shared__ __align__(16) u16 Qh[64][136], Ql[64][136], Kh[64][136], Kl[64][136];
  __shared__ __align__(16) u16 Vh[32][72], Vl[32][72];
  __shared__ __align__(16) u16 SIh[64][72], SIl[64][72];
  __shared__ __align__(16) u16 SH[2][32][132], SL[2][32][132];
  __shared__ float rv[67][33];
  __shared__ float garr[64], barr[64], warr[64], earr[64];
  __shared__ float sdt;

  const int tid = threadIdx.x;
  const int lane = tid & 63, wv = tid >> 6;
  const int l15 = lane & 15, l16 = lane >> 4;
  const int dq = blockIdx.x & 3, h = (blockIdx.x >> 2) & 31, b = blockIdx.x >> 7;
  const int bT = b * 2048;
  const int hk = h >> 1;
  const int dvl = tid & 31;
  const int vch = h * 128 + dq * 32;
  const float4 cwv = *(const float4*)&cw[(4096 + vch + dvl) * 4];
  const int mblk = wv & 3, nh = wv >> 2;
  const int m0 = mblk * 16;
  const int sr = tid >> 3, d0 = (tid & 7) * 16;
  const int r0v = tid >> 5;

  for (int i = tid; i < 2 * 32 * 132; i += 512) { ((u16*)SH)[i] = 0; ((u16*)SL)[i] = 0; }
  f32x4 st[2] = {};

  short8 pqh[2], pql[2], pkh[2], pkl[2];
  float pv[5];
  auto LOADQK = [&](int t0) {
    const size_t base = (size_t)(bT + t0 + sr) * 4096 + hk * 128 + d0;
    pqh[0] = *(const short8*)&qkh[base];        pqh[1] = *(const short8*)&qkh[base + 8];
    pql[0] = *(const short8*)&qkl[base];        pql[1] = *(const short8*)&qkl[base + 8];
    pkh[0] = *(const short8*)&qkh[base + 2048]; pkh[1] = *(const short8*)&qkh[base + 2056];
    pkl[0] = *(const short8*)&qkl[base + 2048]; pkl[1] = *(const short8*)&qkl[base + 2056];
  };
  auto LOADV = [&](int t0) {
#pragma unroll
    for (int i = 0; i < 5; ++i) {
      int r = r0v + i * 16;
      int tr = t0 - 3 + r;
      pv[i] = (r < 67 && tr >= 0) ? vraw[(size_t)(bT + tr) * 4096 + vch + dvl] : 0.f;
    }
  };

  LOADQK(0);
  LOADV(0);

  for (int ch = 0; ch < NCH; ++ch) {
    const int t0 = ch * CL;
    const int p = ch & 1;
    // ---- store prefetched Q,K planes and raw v rows to LDS (pure copies)
    *(short8*)&Qh[sr][d0] = pqh[0]; *(short8*)&Qh[sr][d0 + 8] = pqh[1];
    *(short8*)&Ql[sr][d0] = pql[0]; *(short8*)&Ql[sr][d0 + 8] = pql[1];
    *(short8*)&Kh[sr][d0] = pkh[0]; *(short8*)&Kh[sr][d0 + 8] = pkh[1];
    *(short8*)&Kl[sr][d0] = pkl[0]; *(short8*)&Kl[sr][d0 + 8] = pkl[1];
#pragma unroll
    for (int i = 0; i < 5; ++i) {
      int r = r0v + i * 16;
      if (r < 67) rv[r][dvl] = pv[i];
    }
    if (wv == 0) {
      float gv = g_t[h * 4096 + bT + t0 + lane];
      float bv = beta_t[h * 4096 + bT + t0 + lane];
      float cum = gv;
#pragma unroll
      for (int off = 1; off < 64; off <<= 1) {
        float o = __shfl_up(cum, off);
        if (lane >= off) cum += o;
      }
      float tot = __shfl(cum, 63);
      garr[lane] = cum;
      earr[lane] = __expf(cum);
      warr[lane] = __expf(tot - cum) * bv;
      barr[lane] = bv;
      if (lane == 0) sdt = __expf(tot);
    }
    __syncthreads();  // B1
    // ---- prefetch next chunk (latency hides under compute below)
    if (ch + 1 < NCH) {
      LOADQK(t0 + CL);
      LOADV(t0 + CL);
    }
    // ---- v conv + silu -> hi/lo transposed [dv][s]
    {
      int tl = tid >> 5;
#pragma unroll
      for (int rr = 0; rr < 4; ++rr) {
        int t = rr * 16 + tl;
        float a = cwv.x * rv[t][dvl] + cwv.y * rv[t + 1][dvl] + cwv.z * rv[t + 2][dvl] + cwv.w * rv[t + 3][dvl];
        a = a * sigm(a);
        u16 hi = f2bf(a);
        Vh[dvl][t] = hi;
        Vl[dvl][t] = f2bf(a - bf2f(hi));
      }
    }
    // ---- A = Q K^T (hi/lo, 3 terms); this wave: rows m0..m0+15, col blocks nh*2, nh*2+1
    short8 ah[4], al[4];
#pragma unroll
    for (int kk = 0; kk < 4; ++kk) {
      ah[kk] = *(short8*)&Qh[m0 + l15][l16 * 8 + kk * 32];
      al[kk] = *(short8*)&Ql[m0 + l15][l16 * 8 + kk * 32];
    }
#pragma unroll
    for (int j = 0; j < 2; ++j) {
      int n = nh * 2 + j;
      f32x4 a4 = {};
#pragma unroll
      for (int kk = 0; kk < 4; ++kk) {
        short8 bh_ = *(short8*)&Kh[n * 16 + l15][l16 * 8 + kk * 32];
        short8 bl_ = *(short8*)&Kl[n * 16 + l15][l16 * 8 + kk * 32];
        a4 = __builtin_amdgcn_mfma_f32_16x16x32_bf16(ah[kk], bh_, a4, 0, 0, 0);
        a4 = __builtin_amdgcn_mfma_f32_16x16x32_bf16(ah[kk], bl_, a4, 0, 0, 0);
        a4 = __builtin_amdgcn_mfma_f32_16x16x32_bf16(al[kk], bh_, a4, 0, 0, 0);
      }
      int col = n * 16 + l15;
      float gc = garr[col], bc = barr[col];
#pragma unroll
      for (int i = 0; i < 4; ++i) {
        int row = m0 + l16 * 4 + i;
        float cval = (col <= row) ? __expf(garr[row] - gc) * bc * a4[i] : 0.f;
        u16 hh = f2bf(cval);
        SIh[row][col] = hh;
        SIl[row][col] = f2bf(cval - bf2f(hh));
      }
    }
    __syncthreads();  // B2
    // ---- out_inter = Q @ St_prev (Q hi/lo x S hi/lo planes, 3 terms), scaled by e^{Gc[t]}
    f32x4 ao = {};
#pragma unroll
    for (int kk = 0; kk < 4; ++kk) {
      short8 sh8 = *(short8*)&SH[p][nh * 16 + l15][l16 * 8 + kk * 32];
      short8 sl8 = *(short8*)&SL[p][nh * 16 + l15][l16 * 8 + kk * 32];
      ao = __builtin_amdgcn_mfma_f32_16x16x32_bf16(ah[kk], sh8, ao, 0, 0, 0);
      ao = __builtin_amdgcn_mfma_f32_16x16x32_bf16(ah[kk], sl8, ao, 0, 0, 0);
      ao = __builtin_amdgcn_mfma_f32_16x16x32_bf16(al[kk], sh8, ao, 0, 0, 0);
    }
#pragma unroll
    for (int i = 0; i < 4; ++i) ao[i] *= earr[m0 + l16 * 4 + i];
    // ---- out += SI @ V (3 terms)
#pragma unroll
    for (int kk = 0; kk < 2; ++kk) {
      short8 asih = *(short8*)&SIh[m0 + l15][l16 * 8 + kk * 32];
      short8 asil = *(short8*)&SIl[m0 + l15][l16 * 8 + kk * 32];
      short8 bvh = *(short8*)&Vh[nh * 16 + l15][l16 * 8 + kk * 32];
      short8 bvl = *(short8*)&Vl[nh * 16 + l15][l16 * 8 + kk * 32];
      ao = __builtin_amdgcn_mfma_f32_16x16x32_bf16(asih, bvh, ao, 0, 0, 0);
      ao = __builtin_amdgcn_mfma_f32_16x16x32_bf16(asih, bvl, ao, 0, 0, 0);
      ao = __builtin_amdgcn_mfma_f32_16x16x32_bf16(asil, bvh, ao, 0, 0, 0);
    }
#pragma unroll
    for (int i = 0; i < 4; ++i)
      outr[(size_t)(bT + t0 + m0 + l16 * 4 + i) * 4096 + vch + nh * 16 + l15] = ao[i];
    // ---- state update: St = sdt*St + V^T (K.w); this wave: dk band wv*16
#pragma unroll
    for (int m = 0; m < 2; ++m)
#pragma unroll
      for (int i = 0; i < 4; ++i) st[m][i] *= sdt;
#pragma unroll
    for (int kk = 0; kk < 2; ++kk) {
      short8 bwh, bwl;
      {
        int dk = wv * 16 + l15;
#pragma unroll
        for (int e = 0; e < 8; ++e) {
          int s = l16 * 8 + e + kk * 32;
          float kvv = (bf2f(Kh[s][dk]) + bf2f(Kl[s][dk])) * warr[s];
          u16 hh = f2bf(kvv);
          bwh[e] = (short)hh;
          bwl[e] = (short)f2bf(kvv - bf2f(hh));
        }
      }
#pragma unroll
      for (int m = 0; m < 2; ++m) {
        short8 avh = *(short8*)&Vh[m * 16 + l15][l16 * 8 + kk * 32];
        short8 avl = *(short8*)&Vl[m * 16 + l15][l16 * 8 + kk * 32];
        st[m] = __builtin_amdgcn_mfma_f32_16x16x32_bf16(avh, bwh, st[m], 0, 0, 0);
        st[m] = __builtin_amdgcn_mfma_f32_16x16x32_bf16(avh, bwl, st[m], 0, 0, 0);
        st[m] = __builtin_amdgcn_mfma_f32_16x16x32_bf16(avl, bwh, st[m], 0, 0, 0);
      }
    }
    // ---- write state hi/lo planes for next chunk (producer-rounded)
#pragma unroll
    for (int m = 0; m < 2; ++m)
#pragma unroll
      for (int i = 0; i < 4; ++i) {
        float sv = st[m][i];
        u16 hh = f2bf(sv);
        SH[p ^ 1][m * 16 + l16 * 4 + i][wv * 16 + l15] = hh;
        SL[p ^ 1][m * 16 + l16 * 4 + i][wv * 16 + l15] = f2bf(sv - bf2f(hh));
      }
    __syncthreads();  // B4
  }
}

// ---------------- per-(bt,head) RMS scale from f32 outr ----------------
__global__ __launch_bounds__(256) void k_rms(const float* __restrict__ outr, float* __restrict__ rms) {
  int pair = blockIdx.x * 4 + (threadIdx.x >> 6);
  int lane = threadIdx.x & 63;
  float2 v = *(const float2*)&outr[(size_t)pair * 128 + lane * 2];
  float ss = v.x * v.x + v.y * v.y;
#pragma unroll
  for (int m = 1; m < 64; m <<= 1) ss += __shfl_xor(ss, m);
  if (lane == 0) rms[pair] = rsqrtf(ss * (1.0f / 128.0f) + 1e-6f);
}

extern "C" void kernel_launch(void* const* d_in, const int* in_sizes, int n_in,
                              void* d_out, int out_size, void* d_ws, size_t ws_size,
                              hipStream_t stream) {
  const float* x = (const float*)d_in[0];
  // d_in[1] = positions (int64) — unused by the math
  const float* W_qkv = (const float*)d_in[2];
  const float* W_z = (const float*)d_in[3];
  const float* W_b = (const float*)d_in[4];
  const float* W_a = (const float*)d_in[5];
  const float* conv_w = (const float*)d_in[6];
  const float* dt_bias = (const float*)d_in[7];
  const float* A_log = (const float*)d_in[8];
  const float* norm_w = (const float*)d_in[9];
  const float* W_out = (const float*)d_in[10];
  float* out = (float*)d_out;

  const size_t MB = 1ull << 20;
  const size_t need = 192 * MB + 3 * (size_t)NBT * 32 * 4;  // 202,899,456 B == proven bound
  if (ws_size < need) {
    k_sentinel<<<1, 1, 0, stream>>>(out);
    return;
  }
  char* ws = (char*)d_ws;
  // Region A [0,64MB): x planes + W-slot hi/lo planes; later outr f32; later wout hi
  u16* xh = (u16*)ws;
  u16* xl = (u16*)(ws + 16 * MB);
  u16* wsh = (u16*)(ws + 32 * MB);   // W_qkv qk-rows planes, then v-rows planes
  u16* wsl = (u16*)(ws + 48 * MB);
  float* outr = (float*)ws;
  u16* wouth = (u16*)ws;
  // Region B [64,128MB): early: wba planes + babuf; then qkB hi/lo planes; later om planes
  u16* wbah = (u16*)(ws + 64 * MB);
  u16* wbal = (u16*)(ws + 64 * MB + 512 * 1024);
  float* babuf = (float*)(ws + 65 * MB);
  u16* qkBh = (u16*)(ws + 64 * MB);
  u16* qkBl = (u16*)(ws + 96 * MB);
  u16* omh = (u16*)(ws + 64 * MB);
  u16* oml = (u16*)(ws + 96 * MB);
  // Region C [128,192MB): qkA f32; then vbuf f32; later x2 planes + wz hi
  float* qkA = (float*)(ws + 128 * MB);
  float* vbuf = (float*)(ws + 128 * MB);
  u16* xh2 = (u16*)(ws + 128 * MB);
  u16* xl2 = (u16*)(ws + 144 * MB);
  u16* wzh = (u16*)(ws + 160 * MB);
  float* beta_t = (float*)(ws + 192 * MB);
  float* g_t = beta_t + (size_t)NBT * 32;
  float* rmsb = g_t + (size_t)NBT * 32;

  const int N4X = NBT * NC / 4;
  // --- conversions + ba path (3-pass: recurrence path fully compensated) ---
  k_cvt<true><<<N4X / 256, 256, 0, stream>>>(x, xh, xl, N4X);
  k_cvt<true><<<N4X / 256, 256, 0, stream>>>(W_qkv, wsh, wsl, N4X);  // qk rows 0..4095
  k_wba<<<128 * NC / 256, 256, 0, stream>>>(W_b, W_a, wbah, wbal);
  k_gemm_bf<0, 3><<<dim3(1, NBT / 128), 256, 0, stream>>>(xh, xl, wbah, wbal, babuf, nullptr,
                                                          NBT, 128, NC, nullptr, nullptr, nullptr);
  k_bg<<<NBT * 32 / 256, 256, 0, stream>>>(babuf, dt_bias, A_log, beta_t, g_t);

  // --- qk projection (3-pass) -> conv+norm -> qkB hi/lo planes ---
  k_gemm_bf<0, 3><<<dim3(4096 / 128, NBT / 128), 256, 0, stream>>>(xh, xl, wsh, wsl, qkA, nullptr,
                                                                   NBT, 4096, NC, nullptr, nullptr, nullptr);
  k_convqk<<<NBT, 256, 0, stream>>>(qkA, conv_w, qkBh, qkBl);

  // --- v projection (3-pass; vbuf overwrites qkA which is dead) ---
  k_cvt<true><<<N4X / 256, 256, 0, stream>>>(W_qkv + (size_t)4096 * NC, wsh, wsl, N4X);  // v rows
  k_gemm_bf<0, 3><<<dim3(4096 / 128, NBT / 128), 256, 0, stream>>>(xh, xl, wsh, wsl, vbuf, nullptr,
                                                                   NBT, 4096, NC, nullptr, nullptr, nullptr);

  // --- chunked scan (both batches) -> outr (overlays x/w planes, all dead) ---
  k_scanc<<<256, 512, 0, stream>>>(qkBh, qkBl, vbuf, conv_w, beta_t, g_t, outr);
  k_rms<<<NBT * NHV / 4, 256, 0, stream>>>(outr, rmsb);

  // --- z projection (2-pass; proven harmless) with fused gate epilogue -> om hi/lo planes ---
  k_cvt<true><<<N4X / 256, 256, 0, stream>>>(x, xh2, xl2, N4X);
  k_cvt<false><<<N4X / 256, 256, 0, stream>>>(W_z, wzh, nullptr, N4X);
  k_gemm_bf<2, 2><<<dim3(VALD / 128, NBT / 128), 256, 0, stream>>>(xh2, xl2, wzh, nullptr, omh, oml,
                                                                   NBT, VALD, NC, outr, rmsb, norm_w);

  // --- output projection (2-pass; proven harmless) -> f32 out ---
  k_cvt<false><<<N4X / 256, 256, 0, stream>>>(W_out, wouth, nullptr, N4X);
  k_gemm_bf<0, 2><<<dim3(NC / 128, NBT / 128), 256, 0, stream>>>(omh, oml, wouth, nullptr, out, nullptr,
                                                                 NBT, NC, VALD, nullptr, nullptr, nullptr);
}

// Round 13
// 1081.355 us; speedup vs baseline: 2.7732x; 1.1040x over previous
//
#include <hip/hip_runtime.h>

typedef unsigned short u16;
typedef unsigned int u32;
typedef __attribute__((ext_vector_type(8))) short short8;
typedef __attribute__((ext_vector_type(4))) float f32x4;

#define NB 2
#define NT 2048
#define NC 2048
#define NHV 32
#define KEYD 2048
#define VALD 4096
#define QKVD 8192
#define NBT 4096
#define CL 64
#define NCH (NT / CL)

static __device__ __forceinline__ float bf2f(u16 u) {
  union { u32 u; float f; } x; x.u = ((u32)u) << 16; return x.f;
}
static __device__ __forceinline__ u16 f2bf(float f) {
  union { float f; u32 u; } x; x.f = f;
  u32 r = x.u + 0x7fffu + ((x.u >> 16) & 1u);
  return (u16)(r >> 16);
}
static __device__ __forceinline__ float sigm(float x) { return 1.0f / (1.0f + __expf(-x)); }
// LDS chunk-XOR swizzle for stride-48 u16 rows: chunk(16B) index ^= (row>>2)&3.
// Makes wave64 ds_read_b128 at row-stride 96B bank-balanced (was 4-way conflicted).
static __device__ __forceinline__ int ldsoff(int row, int c8) {
  return row * 48 + ((c8 ^ ((row >> 2) & 3)) << 3);
}

// ---------------- sentinel: ws too small marker ----------------
__global__ void k_sentinel(float* out) { out[0] = 1.0e6f; }

// ---------------- f32 -> bf16 hi (+ optional lo residual) planes ----------------
template <bool LO>
__global__ __launch_bounds__(256) void k_cvt(const float* __restrict__ in, u16* __restrict__ hi,
                                             u16* __restrict__ lo, int n4) {
  int i = blockIdx.x * 256 + threadIdx.x;
  if (i >= n4) return;
  float4 v = ((const float4*)in)[i];
  ushort4 h;
  h.x = f2bf(v.x); h.y = f2bf(v.y); h.z = f2bf(v.z); h.w = f2bf(v.w);
  ((ushort4*)hi)[i] = h;
  if constexpr (LO) {
    ushort4 l;
    l.x = f2bf(v.x - bf2f(h.x)); l.y = f2bf(v.y - bf2f(h.y));
    l.z = f2bf(v.z - bf2f(h.z)); l.w = f2bf(v.w - bf2f(h.w));
    ((ushort4*)lo)[i] = l;
  }
}

// ---------------- build padded W_ba hi/lo planes [128][2048] ----------------
__global__ __launch_bounds__(256) void k_wba(const float* __restrict__ Wb, const float* __restrict__ Wa,
                                             u16* __restrict__ hi, u16* __restrict__ lo) {
  int i = blockIdx.x * 256 + threadIdx.x;
  int r = i >> 11, c = i & 2047;
  float v = 0.f;
  if (r < 32) v = Wb[r * 2048 + c];
  else if (r < 64) v = Wa[(r - 32) * 2048 + c];
  u16 h = f2bf(v);
  hi[i] = h;
  lo[i] = f2bf(v - bf2f(h));
}

// ---------------- GEMM on pre-split bf16 planes: C = A[M][K] * B[N][K]^T ----------------
// PASSES 3: AhBh + AlBh + AhBl (~f32). PASSES 2: AhBh + AlBh (B single). PASSES 1: AhBh.
// MODE 0: f32 out C0. MODE 2: z epilogue: o = e0(outr)*e1(rms)*e2(nw)*silu(acc) -> bf16 C0 (hi only).
template <int MODE, int PASSES>
__global__ __launch_bounds__(256) void k_gemm_bf(const u16* __restrict__ Ahg, const u16* __restrict__ Alg,
                                                 const u16* __restrict__ Bhg, const u16* __restrict__ Blg,
                                                 void* __restrict__ C0, void* __restrict__ C1,
                                                 int M, int N, int K,
                                                 const float* __restrict__ e0, const float* __restrict__ e1,
                                                 const float* __restrict__ e2) {
  __shared__ __align__(16) u16 As_h[128 * 48];
  __shared__ __align__(16) u16 As_l[(PASSES >= 2) ? 128 * 48 : 8];
  __shared__ __align__(16) u16 Bs_h[128 * 48];
  __shared__ __align__(16) u16 Bs_l[(PASSES == 3) ? 128 * 48 : 8];
  const int tid = threadIdx.x;
  const int lane = tid & 63, wave = tid >> 6;
  const int wr = wave >> 1, wc = wave & 1;
  const int l15 = lane & 15, l16 = lane >> 4;
  const int row0 = blockIdx.y * 128, col0 = blockIdx.x * 128;
  const int sr = tid >> 1, sk = (tid & 1) * 16;
  const int c0 = sk >> 3;  // chunk index 0 or 2
  const int w0 = ldsoff(sr, c0), w1 = ldsoff(sr, c0 + 1);
  f32x4 acc[4][4] = {};
  for (int k0 = 0; k0 < K; k0 += 32) {
    const size_t aoff = (size_t)(row0 + sr) * K + k0 + sk;
    const size_t boff = (size_t)(col0 + sr) * K + k0 + sk;
    *(short8*)&As_h[w0] = *(const short8*)&Ahg[aoff];
    *(short8*)&As_h[w1] = *(const short8*)&Ahg[aoff + 8];
    if constexpr (PASSES >= 2) {
      *(short8*)&As_l[w0] = *(const short8*)&Alg[aoff];
      *(short8*)&As_l[w1] = *(const short8*)&Alg[aoff + 8];
    }
    *(short8*)&Bs_h[w0] = *(const short8*)&Bhg[boff];
    *(short8*)&Bs_h[w1] = *(const short8*)&Bhg[boff + 8];
    if constexpr (PASSES == 3) {
      *(short8*)&Bs_l[w0] = *(const short8*)&Blg[boff];
      *(short8*)&Bs_l[w1] = *(const short8*)&Blg[boff + 8];
    }
    __syncthreads();
    short8 ah[4], al[4], bh[4], bl[4];
#pragma unroll
    for (int mi = 0; mi < 4; ++mi) {
      int off = ldsoff(wr * 64 + mi * 16 + l15, l16);
      ah[mi] = *(short8*)&As_h[off];
      if constexpr (PASSES >= 2) al[mi] = *(short8*)&As_l[off];
    }
#pragma unroll
    for (int ni = 0; ni < 4; ++ni) {
      int off = ldsoff(wc * 64 + ni * 16 + l15, l16);
      bh[ni] = *(short8*)&Bs_h[off];
      if constexpr (PASSES == 3) bl[ni] = *(short8*)&Bs_l[off];
    }
#pragma unroll
    for (int mi = 0; mi < 4; ++mi)
#pragma unroll
      for (int ni = 0; ni < 4; ++ni) {
        acc[mi][ni] = __builtin_amdgcn_mfma_f32_16x16x32_bf16(ah[mi], bh[ni], acc[mi][ni], 0, 0, 0);
        if constexpr (PASSES >= 2)
          acc[mi][ni] = __builtin_amdgcn_mfma_f32_16x16x32_bf16(al[mi], bh[ni], acc[mi][ni], 0, 0, 0);
        if constexpr (PASSES == 3)
          acc[mi][ni] = __builtin_amdgcn_mfma_f32_16x16x32_bf16(ah[mi], bl[ni], acc[mi][ni], 0, 0, 0);
      }
    __syncthreads();
  }
#pragma unroll
  for (int mi = 0; mi < 4; ++mi) {
#pragma unroll
    for (int ni = 0; ni < 4; ++ni) {
      int rr = row0 + wr * 64 + mi * 16 + l16 * 4;
      int cc = col0 + wc * 64 + ni * 16 + l15;
#pragma unroll
      for (int i = 0; i < 4; ++i) {
        float v = acc[mi][ni][i];
        size_t idx = (size_t)(rr + i) * N + cc;
        if constexpr (MODE == 0) {
          ((float*)C0)[idx] = v;
        } else {
          float zs = v * sigm(v);
          float o = e0[idx] * e1[(size_t)(rr + i) * 32 + (cc >> 7)] * e2[cc & 127] * zs;
          ((u16*)C0)[idx] = f2bf(o);
        }
      }
    }
  }
}

// ---------------- beta / g from ba [BT,128] f32, TRANSPOSED out [32][4096] ----------------
__global__ __launch_bounds__(256) void k_bg(const float* __restrict__ ba, const float* __restrict__ dt_bias,
                                            const float* __restrict__ A_log, float* __restrict__ beta_t,
                                            float* __restrict__ g_t) {
  int i = blockIdx.x * 256 + threadIdx.x;  // 0..131071
  int bt = i >> 5, h = i & 31;
  float bv = ba[(size_t)bt * 128 + h];
  float av = ba[(size_t)bt * 128 + 32 + h];
  beta_t[h * 4096 + bt] = sigm(bv);
  float xx = av + dt_bias[h];
  float sp = (xx > 20.f) ? xx : log1pf(__expf(xx));
  g_t[h * 4096 + bt] = -__expf(A_log[h]) * sp;
}

// ---------------- conv+SiLU+L2norm for q,k -> pre-split hi/lo bf16 planes ----------------
__global__ __launch_bounds__(256) void k_convqk(const float* __restrict__ qkraw, const float* __restrict__ cw,
                                                u16* __restrict__ qkh, u16* __restrict__ qkl) {
  __shared__ float sval[4096];
  __shared__ float snrm[32];
  const int tid = threadIdx.x;
  const int bt = blockIdx.x;
  const int b = bt >> 11, t = bt & 2047;
  for (int i = 0; i < 16; ++i) {
    int c = i * 256 + tid;  // 0..4095 (q:0-2047, k:2048-4095)
    float acc = 0.f;
#pragma unroll
    for (int j = 0; j < 4; ++j) {
      int ts = t - 3 + j;
      if (ts >= 0) acc += cw[c * 4 + j] * qkraw[(size_t)(b * 2048 + ts) * 4096 + c];
    }
    sval[c] = acc * sigm(acc);
  }
  __syncthreads();
  {
    int gidx = tid >> 3, s = tid & 7;
    float ss = 0.f;
#pragma unroll
    for (int i2 = 0; i2 < 16; ++i2) { float v = sval[gidx * 128 + s * 16 + i2]; ss += v * v; }
    ss += __shfl_xor(ss, 1); ss += __shfl_xor(ss, 2); ss += __shfl_xor(ss, 4);
    if (s == 0) snrm[gidx] = 1.0f / fmaxf(sqrtf(ss), 1e-12f);
  }
  __syncthreads();
  for (int i = 0; i < 16; ++i) {
    int c = i * 256 + tid;
    float v = sval[c] * snrm[c >> 7];
    u16 hh = f2bf(v);
    qkh[(size_t)bt * 4096 + c] = hh;
    qkl[(size_t)bt * 4096 + c] = f2bf(v - bf2f(hh));
  }
}

// ---------------- chunked gated-linear-attention scan, MFMA, hi/lo-compensated ----------------
// grid 256 = dq(4) x h(32) x b(2); block 512 (8 waves). Chunk L=64, 32 chunks sequential.
__global__ __launch_bounds__(512) void k_scanc(const u16* __restrict__ qkh, const u16* __restrict__ qkl,
                                               const float* __restrict__ vraw, const float* __restrict__ cw,
                                               const float* __restrict__ beta_t, const float* __restrict__ g_t,
                                               float* __restrict__ outr) {
  __shared__ __align__(16) u16 Qh[64][136], Ql[64][136], Kh[64][136], Kl[64][136];
  __shared__ __align__(16) u16 Vh[32][72], Vl[32][72];
  __shared__ __align__(16) u16 SIh[64][72], SIl[64][72];
  __shared__ __align__(16) u16 SH[2][32][132], SL[2][32][132];
  __shared__ float rv[67][33];
  __shared__ float garr[64], barr[64], warr[64], earr[64];
  __shared__ float sdt;

  const int tid = threadIdx.x;
  const int lane = tid & 63, wv = tid >> 6;
  const int l15 = lane & 15, l16 = lane >> 4;
  const int dq = blockIdx.x & 3, h = (blockIdx.x >> 2) & 31, b = blockIdx.x >> 7;
  const int bT = b * 2048;
  const int hk = h >> 1;
  const int dvl = tid & 31;
  const int vch = h * 128 + dq * 32;
  const float4 cwv = *(const float4*)&cw[(4096 + vch + dvl) * 4];
  const int mblk = wv & 3, nh = wv >> 2;
  const int m0 = mblk * 16;
  const int sr = tid >> 3, d0 = (tid & 7) * 16;
  const int r0v = tid >> 5;

  for (int i = tid; i < 2 * 32 * 132; i += 512) { ((u16*)SH)[i] = 0; ((u16*)SL)[i] = 0; }
  f32x4 st[2] = {};

  short8 pqh[2], pql[2], pkh[2], pkl[2];
  float pv[5];
  auto LOADQK = [&](int t0) {
    const size_t base = (size_t)(bT + t0 + sr) * 4096 + hk * 128 + d0;
    pqh[0] = *(const short8*)&qkh[base];        pqh[1] = *(const short8*)&qkh[base + 8];
    pql[0] = *(const short8*)&qkl[base];        pql[1] = *(const short8*)&qkl[base + 8];
    pkh[0] = *(const short8*)&qkh[base + 2048]; pkh[1] = *(const short8*)&qkh[base + 2056];
    pkl[0] = *(const short8*)&qkl[base + 2048]; pkl[1] = *(const short8*)&qkl[base + 2056];
  };
  auto LOADV = [&](int t0) {
#pragma unroll
    for (int i = 0; i < 5; ++i) {
      int r = r0v + i * 16;
      int tr = t0 - 3 + r;
      pv[i] = (r < 67 && tr >= 0) ? vraw[(size_t)(bT + tr) * 4096 + vch + dvl] : 0.f;
    }
  };

  LOADQK(0);
  LOADV(0);

  for (int ch = 0; ch < NCH; ++ch) {
    const int t0 = ch * CL;
    const int p = ch & 1;
    *(short8*)&Qh[sr][d0] = pqh[0]; *(short8*)&Qh[sr][d0 + 8] = pqh[1];
    *(short8*)&Ql[sr][d0] = pql[0]; *(short8*)&Ql[sr][d0 + 8] = pql[1];
    *(short8*)&Kh[sr][d0] = pkh[0]; *(short8*)&Kh[sr][d0 + 8] = pkh[1];
    *(short8*)&Kl[sr][d0] = pkl[0]; *(short8*)&Kl[sr][d0 + 8] = pkl[1];
#pragma unroll
    for (int i = 0; i < 5; ++i) {
      int r = r0v + i * 16;
      if (r < 67) rv[r][dvl] = pv[i];
    }
    if (wv == 0) {
      float gv = g_t[h * 4096 + bT + t0 + lane];
      float bv = beta_t[h * 4096 + bT + t0 + lane];
      float cum = gv;
#pragma unroll
      for (int off = 1; off < 64; off <<= 1) {
        float o = __shfl_up(cum, off);
        if (lane >= off) cum += o;
      }
      float tot = __shfl(cum, 63);
      garr[lane] = cum;
      earr[lane] = __expf(cum);
      warr[lane] = __expf(tot - cum) * bv;
      barr[lane] = bv;
      if (lane == 0) sdt = __expf(tot);
    }
    __syncthreads();  // B1
    if (ch + 1 < NCH) {
      LOADQK(t0 + CL);
      LOADV(t0 + CL);
    }
    {
      int tl = tid >> 5;
#pragma unroll
      for (int rr = 0; rr < 4; ++rr) {
        int t = rr * 16 + tl;
        float a = cwv.x * rv[t][dvl] + cwv.y * rv[t + 1][dvl] + cwv.z * rv[t + 2][dvl] + cwv.w * rv[t + 3][dvl];
        a = a * sigm(a);
        u16 hi = f2bf(a);
        Vh[dvl][t] = hi;
        Vl[dvl][t] = f2bf(a - bf2f(hi));
      }
    }
    short8 ah[4], al[4];
#pragma unroll
    for (int kk = 0; kk < 4; ++kk) {
      ah[kk] = *(short8*)&Qh[m0 + l15][l16 * 8 + kk * 32];
      al[kk] = *(short8*)&Ql[m0 + l15][l16 * 8 + kk * 32];
    }
#pragma unroll
    for (int j = 0; j < 2; ++j) {
      int n = nh * 2 + j;
      f32x4 a4 = {};
#pragma unroll
      for (int kk = 0; kk < 4; ++kk) {
        short8 bh_ = *(short8*)&Kh[n * 16 + l15][l16 * 8 + kk * 32];
        short8 bl_ = *(short8*)&Kl[n * 16 + l15][l16 * 8 + kk * 32];
        a4 = __builtin_amdgcn_mfma_f32_16x16x32_bf16(ah[kk], bh_, a4, 0, 0, 0);
        a4 = __builtin_amdgcn_mfma_f32_16x16x32_bf16(ah[kk], bl_, a4, 0, 0, 0);
        a4 = __builtin_amdgcn_mfma_f32_16x16x32_bf16(al[kk], bh_, a4, 0, 0, 0);
      }
      int col = n * 16 + l15;
      float gc = garr[col], bc = barr[col];
#pragma unroll
      for (int i = 0; i < 4; ++i) {
        int row = m0 + l16 * 4 + i;
        float cval = (col <= row) ? __expf(garr[row] - gc) * bc * a4[i] : 0.f;
        u16 hh = f2bf(cval);
        SIh[row][col] = hh;
        SIl[row][col] = f2bf(cval - bf2f(hh));
      }
    }
    __syncthreads();  // B2
    f32x4 ao = {};
#pragma unroll
    for (int kk = 0; kk < 4; ++kk) {
      short8 sh8 = *(short8*)&SH[p][nh * 16 + l15][l16 * 8 + kk * 32];
      short8 sl8 = *(short8*)&SL[p][nh * 16 + l15][l16 * 8 + kk * 32];
      ao = __builtin_amdgcn_mfma_f32_16x16x32_bf16(ah[kk], sh8, ao, 0, 0, 0);
      ao = __builtin_amdgcn_mfma_f32_16x16x32_bf16(ah[kk], sl8, ao, 0, 0, 0);
      ao = __builtin_amdgcn_mfma_f32_16x16x32_bf16(al[kk], sh8, ao, 0, 0, 0);
    }
#pragma unroll
    for (int i = 0; i < 4; ++i) ao[i] *= earr[m0 + l16 * 4 + i];
#pragma unroll
    for (int kk = 0; kk < 2; ++kk) {
      short8 asih = *(short8*)&SIh[m0 + l15][l16 * 8 + kk * 32];
      short8 asil = *(short8*)&SIl[m0 + l15][l16 * 8 + kk * 32];
      short8 bvh = *(short8*)&Vh[nh * 16 + l15][l16 * 8 + kk * 32];
      short8 bvl = *(short8*)&Vl[nh * 16 + l15][l16 * 8 + kk * 32];
      ao = __builtin_amdgcn_mfma_f32_16x16x32_bf16(asih, bvh, ao, 0, 0, 0);
      ao = __builtin_amdgcn_mfma_f32_16x16x32_bf16(asih, bvl, ao, 0, 0, 0);
      ao = __builtin_amdgcn_mfma_f32_16x16x32_bf16(asil, bvh, ao, 0, 0, 0);
    }
#pragma unroll
    for (int i = 0; i < 4; ++i)
      outr[(size_t)(bT + t0 + m0 + l16 * 4 + i) * 4096 + vch + nh * 16 + l15] = ao[i];
#pragma unroll
    for (int m = 0; m < 2; ++m)
#pragma unroll
      for (int i = 0; i < 4; ++i) st[m][i] *= sdt;
#pragma unroll
    for (int kk = 0; kk < 2; ++kk) {
      short8 bwh, bwl;
      {
        int dk = wv * 16 + l15;
#pragma unroll
        for (int e = 0; e < 8; ++e) {
          int s = l16 * 8 + e + kk * 32;
          float kvv = (bf2f(Kh[s][dk]) + bf2f(Kl[s][dk])) * warr[s];
          u16 hh = f2bf(kvv);
          bwh[e] = (short)hh;
          bwl[e] = (short)f2bf(kvv - bf2f(hh));
        }
      }
#pragma unroll
      for (int m = 0; m < 2; ++m) {
        short8 avh = *(short8*)&Vh[m * 16 + l15][l16 * 8 + kk * 32];
        short8 avl = *(short8*)&Vl[m * 16 + l15][l16 * 8 + kk * 32];
        st[m] = __builtin_amdgcn_mfma_f32_16x16x32_bf16(avh, bwh, st[m], 0, 0, 0);
        st[m] = __builtin_amdgcn_mfma_f32_16x16x32_bf16(avh, bwl, st[m], 0, 0, 0);
        st[m] = __builtin_amdgcn_mfma_f32_16x16x32_bf16(avl, bwh, st[m], 0, 0, 0);
      }
    }
#pragma unroll
    for (int m = 0; m < 2; ++m)
#pragma unroll
      for (int i = 0; i < 4; ++i) {
        float sv = st[m][i];
        u16 hh = f2bf(sv);
        SH[p ^ 1][m * 16 + l16 * 4 + i][wv * 16 + l15] = hh;
        SL[p ^ 1][m * 16 + l16 * 4 + i][wv * 16 + l15] = f2bf(sv - bf2f(hh));
      }
    __syncthreads();  // B4
  }
}

// ---------------- per-(bt,head) RMS scale from f32 outr ----------------
__global__ __launch_bounds__(256) void k_rms(const float* __restrict__ outr, float* __restrict__ rms) {
  int pair = blockIdx.x * 4 + (threadIdx.x >> 6);
  int lane = threadIdx.x & 63;
  float2 v = *(const float2*)&outr[(size_t)pair * 128 + lane * 2];
  float ss = v.x * v.x + v.y * v.y;
#pragma unroll
  for (int m = 1; m < 64; m <<= 1) ss += __shfl_xor(ss, m);
  if (lane == 0) rms[pair] = rsqrtf(ss * (1.0f / 128.0f) + 1e-6f);
}

extern "C" void kernel_launch(void* const* d_in, const int* in_sizes, int n_in,
                              void* d_out, int out_size, void* d_ws, size_t ws_size,
                              hipStream_t stream) {
  const float* x = (const float*)d_in[0];
  // d_in[1] = positions (int64) — unused by the math
  const float* W_qkv = (const float*)d_in[2];
  const float* W_z = (const float*)d_in[3];
  const float* W_b = (const float*)d_in[4];
  const float* W_a = (const float*)d_in[5];
  const float* conv_w = (const float*)d_in[6];
  const float* dt_bias = (const float*)d_in[7];
  const float* A_log = (const float*)d_in[8];
  const float* norm_w = (const float*)d_in[9];
  const float* W_out = (const float*)d_in[10];
  float* out = (float*)d_out;

  const size_t MB = 1ull << 20;
  const size_t need = 192 * MB + 3 * (size_t)NBT * 32 * 4;  // 202,899,456 B == proven bound
  if (ws_size < need) {
    k_sentinel<<<1, 1, 0, stream>>>(out);
    return;
  }
  char* ws = (char*)d_ws;
  // Region A [0,64MB): x planes + W-slot hi/lo planes; later outr f32; later wout hi
  u16* xh = (u16*)ws;
  u16* xl = (u16*)(ws + 16 * MB);
  u16* wsh = (u16*)(ws + 32 * MB);   // W_qkv qk-rows planes, then v-rows planes
  u16* wsl = (u16*)(ws + 48 * MB);
  float* outr = (float*)ws;
  u16* wouth = (u16*)ws;
  // Region B [64,128MB): early: wba planes + babuf; then qkB hi/lo planes; later omat hi plane
  u16* wbah = (u16*)(ws + 64 * MB);
  u16* wbal = (u16*)(ws + 64 * MB + 512 * 1024);
  float* babuf = (float*)(ws + 65 * MB);
  u16* qkBh = (u16*)(ws + 64 * MB);
  u16* qkBl = (u16*)(ws + 96 * MB);
  u16* omh = (u16*)(ws + 64 * MB);
  // Region C [128,192MB): qkA f32; then vbuf f32; later x2 hi plane + wz hi
  float* qkA = (float*)(ws + 128 * MB);
  float* vbuf = (float*)(ws + 128 * MB);
  u16* xh2 = (u16*)(ws + 128 * MB);
  u16* wzh = (u16*)(ws + 160 * MB);
  float* beta_t = (float*)(ws + 192 * MB);
  float* g_t = beta_t + (size_t)NBT * 32;
  float* rmsb = g_t + (size_t)NBT * 32;

  const int N4X = NBT * NC / 4;
  // --- conversions + ba path (3-pass: recurrence path fully compensated) ---
  k_cvt<true><<<N4X / 256, 256, 0, stream>>>(x, xh, xl, N4X);
  k_cvt<true><<<N4X / 256, 256, 0, stream>>>(W_qkv, wsh, wsl, N4X);  // qk rows 0..4095
  k_wba<<<128 * NC / 256, 256, 0, stream>>>(W_b, W_a, wbah, wbal);
  k_gemm_bf<0, 3><<<dim3(1, NBT / 128), 256, 0, stream>>>(xh, xl, wbah, wbal, babuf, nullptr,
                                                          NBT, 128, NC, nullptr, nullptr, nullptr);
  k_bg<<<NBT * 32 / 256, 256, 0, stream>>>(babuf, dt_bias, A_log, beta_t, g_t);

  // --- qk projection (3-pass) -> conv+norm -> qkB hi/lo planes ---
  k_gemm_bf<0, 3><<<dim3(4096 / 128, NBT / 128), 256, 0, stream>>>(xh, xl, wsh, wsl, qkA, nullptr,
                                                                   NBT, 4096, NC, nullptr, nullptr, nullptr);
  k_convqk<<<NBT, 256, 0, stream>>>(qkA, conv_w, qkBh, qkBl);

  // --- v projection (3-pass; vbuf overwrites qkA which is dead) ---
  k_cvt<true><<<N4X / 256, 256, 0, stream>>>(W_qkv + (size_t)4096 * NC, wsh, wsl, N4X);  // v rows
  k_gemm_bf<0, 3><<<dim3(4096 / 128, NBT / 128), 256, 0, stream>>>(xh, xl, wsh, wsl, vbuf, nullptr,
                                                                   NBT, 4096, NC, nullptr, nullptr, nullptr);

  // --- chunked scan (both batches) -> outr (overlays x/w planes, all dead) ---
  k_scanc<<<256, 512, 0, stream>>>(qkBh, qkBl, vbuf, conv_w, beta_t, g_t, outr);
  k_rms<<<NBT * NHV / 4, 256, 0, stream>>>(outr, rmsb);

  // --- z projection (1-pass; non-recurrent path, anchored by 2-pass-at-floor evidence) ---
  k_cvt<false><<<N4X / 256, 256, 0, stream>>>(x, xh2, nullptr, N4X);
  k_cvt<false><<<N4X / 256, 256, 0, stream>>>(W_z, wzh, nullptr, N4X);
  k_gemm_bf<2, 1><<<dim3(VALD / 128, NBT / 128), 256, 0, stream>>>(xh2, nullptr, wzh, nullptr, omh, nullptr,
                                                                   NBT, VALD, NC, outr, rmsb, norm_w);

  // --- output projection (1-pass) -> f32 out ---
  k_cvt<false><<<N4X / 256, 256, 0, stream>>>(W_out, wouth, nullptr, N4X);
  k_gemm_bf<0, 1><<<dim3(NC / 128, NBT / 128), 256, 0, stream>>>(omh, nullptr, wouth, nullptr, out, nullptr,
                                                                 NBT, NC, VALD, nullptr, nullptr, nullptr);
}

// Round 14
// 859.695 us; speedup vs baseline: 3.4882x; 1.2578x over previous
//
#include <hip/hip_runtime.h>

typedef unsigned short u16;
typedef unsigned int u32;
typedef __attribute__((ext_vector_type(8))) short short8;
typedef __attribute__((ext_vector_type(8))) _Float16 half8;
typedef __attribute__((ext_vector_type(4))) float f32x4;

#define NB 2
#define NT 2048
#define NC 2048
#define NHV 32
#define KEYD 2048
#define VALD 4096
#define QKVD 8192
#define NBT 4096
#define CL 64
#define NCH (NT / CL)

static __device__ __forceinline__ float bf2f(u16 u) {
  union { u32 u; float f; } x; x.u = ((u32)u) << 16; return x.f;
}
static __device__ __forceinline__ u16 f2bf(float f) {
  union { float f; u32 u; } x; x.f = f;
  u32 r = x.u + 0x7fffu + ((x.u >> 16) & 1u);
  return (u16)(r >> 16);
}
static __device__ __forceinline__ u16 f2h(float f) {
  union { _Float16 h; u16 u; } c; c.h = (_Float16)f; return c.u;
}
static __device__ __forceinline__ float sigm(float x) { return 1.0f / (1.0f + __expf(-x)); }
// LDS offset map for stride-48 u16 rows (kept from r13; reads verified bank-balanced)
static __device__ __forceinline__ int ldsoff(int row, int c8) {
  return row * 48 + ((c8 ^ ((row >> 2) & 3)) << 3);
}

// ---------------- sentinel: ws too small marker ----------------
__global__ void k_sentinel(float* out) { out[0] = 1.0e6f; }

// ---------------- f32 -> bf16 hi (+ optional lo residual) planes ----------------
template <bool LO>
__global__ __launch_bounds__(256) void k_cvt(const float* __restrict__ in, u16* __restrict__ hi,
                                             u16* __restrict__ lo, int n4) {
  int i = blockIdx.x * 256 + threadIdx.x;
  if (i >= n4) return;
  float4 v = ((const float4*)in)[i];
  ushort4 h;
  h.x = f2bf(v.x); h.y = f2bf(v.y); h.z = f2bf(v.z); h.w = f2bf(v.w);
  ((ushort4*)hi)[i] = h;
  if constexpr (LO) {
    ushort4 l;
    l.x = f2bf(v.x - bf2f(h.x)); l.y = f2bf(v.y - bf2f(h.y));
    l.z = f2bf(v.z - bf2f(h.z)); l.w = f2bf(v.w - bf2f(h.w));
    ((ushort4*)lo)[i] = l;
  }
}

// ---------------- f32 -> fp16 plane ----------------
__global__ __launch_bounds__(256) void k_cvt16(const float* __restrict__ in, u16* __restrict__ out, int n4) {
  int i = blockIdx.x * 256 + threadIdx.x;
  if (i >= n4) return;
  float4 v = ((const float4*)in)[i];
  ushort4 o;
  o.x = f2h(v.x); o.y = f2h(v.y); o.z = f2h(v.z); o.w = f2h(v.w);
  ((ushort4*)out)[i] = o;
}

// ---------------- build padded W_ba hi/lo bf16 planes [128][2048] ----------------
__global__ __launch_bounds__(256) void k_wba(const float* __restrict__ Wb, const float* __restrict__ Wa,
                                             u16* __restrict__ hi, u16* __restrict__ lo) {
  int i = blockIdx.x * 256 + threadIdx.x;
  int r = i >> 11, c = i & 2047;
  float v = 0.f;
  if (r < 32) v = Wb[r * 2048 + c];
  else if (r < 64) v = Wa[(r - 32) * 2048 + c];
  u16 h = f2bf(v);
  hi[i] = h;
  lo[i] = f2bf(v - bf2f(h));
}

// ---------------- 3-pass bf16 GEMM (ba projection only; recurrence-gate path) ----------------
__global__ __launch_bounds__(256) void k_gemm_bf3(const u16* __restrict__ Ahg, const u16* __restrict__ Alg,
                                                  const u16* __restrict__ Bhg, const u16* __restrict__ Blg,
                                                  float* __restrict__ C0, int M, int N, int K) {
  __shared__ __align__(16) u16 As_h[128 * 48];
  __shared__ __align__(16) u16 As_l[128 * 48];
  __shared__ __align__(16) u16 Bs_h[128 * 48];
  __shared__ __align__(16) u16 Bs_l[128 * 48];
  const int tid = threadIdx.x;
  const int lane = tid & 63, wave = tid >> 6;
  const int wr = wave >> 1, wc = wave & 1;
  const int l15 = lane & 15, l16 = lane >> 4;
  const int row0 = blockIdx.y * 128, col0 = blockIdx.x * 128;
  const int sr = tid >> 1, sk = (tid & 1) * 16;
  const int c0 = sk >> 3;
  const int w0 = ldsoff(sr, c0), w1 = ldsoff(sr, c0 + 1);
  f32x4 acc[4][4] = {};
  for (int k0 = 0; k0 < K; k0 += 32) {
    const size_t aoff = (size_t)(row0 + sr) * K + k0 + sk;
    const size_t boff = (size_t)(col0 + sr) * K + k0 + sk;
    *(short8*)&As_h[w0] = *(const short8*)&Ahg[aoff];
    *(short8*)&As_h[w1] = *(const short8*)&Ahg[aoff + 8];
    *(short8*)&As_l[w0] = *(const short8*)&Alg[aoff];
    *(short8*)&As_l[w1] = *(const short8*)&Alg[aoff + 8];
    *(short8*)&Bs_h[w0] = *(const short8*)&Bhg[boff];
    *(short8*)&Bs_h[w1] = *(const short8*)&Bhg[boff + 8];
    *(short8*)&Bs_l[w0] = *(const short8*)&Blg[boff];
    *(short8*)&Bs_l[w1] = *(const short8*)&Blg[boff + 8];
    __syncthreads();
    short8 ah[4], al[4], bh[4], bl[4];
#pragma unroll
    for (int mi = 0; mi < 4; ++mi) {
      int off = ldsoff(wr * 64 + mi * 16 + l15, l16);
      ah[mi] = *(short8*)&As_h[off];
      al[mi] = *(short8*)&As_l[off];
    }
#pragma unroll
    for (int ni = 0; ni < 4; ++ni) {
      int off = ldsoff(wc * 64 + ni * 16 + l15, l16);
      bh[ni] = *(short8*)&Bs_h[off];
      bl[ni] = *(short8*)&Bs_l[off];
    }
#pragma unroll
    for (int mi = 0; mi < 4; ++mi)
#pragma unroll
      for (int ni = 0; ni < 4; ++ni) {
        acc[mi][ni] = __builtin_amdgcn_mfma_f32_16x16x32_bf16(ah[mi], bh[ni], acc[mi][ni], 0, 0, 0);
        acc[mi][ni] = __builtin_amdgcn_mfma_f32_16x16x32_bf16(al[mi], bh[ni], acc[mi][ni], 0, 0, 0);
        acc[mi][ni] = __builtin_amdgcn_mfma_f32_16x16x32_bf16(ah[mi], bl[ni], acc[mi][ni], 0, 0, 0);
      }
    __syncthreads();
  }
#pragma unroll
  for (int mi = 0; mi < 4; ++mi)
#pragma unroll
    for (int ni = 0; ni < 4; ++ni) {
      int rr = row0 + wr * 64 + mi * 16 + l16 * 4;
      int cc = col0 + wc * 64 + ni * 16 + l15;
#pragma unroll
      for (int i = 0; i < 4; ++i)
        C0[(size_t)(rr + i) * N + cc] = acc[mi][ni][i];
    }
}

// ---------------- single-pass fp16 GEMM: C = A[M][K] * B[N][K]^T ----------------
// MODE 0: f32 out. MODE 2: z epilogue: o = e0(outr)*e1(rms)*e2(nw)*silu(acc) -> fp16 plane C0.
template <int MODE>
__global__ __launch_bounds__(256) void k_gemm16(const u16* __restrict__ Ag, const u16* __restrict__ Bg,
                                                void* __restrict__ C0, int M, int N, int K,
                                                const float* __restrict__ e0, const float* __restrict__ e1,
                                                const float* __restrict__ e2) {
  __shared__ __align__(16) u16 As[128 * 48];
  __shared__ __align__(16) u16 Bs[128 * 48];
  const int tid = threadIdx.x;
  const int lane = tid & 63, wave = tid >> 6;
  const int wr = wave >> 1, wc = wave & 1;
  const int l15 = lane & 15, l16 = lane >> 4;
  const int row0 = blockIdx.y * 128, col0 = blockIdx.x * 128;
  const int sr = tid >> 1, sk = (tid & 1) * 16;
  const int c0 = sk >> 3;
  const int w0 = ldsoff(sr, c0), w1 = ldsoff(sr, c0 + 1);
  f32x4 acc[4][4] = {};
  for (int k0 = 0; k0 < K; k0 += 32) {
    const size_t aoff = (size_t)(row0 + sr) * K + k0 + sk;
    const size_t boff = (size_t)(col0 + sr) * K + k0 + sk;
    *(short8*)&As[w0] = *(const short8*)&Ag[aoff];
    *(short8*)&As[w1] = *(const short8*)&Ag[aoff + 8];
    *(short8*)&Bs[w0] = *(const short8*)&Bg[boff];
    *(short8*)&Bs[w1] = *(const short8*)&Bg[boff + 8];
    __syncthreads();
    half8 a[4], b[4];
#pragma unroll
    for (int mi = 0; mi < 4; ++mi) a[mi] = *(half8*)&As[ldsoff(wr * 64 + mi * 16 + l15, l16)];
#pragma unroll
    for (int ni = 0; ni < 4; ++ni) b[ni] = *(half8*)&Bs[ldsoff(wc * 64 + ni * 16 + l15, l16)];
#pragma unroll
    for (int mi = 0; mi < 4; ++mi)
#pragma unroll
      for (int ni = 0; ni < 4; ++ni)
        acc[mi][ni] = __builtin_amdgcn_mfma_f32_16x16x32_f16(a[mi], b[ni], acc[mi][ni], 0, 0, 0);
    __syncthreads();
  }
#pragma unroll
  for (int mi = 0; mi < 4; ++mi) {
#pragma unroll
    for (int ni = 0; ni < 4; ++ni) {
      int rr = row0 + wr * 64 + mi * 16 + l16 * 4;
      int cc = col0 + wc * 64 + ni * 16 + l15;
#pragma unroll
      for (int i = 0; i < 4; ++i) {
        float v = acc[mi][ni][i];
        size_t idx = (size_t)(rr + i) * N + cc;
        if constexpr (MODE == 0) {
          ((float*)C0)[idx] = v;
        } else {
          float zs = v * sigm(v);
          float o = e0[idx] * e1[(size_t)(rr + i) * 32 + (cc >> 7)] * e2[cc & 127] * zs;
          ((u16*)C0)[idx] = f2h(o);
        }
      }
    }
  }
}

// ---------------- beta / g from ba [BT,128] f32, TRANSPOSED out [32][4096] ----------------
__global__ __launch_bounds__(256) void k_bg(const float* __restrict__ ba, const float* __restrict__ dt_bias,
                                            const float* __restrict__ A_log, float* __restrict__ beta_t,
                                            float* __restrict__ g_t) {
  int i = blockIdx.x * 256 + threadIdx.x;  // 0..131071
  int bt = i >> 5, h = i & 31;
  float bv = ba[(size_t)bt * 128 + h];
  float av = ba[(size_t)bt * 128 + 32 + h];
  beta_t[h * 4096 + bt] = sigm(bv);
  float xx = av + dt_bias[h];
  float sp = (xx > 20.f) ? xx : log1pf(__expf(xx));
  g_t[h * 4096 + bt] = -__expf(A_log[h]) * sp;
}

// ---------------- conv+SiLU+L2norm for q,k -> pre-split hi/lo bf16 planes ----------------
__global__ __launch_bounds__(256) void k_convqk(const float* __restrict__ qkraw, const float* __restrict__ cw,
                                                u16* __restrict__ qkh, u16* __restrict__ qkl) {
  __shared__ float sval[4096];
  __shared__ float snrm[32];
  const int tid = threadIdx.x;
  const int bt = blockIdx.x;
  const int b = bt >> 11, t = bt & 2047;
  for (int i = 0; i < 16; ++i) {
    int c = i * 256 + tid;  // 0..4095 (q:0-2047, k:2048-4095)
    float acc = 0.f;
#pragma unroll
    for (int j = 0; j < 4; ++j) {
      int ts = t - 3 + j;
      if (ts >= 0) acc += cw[c * 4 + j] * qkraw[(size_t)(b * 2048 + ts) * 4096 + c];
    }
    sval[c] = acc * sigm(acc);
  }
  __syncthreads();
  {
    int gidx = tid >> 3, s = tid & 7;
    float ss = 0.f;
#pragma unroll
    for (int i2 = 0; i2 < 16; ++i2) { float v = sval[gidx * 128 + s * 16 + i2]; ss += v * v; }
    ss += __shfl_xor(ss, 1); ss += __shfl_xor(ss, 2); ss += __shfl_xor(ss, 4);
    if (s == 0) snrm[gidx] = 1.0f / fmaxf(sqrtf(ss), 1e-12f);
  }
  __syncthreads();
  for (int i = 0; i < 16; ++i) {
    int c = i * 256 + tid;
    float v = sval[c] * snrm[c >> 7];
    u16 hh = f2bf(v);
    qkh[(size_t)bt * 4096 + c] = hh;
    qkl[(size_t)bt * 4096 + c] = f2bf(v - bf2f(hh));
  }
}

// ---------------- chunked gated-linear-attention scan, MFMA, hi/lo-compensated ----------------
// grid 256 = dq(4) x h(32) x b(2); block 512 (8 waves). Chunk L=64, 32 chunks sequential.
__global__ __launch_bounds__(512) void k_scanc(const u16* __restrict__ qkh, const u16* __restrict__ qkl,
                                               const float* __restrict__ vraw, const float* __restrict__ cw,
                                               const float* __restrict__ beta_t, const float* __restrict__ g_t,
                                               float* __restrict__ outr) {
  __shared__ __align__(16) u16 Qh[64][136], Ql[64][136], Kh[64][136], Kl[64][136];
  __shared__ __align__(16) u16 Vh[32][72], Vl[32][72];
  __shared__ __align__(16) u16 SIh[64][72], SIl[64][72];
  __shared__ __align__(16) u16 SH[2][32][132], SL[2][32][132];
  __shared__ float rv[67][33];
  __shared__ float garr[64], barr[64], warr[64], earr[64];
  __shared__ float sdt;

  const int tid = threadIdx.x;
  const int lane = tid & 63, wv = tid >> 6;
  const int l15 = lane & 15, l16 = lane >> 4;
  const int dq = blockIdx.x & 3, h = (blockIdx.x >> 2) & 31, b = blockIdx.x >> 7;
  const int bT = b * 2048;
  const int hk = h >> 1;
  const int dvl = tid & 31;
  const int vch = h * 128 + dq * 32;
  const float4 cwv = *(const float4*)&cw[(4096 + vch + dvl) * 4];
  const int mblk = wv & 3, nh = wv >> 2;
  const int m0 = mblk * 16;
  const int sr = tid >> 3, d0 = (tid & 7) * 16;
  const int r0v = tid >> 5;

  for (int i = tid; i < 2 * 32 * 132; i += 512) { ((u16*)SH)[i] = 0; ((u16*)SL)[i] = 0; }
  f32x4 st[2] = {};

  short8 pqh[2], pql[2], pkh[2], pkl[2];
  float pv[5];
  auto LOADQK = [&](int t0) {
    const size_t base = (size_t)(bT + t0 + sr) * 4096 + hk * 128 + d0;
    pqh[0] = *(const short8*)&qkh[base];        pqh[1] = *(const short8*)&qkh[base + 8];
    pql[0] = *(const short8*)&qkl[base];        pql[1] = *(const short8*)&qkl[base + 8];
    pkh[0] = *(const short8*)&qkh[base + 2048]; pkh[1] = *(const short8*)&qkh[base + 2056];
    pkl[0] = *(const short8*)&qkl[base + 2048]; pkl[1] = *(const short8*)&qkl[base + 2056];
  };
  auto LOADV = [&](int t0) {
#pragma unroll
    for (int i = 0; i < 5; ++i) {
      int r = r0v + i * 16;
      int tr = t0 - 3 + r;
      pv[i] = (r < 67 && tr >= 0) ? vraw[(size_t)(bT + tr) * 4096 + vch + dvl] : 0.f;
    }
  };

  LOADQK(0);
  LOADV(0);

  for (int ch = 0; ch < NCH; ++ch) {
    const int t0 = ch * CL;
    const int p = ch & 1;
    *(short8*)&Qh[sr][d0] = pqh[0]; *(short8*)&Qh[sr][d0 + 8] = pqh[1];
    *(short8*)&Ql[sr][d0] = pql[0]; *(short8*)&Ql[sr][d0 + 8] = pql[1];
    *(short8*)&Kh[sr][d0] = pkh[0]; *(short8*)&Kh[sr][d0 + 8] = pkh[1];
    *(short8*)&Kl[sr][d0] = pkl[0]; *(short8*)&Kl[sr][d0 + 8] = pkl[1];
#pragma unroll
    for (int i = 0; i < 5; ++i) {
      int r = r0v + i * 16;
      if (r < 67) rv[r][dvl] = pv[i];
    }
    if (wv == 0) {
      float gv = g_t[h * 4096 + bT + t0 + lane];
      float bv = beta_t[h * 4096 + bT + t0 + lane];
      float cum = gv;
#pragma unroll
      for (int off = 1; off < 64; off <<= 1) {
        float o = __shfl_up(cum, off);
        if (lane >= off) cum += o;
      }
      float tot = __shfl(cum, 63);
      garr[lane] = cum;
      earr[lane] = __expf(cum);
      warr[lane] = __expf(tot - cum) * bv;
      barr[lane] = bv;
      if (lane == 0) sdt = __expf(tot);
    }
    __syncthreads();  // B1
    if (ch + 1 < NCH) {
      LOADQK(t0 + CL);
      LOADV(t0 + CL);
    }
    {
      int tl = tid >> 5;
#pragma unroll
      for (int rr = 0; rr < 4; ++rr) {
        int t = rr * 16 + tl;
        float a = cwv.x * rv[t][dvl] + cwv.y * rv[t + 1][dvl] + cwv.z * rv[t + 2][dvl] + cwv.w * rv[t + 3][dvl];
        a = a * sigm(a);
        u16 hi = f2bf(a);
        Vh[dvl][t] = hi;
        Vl[dvl][t] = f2bf(a - bf2f(hi));
      }
    }
    short8 ah[4], al[4];
#pragma unroll
    for (int kk = 0; kk < 4; ++kk) {
      ah[kk] = *(short8*)&Qh[m0 + l15][l16 * 8 + kk * 32];
      al[kk] = *(short8*)&Ql[m0 + l15][l16 * 8 + kk * 32];
    }
#pragma unroll
    for (int j = 0; j < 2; ++j) {
      int n = nh * 2 + j;
      f32x4 a4 = {};
#pragma unroll
      for (int kk = 0; kk < 4; ++kk) {
        short8 bh_ = *(short8*)&Kh[n * 16 + l15][l16 * 8 + kk * 32];
        short8 bl_ = *(short8*)&Kl[n * 16 + l15][l16 * 8 + kk * 32];
        a4 = __builtin_amdgcn_mfma_f32_16x16x32_bf16(ah[kk], bh_, a4, 0, 0, 0);
        a4 = __builtin_amdgcn_mfma_f32_16x16x32_bf16(ah[kk], bl_, a4, 0, 0, 0);
        a4 = __builtin_amdgcn_mfma_f32_16x16x32_bf16(al[kk], bh_, a4, 0, 0, 0);
      }
      int col = n * 16 + l15;
      float gc = garr[col], bc = barr[col];
#pragma unroll
      for (int i = 0; i < 4; ++i) {
        int row = m0 + l16 * 4 + i;
        float cval = (col <= row) ? __expf(garr[row] - gc) * bc * a4[i] : 0.f;
        u16 hh = f2bf(cval);
        SIh[row][col] = hh;
        SIl[row][col] = f2bf(cval - bf2f(hh));
      }
    }
    __syncthreads();  // B2
    f32x4 ao = {};
#pragma unroll
    for (int kk = 0; kk < 4; ++kk) {
      short8 sh8 = *(short8*)&SH[p][nh * 16 + l15][l16 * 8 + kk * 32];
      short8 sl8 = *(short8*)&SL[p][nh * 16 + l15][l16 * 8 + kk * 32];
      ao = __builtin_amdgcn_mfma_f32_16x16x32_bf16(ah[kk], sh8, ao, 0, 0, 0);
      ao = __builtin_amdgcn_mfma_f32_16x16x32_bf16(ah[kk], sl8, ao, 0, 0, 0);
      ao = __builtin_amdgcn_mfma_f32_16x16x32_bf16(al[kk], sh8, ao, 0, 0, 0);
    }
#pragma unroll
    for (int i = 0; i < 4; ++i) ao[i] *= earr[m0 + l16 * 4 + i];
#pragma unroll
    for (int kk = 0; kk < 2; ++kk) {
      short8 asih = *(short8*)&SIh[m0 + l15][l16 * 8 + kk * 32];
      short8 asil = *(short8*)&SIl[m0 + l15][l16 * 8 + kk * 32];
      short8 bvh = *(short8*)&Vh[nh * 16 + l15][l16 * 8 + kk * 32];
      short8 bvl = *(short8*)&Vl[nh * 16 + l15][l16 * 8 + kk * 32];
      ao = __builtin_amdgcn_mfma_f32_16x16x32_bf16(asih, bvh, ao, 0, 0, 0);
      ao = __builtin_amdgcn_mfma_f32_16x16x32_bf16(asih, bvl, ao, 0, 0, 0);
      ao = __builtin_amdgcn_mfma_f32_16x16x32_bf16(asil, bvh, ao, 0, 0, 0);
    }
#pragma unroll
    for (int i = 0; i < 4; ++i)
      outr[(size_t)(bT + t0 + m0 + l16 * 4 + i) * 4096 + vch + nh * 16 + l15] = ao[i];
#pragma unroll
    for (int m = 0; m < 2; ++m)
#pragma unroll
      for (int i = 0; i < 4; ++i) st[m][i] *= sdt;
#pragma unroll
    for (int kk = 0; kk < 2; ++kk) {
      short8 bwh, bwl;
      {
        int dk = wv * 16 + l15;
#pragma unroll
        for (int e = 0; e < 8; ++e) {
          int s = l16 * 8 + e + kk * 32;
          float kvv = (bf2f(Kh[s][dk]) + bf2f(Kl[s][dk])) * warr[s];
          u16 hh = f2bf(kvv);
          bwh[e] = (short)hh;
          bwl[e] = (short)f2bf(kvv - bf2f(hh));
        }
      }
#pragma unroll
      for (int m = 0; m < 2; ++m) {
        short8 avh = *(short8*)&Vh[m * 16 + l15][l16 * 8 + kk * 32];
        short8 avl = *(short8*)&Vl[m * 16 + l15][l16 * 8 + kk * 32];
        st[m] = __builtin_amdgcn_mfma_f32_16x16x32_bf16(avh, bwh, st[m], 0, 0, 0);
        st[m] = __builtin_amdgcn_mfma_f32_16x16x32_bf16(avh, bwl, st[m], 0, 0, 0);
        st[m] = __builtin_amdgcn_mfma_f32_16x16x32_bf16(avl, bwh, st[m], 0, 0, 0);
      }
    }
#pragma unroll
    for (int m = 0; m < 2; ++m)
#pragma unroll
      for (int i = 0; i < 4; ++i) {
        float sv = st[m][i];
        u16 hh = f2bf(sv);
        SH[p ^ 1][m * 16 + l16 * 4 + i][wv * 16 + l15] = hh;
        SL[p ^ 1][m * 16 + l16 * 4 + i][wv * 16 + l15] = f2bf(sv - bf2f(hh));
      }
    __syncthreads();  // B4
  }
}

// ---------------- per-(bt,head) RMS scale from f32 outr ----------------
__global__ __launch_bounds__(256) void k_rms(const float* __restrict__ outr, float* __restrict__ rms) {
  int pair = blockIdx.x * 4 + (threadIdx.x >> 6);
  int lane = threadIdx.x & 63;
  float2 v = *(const float2*)&outr[(size_t)pair * 128 + lane * 2];
  float ss = v.x * v.x + v.y * v.y;
#pragma unroll
  for (int m = 1; m < 64; m <<= 1) ss += __shfl_xor(ss, m);
  if (lane == 0) rms[pair] = rsqrtf(ss * (1.0f / 128.0f) + 1e-6f);
}

extern "C" void kernel_launch(void* const* d_in, const int* in_sizes, int n_in,
                              void* d_out, int out_size, void* d_ws, size_t ws_size,
                              hipStream_t stream) {
  const float* x = (const float*)d_in[0];
  // d_in[1] = positions (int64) — unused by the math
  const float* W_qkv = (const float*)d_in[2];
  const float* W_z = (const float*)d_in[3];
  const float* W_b = (const float*)d_in[4];
  const float* W_a = (const float*)d_in[5];
  const float* conv_w = (const float*)d_in[6];
  const float* dt_bias = (const float*)d_in[7];
  const float* A_log = (const float*)d_in[8];
  const float* norm_w = (const float*)d_in[9];
  const float* W_out = (const float*)d_in[10];
  float* out = (float*)d_out;

  const size_t MB = 1ull << 20;
  const size_t need = 192 * MB + 3 * (size_t)NBT * 32 * 4;  // 202,899,456 B == proven bound
  if (ws_size < need) {
    k_sentinel<<<1, 1, 0, stream>>>(out);
    return;
  }
  char* ws = (char*)d_ws;
  // Region A [0,64MB): xh/xl bf16 (ba path) + xh16 fp16 + wsh16 fp16; later outr f32; later wout16
  u16* xh = (u16*)ws;                 // bf16 hi (ba GEMM)
  u16* xl = (u16*)(ws + 16 * MB);     // bf16 lo (ba GEMM)
  u16* xh16 = (u16*)(ws + 32 * MB);   // fp16 x (qk/v GEMMs)
  u16* wsh16 = (u16*)(ws + 48 * MB);  // fp16 W_qkv qk-rows, then v-rows
  float* outr = (float*)ws;
  u16* wout16 = (u16*)ws;
  // Region B [64,128MB): early: wba planes + babuf; then qkB hi/lo bf16 planes; later om fp16 plane
  u16* wbah = (u16*)(ws + 64 * MB);
  u16* wbal = (u16*)(ws + 64 * MB + 512 * 1024);
  float* babuf = (float*)(ws + 65 * MB);
  u16* qkBh = (u16*)(ws + 64 * MB);
  u16* qkBl = (u16*)(ws + 96 * MB);
  u16* om16 = (u16*)(ws + 64 * MB);
  // Region C [128,192MB): qkA f32; then vbuf f32; later x fp16 (z GEMM) + wz fp16
  float* qkA = (float*)(ws + 128 * MB);
  float* vbuf = (float*)(ws + 128 * MB);
  u16* xh16b = (u16*)(ws + 128 * MB);
  u16* wz16 = (u16*)(ws + 144 * MB);
  float* beta_t = (float*)(ws + 192 * MB);
  float* g_t = beta_t + (size_t)NBT * 32;
  float* rmsb = g_t + (size_t)NBT * 32;

  const int N4X = NBT * NC / 4;
  // --- conversions + ba path (3-pass bf16: g-gate path fully compensated) ---
  k_cvt<true><<<N4X / 256, 256, 0, stream>>>(x, xh, xl, N4X);
  k_cvt16<<<N4X / 256, 256, 0, stream>>>(x, xh16, N4X);
  k_cvt16<<<N4X / 256, 256, 0, stream>>>(W_qkv, wsh16, N4X);  // qk rows 0..4095
  k_wba<<<128 * NC / 256, 256, 0, stream>>>(W_b, W_a, wbah, wbal);
  k_gemm_bf3<<<dim3(1, NBT / 128), 256, 0, stream>>>(xh, xl, wbah, wbal, babuf, NBT, 128, NC);
  k_bg<<<NBT * 32 / 256, 256, 0, stream>>>(babuf, dt_bias, A_log, beta_t, g_t);

  // --- qk projection (1-pass fp16) -> conv+norm -> qkB hi/lo bf16 planes ---
  k_gemm16<0><<<dim3(4096 / 128, NBT / 128), 256, 0, stream>>>(xh16, wsh16, qkA, NBT, 4096, NC,
                                                               nullptr, nullptr, nullptr);
  k_convqk<<<NBT, 256, 0, stream>>>(qkA, conv_w, qkBh, qkBl);

  // --- v projection (1-pass fp16; vbuf overwrites qkA which is dead) ---
  k_cvt16<<<N4X / 256, 256, 0, stream>>>(W_qkv + (size_t)4096 * NC, wsh16, N4X);  // v rows
  k_gemm16<0><<<dim3(4096 / 128, NBT / 128), 256, 0, stream>>>(xh16, wsh16, vbuf, NBT, 4096, NC,
                                                               nullptr, nullptr, nullptr);

  // --- chunked scan (both batches) -> outr (overlays x/w planes, all dead) ---
  k_scanc<<<256, 512, 0, stream>>>(qkBh, qkBl, vbuf, conv_w, beta_t, g_t, outr);
  k_rms<<<NBT * NHV / 4, 256, 0, stream>>>(outr, rmsb);

  // --- z projection (1-pass fp16) with fused gate epilogue -> om fp16 plane ---
  k_cvt16<<<N4X / 256, 256, 0, stream>>>(x, xh16b, N4X);
  k_cvt16<<<N4X / 256, 256, 0, stream>>>(W_z, wz16, N4X);
  k_gemm16<2><<<dim3(VALD / 128, NBT / 128), 256, 0, stream>>>(xh16b, wz16, om16, NBT, VALD, NC,
                                                               outr, rmsb, norm_w);

  // --- output projection (1-pass fp16) -> f32 out ---
  k_cvt16<<<N4X / 256, 256, 0, stream>>>(W_out, wout16, N4X);
  k_gemm16<0><<<dim3(NC / 128, NBT / 128), 256, 0, stream>>>(om16, wout16, out, NBT, NC, VALD,
                                                             nullptr, nullptr, nullptr);
}

// Round 15
// 822.032 us; speedup vs baseline: 3.6480x; 1.0458x over previous
//
#include <hip/hip_runtime.h>

typedef unsigned short u16;
typedef unsigned int u32;
typedef __attribute__((ext_vector_type(8))) short short8;
typedef __attribute__((ext_vector_type(8))) _Float16 half8;
typedef __attribute__((ext_vector_type(4))) float f32x4;

#define NB 2
#define NT 2048
#define NC 2048
#define NHV 32
#define VALD 4096
#define NBT 4096
#define CL 64
#define NCH (NT / CL)

static __device__ __forceinline__ float bf2f(u16 u) {
  union { u32 u; float f; } x; x.u = ((u32)u) << 16; return x.f;
}
static __device__ __forceinline__ u16 f2bf(float f) {
  union { float f; u32 u; } x; x.f = f;
  u32 r = x.u + 0x7fffu + ((x.u >> 16) & 1u);
  return (u16)(r >> 16);
}
static __device__ __forceinline__ u16 f2h(float f) {
  union { _Float16 h; u16 u; } c; c.h = (_Float16)f; return c.u;
}
static __device__ __forceinline__ float h2f(u16 u) {
  union { u16 u; _Float16 h; } c; c.u = u; return (float)c.h;
}
static __device__ __forceinline__ float sigm(float x) { return 1.0f / (1.0f + __expf(-x)); }
static __device__ __forceinline__ int ldsoff(int row, int c8) {
  return row * 48 + ((c8 ^ ((row >> 2) & 3)) << 3);
}

// ---------------- sentinel ----------------
__global__ void k_sentinel(float* out) { out[0] = 1.0e6f; }

// ---------------- x -> bf16 hi/lo planes + fp16 plane (single read of x) ----------------
__global__ __launch_bounds__(256) void k_cvtx(const float* __restrict__ in, u16* __restrict__ hi,
                                              u16* __restrict__ lo, u16* __restrict__ h16, int n4) {
  int i = blockIdx.x * 256 + threadIdx.x;
  if (i >= n4) return;
  float4 v = ((const float4*)in)[i];
  ushort4 h, l, p;
  h.x = f2bf(v.x); l.x = f2bf(v.x - bf2f(h.x)); p.x = f2h(v.x);
  h.y = f2bf(v.y); l.y = f2bf(v.y - bf2f(h.y)); p.y = f2h(v.y);
  h.z = f2bf(v.z); l.z = f2bf(v.z - bf2f(h.z)); p.z = f2h(v.z);
  h.w = f2bf(v.w); l.w = f2bf(v.w - bf2f(h.w)); p.w = f2h(v.w);
  ((ushort4*)hi)[i] = h;
  ((ushort4*)lo)[i] = l;
  ((ushort4*)h16)[i] = p;
}

// ---------------- f32 -> fp16 plane ----------------
__global__ __launch_bounds__(256) void k_cvt16(const float* __restrict__ in, u16* __restrict__ out, int n4) {
  int i = blockIdx.x * 256 + threadIdx.x;
  if (i >= n4) return;
  float4 v = ((const float4*)in)[i];
  ushort4 o;
  o.x = f2h(v.x); o.y = f2h(v.y); o.z = f2h(v.z); o.w = f2h(v.w);
  ((ushort4*)out)[i] = o;
}

// ---------------- build padded W_ba hi/lo bf16 planes [128][2048] ----------------
__global__ __launch_bounds__(256) void k_wba(const float* __restrict__ Wb, const float* __restrict__ Wa,
                                             u16* __restrict__ hi, u16* __restrict__ lo) {
  int i = blockIdx.x * 256 + threadIdx.x;
  int r = i >> 11, c = i & 2047;
  float v = 0.f;
  if (r < 32) v = Wb[r * 2048 + c];
  else if (r < 64) v = Wa[(r - 32) * 2048 + c];
  u16 h = f2bf(v);
  hi[i] = h;
  lo[i] = f2bf(v - bf2f(h));
}

// ---------------- 3-pass bf16 GEMM (ba projection; recurrence-gate path) ----------------
__global__ __launch_bounds__(256) void k_gemm_bf3(const u16* __restrict__ Ahg, const u16* __restrict__ Alg,
                                                  const u16* __restrict__ Bhg, const u16* __restrict__ Blg,
                                                  float* __restrict__ C0, int M, int N, int K) {
  __shared__ __align__(16) u16 As_h[128 * 48];
  __shared__ __align__(16) u16 As_l[128 * 48];
  __shared__ __align__(16) u16 Bs_h[128 * 48];
  __shared__ __align__(16) u16 Bs_l[128 * 48];
  const int tid = threadIdx.x;
  const int lane = tid & 63, wave = tid >> 6;
  const int wr = wave >> 1, wc = wave & 1;
  const int l15 = lane & 15, l16 = lane >> 4;
  const int row0 = blockIdx.y * 128, col0 = blockIdx.x * 128;
  const int sr = tid >> 1, sk = (tid & 1) * 16;
  const int c0 = sk >> 3;
  const int w0 = ldsoff(sr, c0), w1 = ldsoff(sr, c0 + 1);
  f32x4 acc[4][4] = {};
  for (int k0 = 0; k0 < K; k0 += 32) {
    const size_t aoff = (size_t)(row0 + sr) * K + k0 + sk;
    const size_t boff = (size_t)(col0 + sr) * K + k0 + sk;
    *(short8*)&As_h[w0] = *(const short8*)&Ahg[aoff];
    *(short8*)&As_h[w1] = *(const short8*)&Ahg[aoff + 8];
    *(short8*)&As_l[w0] = *(const short8*)&Alg[aoff];
    *(short8*)&As_l[w1] = *(const short8*)&Alg[aoff + 8];
    *(short8*)&Bs_h[w0] = *(const short8*)&Bhg[boff];
    *(short8*)&Bs_h[w1] = *(const short8*)&Bhg[boff + 8];
    *(short8*)&Bs_l[w0] = *(const short8*)&Blg[boff];
    *(short8*)&Bs_l[w1] = *(const short8*)&Blg[boff + 8];
    __syncthreads();
    short8 ah[4], al[4], bh[4], bl[4];
#pragma unroll
    for (int mi = 0; mi < 4; ++mi) {
      int off = ldsoff(wr * 64 + mi * 16 + l15, l16);
      ah[mi] = *(short8*)&As_h[off];
      al[mi] = *(short8*)&As_l[off];
    }
#pragma unroll
    for (int ni = 0; ni < 4; ++ni) {
      int off = ldsoff(wc * 64 + ni * 16 + l15, l16);
      bh[ni] = *(short8*)&Bs_h[off];
      bl[ni] = *(short8*)&Bs_l[off];
    }
#pragma unroll
    for (int mi = 0; mi < 4; ++mi)
#pragma unroll
      for (int ni = 0; ni < 4; ++ni) {
        acc[mi][ni] = __builtin_amdgcn_mfma_f32_16x16x32_bf16(ah[mi], bh[ni], acc[mi][ni], 0, 0, 0);
        acc[mi][ni] = __builtin_amdgcn_mfma_f32_16x16x32_bf16(al[mi], bh[ni], acc[mi][ni], 0, 0, 0);
        acc[mi][ni] = __builtin_amdgcn_mfma_f32_16x16x32_bf16(ah[mi], bl[ni], acc[mi][ni], 0, 0, 0);
      }
    __syncthreads();
  }
#pragma unroll
  for (int mi = 0; mi < 4; ++mi)
#pragma unroll
    for (int ni = 0; ni < 4; ++ni) {
      int rr = row0 + wr * 64 + mi * 16 + l16 * 4;
      int cc = col0 + wc * 64 + ni * 16 + l15;
#pragma unroll
      for (int i = 0; i < 4; ++i)
        C0[(size_t)(rr + i) * N + cc] = acc[mi][ni][i];
    }
}

// ---------------- single-pass fp16 GEMM: C = A[M][K] * B[N][K]^T ----------------
// MODE 0: f32 out. MODE 1: fp16 out. MODE 2: z epilogue -> fp16 out.
template <int MODE>
__global__ __launch_bounds__(256) void k_gemm16(const u16* __restrict__ Ag, const u16* __restrict__ Bg,
                                                void* __restrict__ C0, int M, int N, int K,
                                                const float* __restrict__ e0, const float* __restrict__ e1,
                                                const float* __restrict__ e2) {
  __shared__ __align__(16) u16 As[128 * 48];
  __shared__ __align__(16) u16 Bs[128 * 48];
  const int tid = threadIdx.x;
  const int lane = tid & 63, wave = tid >> 6;
  const int wr = wave >> 1, wc = wave & 1;
  const int l15 = lane & 15, l16 = lane >> 4;
  const int row0 = blockIdx.y * 128, col0 = blockIdx.x * 128;
  const int sr = tid >> 1, sk = (tid & 1) * 16;
  const int c0 = sk >> 3;
  const int w0 = ldsoff(sr, c0), w1 = ldsoff(sr, c0 + 1);
  f32x4 acc[4][4] = {};
  for (int k0 = 0; k0 < K; k0 += 32) {
    const size_t aoff = (size_t)(row0 + sr) * K + k0 + sk;
    const size_t boff = (size_t)(col0 + sr) * K + k0 + sk;
    *(short8*)&As[w0] = *(const short8*)&Ag[aoff];
    *(short8*)&As[w1] = *(const short8*)&Ag[aoff + 8];
    *(short8*)&Bs[w0] = *(const short8*)&Bg[boff];
    *(short8*)&Bs[w1] = *(const short8*)&Bg[boff + 8];
    __syncthreads();
    half8 a[4], b[4];
#pragma unroll
    for (int mi = 0; mi < 4; ++mi) a[mi] = *(half8*)&As[ldsoff(wr * 64 + mi * 16 + l15, l16)];
#pragma unroll
    for (int ni = 0; ni < 4; ++ni) b[ni] = *(half8*)&Bs[ldsoff(wc * 64 + ni * 16 + l15, l16)];
#pragma unroll
    for (int mi = 0; mi < 4; ++mi)
#pragma unroll
      for (int ni = 0; ni < 4; ++ni)
        acc[mi][ni] = __builtin_amdgcn_mfma_f32_16x16x32_f16(a[mi], b[ni], acc[mi][ni], 0, 0, 0);
    __syncthreads();
  }
#pragma unroll
  for (int mi = 0; mi < 4; ++mi) {
#pragma unroll
    for (int ni = 0; ni < 4; ++ni) {
      int rr = row0 + wr * 64 + mi * 16 + l16 * 4;
      int cc = col0 + wc * 64 + ni * 16 + l15;
#pragma unroll
      for (int i = 0; i < 4; ++i) {
        float v = acc[mi][ni][i];
        size_t idx = (size_t)(rr + i) * N + cc;
        if constexpr (MODE == 0) {
          ((float*)C0)[idx] = v;
        } else if constexpr (MODE == 1) {
          ((u16*)C0)[idx] = f2h(v);
        } else {
          float zs = v * sigm(v);
          float o = e0[idx] * e1[(size_t)(rr + i) * 32 + (cc >> 7)] * e2[cc & 127] * zs;
          ((u16*)C0)[idx] = f2h(o);
        }
      }
    }
  }
}

// ---------------- beta / g from ba [BT,128] f32, TRANSPOSED out [32][4096] ----------------
__global__ __launch_bounds__(256) void k_bg(const float* __restrict__ ba, const float* __restrict__ dt_bias,
                                            const float* __restrict__ A_log, float* __restrict__ beta_t,
                                            float* __restrict__ g_t) {
  int i = blockIdx.x * 256 + threadIdx.x;
  int bt = i >> 5, h = i & 31;
  float bv = ba[(size_t)bt * 128 + h];
  float av = ba[(size_t)bt * 128 + 32 + h];
  beta_t[h * 4096 + bt] = sigm(bv);
  float xx = av + dt_bias[h];
  float sp = (xx > 20.f) ? xx : log1pf(__expf(xx));
  g_t[h * 4096 + bt] = -__expf(A_log[h]) * sp;
}

// ---------------- conv+SiLU+L2norm for q,k: fp16 in [4096][4096] -> fp16 out ----------------
__global__ __launch_bounds__(256) void k_convqk(const u16* __restrict__ qkraw, const float* __restrict__ cw,
                                                u16* __restrict__ qkn) {
  __shared__ float sval[4096];
  __shared__ float snrm[32];
  const int tid = threadIdx.x;
  const int bt = blockIdx.x;
  const int b = bt >> 11, t = bt & 2047;
  for (int i = 0; i < 16; ++i) {
    int c = i * 256 + tid;
    float acc = 0.f;
#pragma unroll
    for (int j = 0; j < 4; ++j) {
      int ts = t - 3 + j;
      if (ts >= 0) acc += cw[c * 4 + j] * h2f(qkraw[(size_t)(b * 2048 + ts) * 4096 + c]);
    }
    sval[c] = acc * sigm(acc);
  }
  __syncthreads();
  {
    int gidx = tid >> 3, s = tid & 7;
    float ss = 0.f;
#pragma unroll
    for (int i2 = 0; i2 < 16; ++i2) { float v = sval[gidx * 128 + s * 16 + i2]; ss += v * v; }
    ss += __shfl_xor(ss, 1); ss += __shfl_xor(ss, 2); ss += __shfl_xor(ss, 4);
    if (s == 0) snrm[gidx] = 1.0f / fmaxf(sqrtf(ss), 1e-12f);
  }
  __syncthreads();
  for (int i = 0; i < 16; ++i) {
    int c = i * 256 + tid;
    qkn[(size_t)bt * 4096 + c] = f2h(sval[c] * snrm[c >> 7]);
  }
}

// ---------------- chunked gated-linear-attention scan, single-fp16 MFMA ----------------
// grid 256 = dq(4) x h(32) x b(2); block 512 (8 waves); ~71 KB LDS -> 2 blocks/CU.
__global__ __launch_bounds__(512, 4) void k_scanc(const u16* __restrict__ qk16, const u16* __restrict__ v16,
                                                  const float* __restrict__ cw,
                                                  const float* __restrict__ beta_t, const float* __restrict__ g_t,
                                                  float* __restrict__ outr) {
  __shared__ __align__(16) u16 Qs[64][136], Ks[64][136];
  __shared__ __align__(16) u16 Vs[32][72];
  __shared__ __align__(16) u16 SIs[64][72];
  __shared__ __align__(16) u16 SH[2][32][132];
  __shared__ u16 rv16[67][36];
  __shared__ float garr[64], barr[64], warr[64], earr[64];
  __shared__ float sdt;

  const int tid = threadIdx.x;
  const int lane = tid & 63, wv = tid >> 6;
  const int l15 = lane & 15, l16 = lane >> 4;
  const int dq = blockIdx.x & 3, h = (blockIdx.x >> 2) & 31, b = blockIdx.x >> 7;
  const int bT = b * 2048;
  const int hk = h >> 1;
  const int dvl = tid & 31;
  const int vch = h * 128 + dq * 32;
  const float4 cwv = *(const float4*)&cw[(4096 + vch + dvl) * 4];
  const int mblk = wv & 3, nh = wv >> 2;
  const int m0 = mblk * 16;
  const int sr = tid >> 3, d0 = (tid & 7) * 16;
  const int r0v = tid >> 5;

  for (int i = tid; i < 2 * 32 * 132; i += 512) ((u16*)SH)[i] = 0;
  f32x4 st[2] = {};

  short8 pq[2], pk[2];
  u16 pv[5];
  auto LOADQK = [&](int t0) {
    const size_t base = (size_t)(bT + t0 + sr) * 4096 + hk * 128 + d0;
    pq[0] = *(const short8*)&qk16[base];        pq[1] = *(const short8*)&qk16[base + 8];
    pk[0] = *(const short8*)&qk16[base + 2048]; pk[1] = *(const short8*)&qk16[base + 2056];
  };
  auto LOADV = [&](int t0) {
#pragma unroll
    for (int i = 0; i < 5; ++i) {
      int r = r0v + i * 16;
      int tr = t0 - 3 + r;
      pv[i] = (r < 67 && tr >= 0) ? v16[(size_t)(bT + tr) * 4096 + vch + dvl] : (u16)0;
    }
  };

  LOADQK(0);
  LOADV(0);

  for (int ch = 0; ch < NCH; ++ch) {
    const int t0 = ch * CL;
    const int p = ch & 1;
    *(short8*)&Qs[sr][d0] = pq[0]; *(short8*)&Qs[sr][d0 + 8] = pq[1];
    *(short8*)&Ks[sr][d0] = pk[0]; *(short8*)&Ks[sr][d0 + 8] = pk[1];
#pragma unroll
    for (int i = 0; i < 5; ++i) {
      int r = r0v + i * 16;
      if (r < 67) rv16[r][dvl] = pv[i];
    }
    if (wv == 0) {
      float gv = g_t[h * 4096 + bT + t0 + lane];
      float bv = beta_t[h * 4096 + bT + t0 + lane];
      float cum = gv;
#pragma unroll
      for (int off = 1; off < 64; off <<= 1) {
        float o = __shfl_up(cum, off);
        if (lane >= off) cum += o;
      }
      float tot = __shfl(cum, 63);
      garr[lane] = cum;
      earr[lane] = __expf(cum);
      warr[lane] = __expf(tot - cum) * bv;
      barr[lane] = bv;
      if (lane == 0) sdt = __expf(tot);
    }
    __syncthreads();  // B1
    if (ch + 1 < NCH) {
      LOADQK(t0 + CL);
      LOADV(t0 + CL);
    }
    // ---- v conv + silu -> fp16 transposed [dv][s]
    {
      int tl = tid >> 5;
#pragma unroll
      for (int rr = 0; rr < 4; ++rr) {
        int t = rr * 16 + tl;
        float a = cwv.x * h2f(rv16[t][dvl]) + cwv.y * h2f(rv16[t + 1][dvl]) +
                  cwv.z * h2f(rv16[t + 2][dvl]) + cwv.w * h2f(rv16[t + 3][dvl]);
        a = a * sigm(a);
        Vs[dvl][t] = f2h(a);
      }
    }
    // ---- A = Q K^T; this wave: rows m0..m0+15, col blocks nh*2, nh*2+1
    half8 a[4];
#pragma unroll
    for (int kk = 0; kk < 4; ++kk) a[kk] = *(half8*)&Qs[m0 + l15][l16 * 8 + kk * 32];
#pragma unroll
    for (int j = 0; j < 2; ++j) {
      int n = nh * 2 + j;
      f32x4 a4 = {};
#pragma unroll
      for (int kk = 0; kk < 4; ++kk) {
        half8 b8 = *(half8*)&Ks[n * 16 + l15][l16 * 8 + kk * 32];
        a4 = __builtin_amdgcn_mfma_f32_16x16x32_f16(a[kk], b8, a4, 0, 0, 0);
      }
      int col = n * 16 + l15;
      float gc = garr[col], bc = barr[col];
#pragma unroll
      for (int i = 0; i < 4; ++i) {
        int row = m0 + l16 * 4 + i;
        float cval = (col <= row) ? __expf(garr[row] - gc) * bc * a4[i] : 0.f;
        SIs[row][col] = f2h(cval);
      }
    }
    __syncthreads();  // B2
    // ---- out_inter = Q @ St_prev, scaled by e^{Gc[t]}
    f32x4 ao = {};
#pragma unroll
    for (int kk = 0; kk < 4; ++kk) {
      half8 s8 = *(half8*)&SH[p][nh * 16 + l15][l16 * 8 + kk * 32];
      ao = __builtin_amdgcn_mfma_f32_16x16x32_f16(a[kk], s8, ao, 0, 0, 0);
    }
#pragma unroll
    for (int i = 0; i < 4; ++i) ao[i] *= earr[m0 + l16 * 4 + i];
    // ---- out += SI @ V
#pragma unroll
    for (int kk = 0; kk < 2; ++kk) {
      half8 asi = *(half8*)&SIs[m0 + l15][l16 * 8 + kk * 32];
      half8 bv8 = *(half8*)&Vs[nh * 16 + l15][l16 * 8 + kk * 32];
      ao = __builtin_amdgcn_mfma_f32_16x16x32_f16(asi, bv8, ao, 0, 0, 0);
    }
#pragma unroll
    for (int i = 0; i < 4; ++i)
      outr[(size_t)(bT + t0 + m0 + l16 * 4 + i) * 4096 + vch + nh * 16 + l15] = ao[i];
    // ---- state update: St = sdt*St + V^T (K.w); this wave: dk band wv*16
#pragma unroll
    for (int m = 0; m < 2; ++m)
#pragma unroll
      for (int i = 0; i < 4; ++i) st[m][i] *= sdt;
#pragma unroll
    for (int kk = 0; kk < 2; ++kk) {
      half8 bw;
      {
        int dk = wv * 16 + l15;
#pragma unroll
        for (int e = 0; e < 8; ++e) {
          int s = l16 * 8 + e + kk * 32;
          bw[e] = (_Float16)(h2f(Ks[s][dk]) * warr[s]);
        }
      }
#pragma unroll
      for (int m = 0; m < 2; ++m) {
        half8 av = *(half8*)&Vs[m * 16 + l15][l16 * 8 + kk * 32];
        st[m] = __builtin_amdgcn_mfma_f32_16x16x32_f16(av, bw, st[m], 0, 0, 0);
      }
    }
#pragma unroll
    for (int m = 0; m < 2; ++m)
#pragma unroll
      for (int i = 0; i < 4; ++i)
        SH[p ^ 1][m * 16 + l16 * 4 + i][wv * 16 + l15] = f2h(st[m][i]);
    __syncthreads();  // B4
  }
}

// ---------------- per-(bt,head) RMS scale from f32 outr ----------------
__global__ __launch_bounds__(256) void k_rms(const float* __restrict__ outr, float* __restrict__ rms) {
  int pair = blockIdx.x * 4 + (threadIdx.x >> 6);
  int lane = threadIdx.x & 63;
  float2 v = *(const float2*)&outr[(size_t)pair * 128 + lane * 2];
  float ss = v.x * v.x + v.y * v.y;
#pragma unroll
  for (int m = 1; m < 64; m <<= 1) ss += __shfl_xor(ss, m);
  if (lane == 0) rms[pair] = rsqrtf(ss * (1.0f / 128.0f) + 1e-6f);
}

extern "C" void kernel_launch(void* const* d_in, const int* in_sizes, int n_in,
                              void* d_out, int out_size, void* d_ws, size_t ws_size,
                              hipStream_t stream) {
  const float* x = (const float*)d_in[0];
  // d_in[1] = positions (int64) — unused by the math
  const float* W_qkv = (const float*)d_in[2];
  const float* W_z = (const float*)d_in[3];
  const float* W_b = (const float*)d_in[4];
  const float* W_a = (const float*)d_in[5];
  const float* conv_w = (const float*)d_in[6];
  const float* dt_bias = (const float*)d_in[7];
  const float* A_log = (const float*)d_in[8];
  const float* norm_w = (const float*)d_in[9];
  const float* W_out = (const float*)d_in[10];
  float* out = (float*)d_out;

  const size_t MB = 1ull << 20;
  const size_t need = 192 * MB + 3 * (size_t)NBT * 32 * 4;  // == proven bound
  if (ws_size < need) {
    k_sentinel<<<1, 1, 0, stream>>>(out);
    return;
  }
  char* ws = (char*)d_ws;
  // Region A [0,64MB): xh | xl | xh16 | spare. Later: outr f32 (full). Later: wout16 [0,16).
  u16* xh = (u16*)ws;
  u16* xl = (u16*)(ws + 16 * MB);
  u16* xh16 = (u16*)(ws + 32 * MB);
  float* outr = (float*)ws;
  u16* wout16 = (u16*)ws;
  // Region B [64,128MB): early wba+babuf [64,67); qkA16 [96,128); qkB16 [64,96); om16 [96,128).
  u16* wbah = (u16*)(ws + 64 * MB);
  u16* wbal = (u16*)(ws + 64 * MB + 512 * 1024);
  float* babuf = (float*)(ws + 65 * MB);
  u16* qkB16 = (u16*)(ws + 64 * MB);
  u16* qkA16 = (u16*)(ws + 96 * MB);
  u16* om16 = (u16*)(ws + 96 * MB);
  // Region C [128,192MB): wsh16 full [128,160); v16 [160,192). Later xh16b [128,144), wz16 [144,160).
  u16* wsh16 = (u16*)(ws + 128 * MB);
  u16* v16 = (u16*)(ws + 160 * MB);
  u16* xh16b = (u16*)(ws + 128 * MB);
  u16* wz16 = (u16*)(ws + 144 * MB);
  float* beta_t = (float*)(ws + 192 * MB);
  float* g_t = beta_t + (size_t)NBT * 32;
  float* rmsb = g_t + (size_t)NBT * 32;

  const int N4X = NBT * NC / 4;
  // --- conversions + ba path ---
  k_cvtx<<<N4X / 256, 256, 0, stream>>>(x, xh, xl, xh16, N4X);
  k_cvt16<<<2 * N4X / 256, 256, 0, stream>>>(W_qkv, wsh16, 2 * N4X);  // full 8192 rows
  k_wba<<<128 * NC / 256, 256, 0, stream>>>(W_b, W_a, wbah, wbal);
  k_gemm_bf3<<<dim3(1, NBT / 128), 256, 0, stream>>>(xh, xl, wbah, wbal, babuf, NBT, 128, NC);
  k_bg<<<NBT * 32 / 256, 256, 0, stream>>>(babuf, dt_bias, A_log, beta_t, g_t);

  // --- qk projection (fp16) -> conv+norm -> qkB16 ---
  k_gemm16<1><<<dim3(4096 / 128, NBT / 128), 256, 0, stream>>>(xh16, wsh16, qkA16, NBT, 4096, NC,
                                                               nullptr, nullptr, nullptr);
  k_convqk<<<NBT, 256, 0, stream>>>(qkA16, conv_w, qkB16);

  // --- v projection (fp16) ---
  k_gemm16<1><<<dim3(4096 / 128, NBT / 128), 256, 0, stream>>>(xh16, wsh16 + (size_t)4096 * NC, v16,
                                                               NBT, 4096, NC, nullptr, nullptr, nullptr);

  // --- chunked scan -> outr (overlays x planes, dead) ---
  k_scanc<<<256, 512, 0, stream>>>(qkB16, v16, conv_w, beta_t, g_t, outr);
  k_rms<<<NBT * NHV / 4, 256, 0, stream>>>(outr, rmsb);

  // --- z projection (fp16) with fused gate epilogue -> om16 (qkA16 dead) ---
  k_cvt16<<<N4X / 256, 256, 0, stream>>>(x, xh16b, N4X);
  k_cvt16<<<N4X / 256, 256, 0, stream>>>(W_z, wz16, N4X);
  k_gemm16<2><<<dim3(VALD / 128, NBT / 128), 256, 0, stream>>>(xh16b, wz16, om16, NBT, VALD, NC,
                                                               outr, rmsb, norm_w);

  // --- output projection (fp16) -> f32 out (outr dead -> wout16 overlay) ---
  k_cvt16<<<N4X / 256, 256, 0, stream>>>(W_out, wout16, N4X);
  k_gemm16<0><<<dim3(NC / 128, NBT / 128), 256, 0, stream>>>(om16, wout16, out, NBT, NC, VALD,
                                                             nullptr, nullptr, nullptr);
}